// Round 5
// baseline (1412.337 us; speedup 1.0000x reference)
//
#include <hip/hip_runtime.h>
#include <math.h>

// B=256, N_ROIS=200, ROI_DIM=199, D=192, H=6, Dh=32, L=3, FF=576, NCLS=2
// T = 51200 tokens.
// GEMMs: bf16x3 split-precision MFMA + global_load_lds width=16 staging.
// R0: fences around Pbuf handoff (race fix). R1: attn LDS 58.4->37.9KB.
// R2: attn launch_bounds (256,2) (undo 64-VGPR spill clamp).
// R3: GEMM chunk-XOR LDS swizzle (neutral; kept, bitwise identical).
// R4 (this): (a) attn launch_bounds (256,3) — unified VGPR+AGPR total ~172
// was capping at 2 waves/SIMD; 170-cap shaves a few regs -> 3 waves/SIMD.
// (b) gemm_mfma templated on MI (BM=MI*64): BM=64 for wo/ff2 doubles their
// grids 400->800 blocks (machine fits ~768 resident) and halves acc regs.

typedef unsigned short u16;
typedef unsigned int u32;
typedef __attribute__((ext_vector_type(8))) __bf16 bf16x8;
typedef __attribute__((ext_vector_type(4))) float f32x4;

#define GLL16(gp, lp) __builtin_amdgcn_global_load_lds(                 \
    (const __attribute__((address_space(1))) void*)(gp),                \
    (__attribute__((address_space(3))) void*)(lp), 16, 0, 0)

#define FENCE_VM()   do { asm volatile("s_waitcnt vmcnt(0)" ::: "memory");  \
                          __builtin_amdgcn_sched_barrier(0); } while (0)
#define FENCE_LGKM() do { asm volatile("s_waitcnt lgkmcnt(0)" ::: "memory");\
                          __builtin_amdgcn_sched_barrier(0); } while (0)

__device__ __forceinline__ u16 f2bf(float x) {
    u32 u = __float_as_uint(x);
    u = (u + 0x7FFFu + ((u >> 16) & 1u)) >> 16;   // RNE
    return (u16)u;
}
__device__ __forceinline__ float bf2f(u16 h) {
    return __uint_as_float(((u32)h) << 16);
}

__device__ __forceinline__ float gelu_exact(float x) {
    return 0.5f * x * (1.0f + erff(x * 0.7071067811865475f));
}

__device__ __forceinline__ float wave_sum(float v) {
#pragma unroll
    for (int o = 32; o > 0; o >>= 1) v += __shfl_xor(v, o, 64);
    return v;
}
__device__ __forceinline__ float wave_max(float v) {
#pragma unroll
    for (int o = 32; o > 0; o >>= 1) v = fmaxf(v, __shfl_xor(v, o, 64));
    return v;
}
__device__ __forceinline__ float row_sum16(float v) {
    v += __shfl_xor(v, 1, 64); v += __shfl_xor(v, 2, 64);
    v += __shfl_xor(v, 4, 64); v += __shfl_xor(v, 8, 64);
    return v;
}

__device__ __forceinline__ f32x4 mfma_bf16(bf16x8 a, bf16x8 b, f32x4 c) {
    return __builtin_amdgcn_mfma_f32_16x16x32_bf16(a, b, c, 0, 0, 0);
}

__device__ __forceinline__ void unpack8(uint4 p0, uint4 p1, uint4& hi, uint4& lo) {
    hi.x = __builtin_amdgcn_perm(p0.y, p0.x, 0x07060302u);
    hi.y = __builtin_amdgcn_perm(p0.w, p0.z, 0x07060302u);
    hi.z = __builtin_amdgcn_perm(p1.y, p1.x, 0x07060302u);
    hi.w = __builtin_amdgcn_perm(p1.w, p1.z, 0x07060302u);
    lo.x = __builtin_amdgcn_perm(p0.y, p0.x, 0x05040100u);
    lo.y = __builtin_amdgcn_perm(p0.w, p0.z, 0x05040100u);
    lo.z = __builtin_amdgcn_perm(p1.y, p1.x, 0x05040100u);
    lo.w = __builtin_amdgcn_perm(p1.w, p1.z, 0x05040100u);
}
__device__ __forceinline__ u32 packpair(float x) {
    u32 u = __float_as_uint(x);
    u32 t = (u + 0x7FFFu + ((u >> 16) & 1u)) & 0xFFFF0000u;
    float lo = x - __uint_as_float(t);
    return t | (__float_as_uint(lo) >> 16);
}

// ---------------------------------------------------------------------------
__global__ void conv_wt(const float* __restrict__ W, u16* __restrict__ oh,
                        u16* __restrict__ ol, int K, int N)
{
    const long z = blockIdx.z;
    const int idx = blockIdx.x * 256 + threadIdx.x;
    if (idx >= K * N) return;
    const int k = idx / N, n = idx - k * N;
    const float x = W[z * K * N + idx];
    const u16 h = f2bf(x);
    const u16 l = f2bf(x - bf2f(h));
    oh[z * (long)K * N + (long)n * K + k] = h;
    ol[z * (long)K * N + (long)n * K + k] = l;
}

// ---------------------------------------------------------------------------
__global__ void conv_x(const float* __restrict__ x,
                       u16* __restrict__ xh, u16* __restrict__ xl)
{
    const long idx = (long)blockIdx.x * 256 + threadIdx.x;
    if (idx >= 200L * 256 * 224) return;
    const int k = (int)(idx % 224);
    const long t = idx / 224;
    const int m = (int)(t % 256);
    const int z = (int)(t / 256);
    const float v = (k < 199) ? x[(long)m * 39800 + z * 199 + k] : 0.f;
    const u16 h = f2bf(v);
    xh[idx] = h;
    xl[idx] = f2bf(v - bf2f(h));
}

// ---------------------------------------------------------------------------
__global__ void conv_roiw(const float* __restrict__ W,
                          u16* __restrict__ oh, u16* __restrict__ ol)
{
    __shared__ float tile[32][33];
    const int z = blockIdx.z;
    const int k0 = blockIdx.x * 32;
    const int n0 = blockIdx.y * 32;
    for (int i = threadIdx.y; i < 32; i += 8) {
        const int k = k0 + i, n = n0 + threadIdx.x;
        tile[i][threadIdx.x] = (k < 199) ? W[((long)z * 199 + k) * 192 + n] : 0.f;
    }
    __syncthreads();
    for (int i = threadIdx.y; i < 32; i += 8) {
        const int n = n0 + i, k = k0 + threadIdx.x;
        const float v = tile[threadIdx.x][i];
        const u16 h = f2bf(v);
        const long o = ((long)z * 192 + n) * 224 + k;
        oh[o] = h;
        ol[o] = f2bf(v - bf2f(h));
    }
}

// ---------------------------------------------------------------------------
// bf16x3 MFMA GEMM, GLL staging. Tile (MI*64)x192, BK=32, 4 waves on M.
// MI=2: 128-row tile (wave: 32 rows). MI=1: 64-row tile (wave: 16 rows) —
// for N=192 single-n0 GEMMs (wo/ff2) to double grid fill 400->800 blocks.
// LDS chunk-XOR swizzle (R3). EPI 0: fp32 C. EPI 2: gelu pair. EPI 3: pair.
// EPI 5: fused residual+LN in place on Hh/Hl (N must be 192).
// ---------------------------------------------------------------------------
template<int EPI, int MI>
__global__ __launch_bounds__(256, 3) void gemm_mfma(
    const u16* __restrict__ Ah, const u16* __restrict__ Al,
    const u16* __restrict__ Bh, const u16* __restrict__ Bl,
    const float* __restrict__ bias,
    float* __restrict__ C, u16* __restrict__ Ch, u16* __restrict__ Cl,
    u16* __restrict__ Hh, u16* __restrict__ Hl,
    const float* __restrict__ lng, const float* __restrict__ lnb,
    int N, int K)
{
    constexpr int BM = MI * 64;
    __shared__ u16 Ash[BM][32];
    __shared__ u16 Als[BM][32];
    __shared__ u16 Bsh[192][32];
    __shared__ u16 Bsl[192][32];

    const int tid = threadIdx.x;
    const int wave = tid >> 6, lane = tid & 63;
    const int lm = lane & 15, quad = lane >> 4;
    const long m0 = (long)blockIdx.x * BM;
    const int n0 = blockIdx.y * 192;
    const int lrow = lane >> 2;
    const int lch  = (((lane & 3) ^ (lrow & 3)) * 8);   // staging swizzle
    const int sq   = (quad ^ (lm & 3)) * 8;             // read swizzle
    const int wrow = wave * (MI * 16);                  // wave's row base

    const u16* pA0h = Ah + (m0 + wrow +  0 + lrow) * K + lch;
    const u16* pA1h = Ah + (m0 + wrow + 16 + lrow) * K + lch;
    const u16* pA0l = Al + (m0 + wrow +  0 + lrow) * K + lch;
    const u16* pA1l = Al + (m0 + wrow + 16 + lrow) * K + lch;
    const u16* pB0h = Bh + (long)(n0 + wave * 48 +  0 + lrow) * K + lch;
    const u16* pB1h = Bh + (long)(n0 + wave * 48 + 16 + lrow) * K + lch;
    const u16* pB2h = Bh + (long)(n0 + wave * 48 + 32 + lrow) * K + lch;
    const u16* pB0l = Bl + (long)(n0 + wave * 48 +  0 + lrow) * K + lch;
    const u16* pB1l = Bl + (long)(n0 + wave * 48 + 16 + lrow) * K + lch;
    const u16* pB2l = Bl + (long)(n0 + wave * 48 + 32 + lrow) * K + lch;

    auto stage = [&](int k0) {
        GLL16(pA0h + k0, &Ash[wrow][0]);
        GLL16(pA0l + k0, &Als[wrow][0]);
        if (MI == 2) {
            GLL16(pA1h + k0, &Ash[wrow + 16][0]);
            GLL16(pA1l + k0, &Als[wrow + 16][0]);
        }
        GLL16(pB0h + k0, &Bsh[wave * 48][0]);
        GLL16(pB1h + k0, &Bsh[wave * 48 + 16][0]);
        GLL16(pB2h + k0, &Bsh[wave * 48 + 32][0]);
        GLL16(pB0l + k0, &Bsl[wave * 48][0]);
        GLL16(pB1l + k0, &Bsl[wave * 48 + 16][0]);
        GLL16(pB2l + k0, &Bsl[wave * 48 + 32][0]);
    };

    f32x4 acc[MI][12];
#pragma unroll
    for (int i = 0; i < MI; i++)
#pragma unroll
        for (int j = 0; j < 12; j++)
#pragma unroll
            for (int r = 0; r < 4; r++) acc[i][j][r] = 0.f;

    const int kt = K >> 5;
    stage(0);
    FENCE_VM();
    __syncthreads();

    for (int t = 0; t < kt; t++) {
        bf16x8 afh[MI], afl[MI];
#pragma unroll
        for (int mi = 0; mi < MI; mi++) {
            afh[mi] = *(const bf16x8*)&Ash[wrow + mi * 16 + lm][sq];
            afl[mi] = *(const bf16x8*)&Als[wrow + mi * 16 + lm][sq];
        }
#pragma unroll
        for (int g = 0; g < 4; g++) {
            bf16x8 bfh[3], bfl[3];
#pragma unroll
            for (int j = 0; j < 3; j++) {
                bfh[j] = *(const bf16x8*)&Bsh[g * 48 + j * 16 + lm][sq];
                bfl[j] = *(const bf16x8*)&Bsl[g * 48 + j * 16 + lm][sq];
            }
#pragma unroll
            for (int mi = 0; mi < MI; mi++)
#pragma unroll
                for (int j = 0; j < 3; j++) {
                    const int ni = g * 3 + j;
                    acc[mi][ni] = mfma_bf16(afh[mi], bfh[j], acc[mi][ni]);
                    acc[mi][ni] = mfma_bf16(afh[mi], bfl[j], acc[mi][ni]);
                    acc[mi][ni] = mfma_bf16(afl[mi], bfh[j], acc[mi][ni]);
                }
        }
        if (t + 1 < kt) {
            __syncthreads();
            stage((t + 1) << 5);
            FENCE_VM();
            __syncthreads();
        }
    }

    if (EPI == 5) {
        float gv[12], bv2[12], biasv[12];
#pragma unroll
        for (int ni = 0; ni < 12; ni++) {
            const int col = ni * 16 + lm;
            gv[ni] = lng[col]; bv2[ni] = lnb[col]; biasv[ni] = bias[col];
        }
#pragma unroll
        for (int mi = 0; mi < MI; mi++) {
#pragma unroll
            for (int r = 0; r < 4; r++) {
                const long row = m0 + wrow + mi * 16 + quad * 4 + r;
                const long rb = row * 192;
                float vals[12];
                float s = 0.f;
#pragma unroll
                for (int ni = 0; ni < 12; ni++) {
                    const int col = ni * 16 + lm;
                    const float hval = bf2f(Hh[rb + col]) + bf2f(Hl[rb + col]);
                    vals[ni] = acc[mi][ni][r] + biasv[ni] + hval;
                    s += vals[ni];
                }
                const float mean = row_sum16(s) * (1.f / 192.f);
                float ss = 0.f;
#pragma unroll
                for (int ni = 0; ni < 12; ni++) {
                    vals[ni] -= mean;
                    ss += vals[ni] * vals[ni];
                }
                const float var = row_sum16(ss) * (1.f / 192.f);
                const float rsr = 1.f / sqrtf(var + 1e-5f);
#pragma unroll
                for (int ni = 0; ni < 12; ni++) {
                    const int col = ni * 16 + lm;
                    const float y = vals[ni] * rsr * gv[ni] + bv2[ni];
                    const u16 hb = f2bf(y);
                    Hh[rb + col] = hb;
                    Hl[rb + col] = f2bf(y - bf2f(hb));
                }
            }
        }
        return;
    }

#pragma unroll
    for (int mi = 0; mi < MI; mi++) {
        const long rowb = m0 + wrow + mi * 16 + quad * 4;
#pragma unroll
        for (int ni = 0; ni < 12; ni++) {
            const int col = n0 + ni * 16 + lm;
            const float bv = bias[col];
#pragma unroll
            for (int r = 0; r < 4; r++) {
                float v = acc[mi][ni][r] + bv;
                if (EPI == 0) {
                    C[(rowb + r) * N + col] = v;
                } else {
                    if (EPI == 2) v = gelu_exact(v);
                    const u16 h = f2bf(v);
                    Ch[(rowb + r) * N + col] = h;
                    Cl[(rowb + r) * N + col] = f2bf(v - bf2f(h));
                }
            }
        }
    }
}

// ---------------------------------------------------------------------------
// Tokenizer MFMA (unchanged): per-z GEMM [256,224]@[192,224]^T, fused epi.
// ---------------------------------------------------------------------------
__global__ __launch_bounds__(256, 3) void tok_mfma(
    const u16* __restrict__ xh, const u16* __restrict__ xl,
    const u16* __restrict__ wth, const u16* __restrict__ wtl,
    const float* __restrict__ roi_b,
    const float* __restrict__ lng, const float* __restrict__ lnb,
    const float* __restrict__ pos,
    u16* __restrict__ hh, u16* __restrict__ hl)
{
    __shared__ u16 Ash[128][32];
    __shared__ u16 Als[128][32];
    __shared__ u16 Bsh[192][32];
    __shared__ u16 Bsl[192][32];

    const int tid = threadIdx.x;
    const int wave = tid >> 6, lane = tid & 63;
    const int lm = lane & 15, quad = lane >> 4;
    const int m0 = blockIdx.x * 128;
    const int z = blockIdx.y;
    const int lrow = lane >> 2;
    const int lch  = (((lane & 3) ^ (lrow & 3)) * 8);
    const int sq   = (quad ^ (lm & 3)) * 8;
    const int K = 224;

    const u16* pA0h = xh + ((long)z * 256 + m0 + wave * 32 +  0 + lrow) * K + lch;
    const u16* pA1h = xh + ((long)z * 256 + m0 + wave * 32 + 16 + lrow) * K + lch;
    const u16* pA0l = xl + ((long)z * 256 + m0 + wave * 32 +  0 + lrow) * K + lch;
    const u16* pA1l = xl + ((long)z * 256 + m0 + wave * 32 + 16 + lrow) * K + lch;
    const u16* pB0h = wth + ((long)z * 192 + wave * 48 +  0 + lrow) * K + lch;
    const u16* pB1h = wth + ((long)z * 192 + wave * 48 + 16 + lrow) * K + lch;
    const u16* pB2h = wth + ((long)z * 192 + wave * 48 + 32 + lrow) * K + lch;
    const u16* pB0l = wtl + ((long)z * 192 + wave * 48 +  0 + lrow) * K + lch;
    const u16* pB1l = wtl + ((long)z * 192 + wave * 48 + 16 + lrow) * K + lch;
    const u16* pB2l = wtl + ((long)z * 192 + wave * 48 + 32 + lrow) * K + lch;

    auto stage = [&](int k0) {
        GLL16(pA0h + k0, &Ash[wave * 32][0]);
        GLL16(pA1h + k0, &Ash[wave * 32 + 16][0]);
        GLL16(pA0l + k0, &Als[wave * 32][0]);
        GLL16(pA1l + k0, &Als[wave * 32 + 16][0]);
        GLL16(pB0h + k0, &Bsh[wave * 48][0]);
        GLL16(pB1h + k0, &Bsh[wave * 48 + 16][0]);
        GLL16(pB2h + k0, &Bsh[wave * 48 + 32][0]);
        GLL16(pB0l + k0, &Bsl[wave * 48][0]);
        GLL16(pB1l + k0, &Bsl[wave * 48 + 16][0]);
        GLL16(pB2l + k0, &Bsl[wave * 48 + 32][0]);
    };

    f32x4 acc[2][12];
#pragma unroll
    for (int i = 0; i < 2; i++)
#pragma unroll
        for (int j = 0; j < 12; j++)
#pragma unroll
            for (int r = 0; r < 4; r++) acc[i][j][r] = 0.f;

    stage(0);
    FENCE_VM();
    __syncthreads();
    for (int t = 0; t < 7; t++) {
        bf16x8 afh[2], afl[2];
#pragma unroll
        for (int mi = 0; mi < 2; mi++) {
            afh[mi] = *(const bf16x8*)&Ash[wave * 32 + mi * 16 + lm][sq];
            afl[mi] = *(const bf16x8*)&Als[wave * 32 + mi * 16 + lm][sq];
        }
#pragma unroll
        for (int g = 0; g < 4; g++) {
            bf16x8 bfh[3], bfl[3];
#pragma unroll
            for (int j = 0; j < 3; j++) {
                bfh[j] = *(const bf16x8*)&Bsh[g * 48 + j * 16 + lm][sq];
                bfl[j] = *(const bf16x8*)&Bsl[g * 48 + j * 16 + lm][sq];
            }
#pragma unroll
            for (int mi = 0; mi < 2; mi++)
#pragma unroll
                for (int j = 0; j < 3; j++) {
                    const int ni = g * 3 + j;
                    acc[mi][ni] = mfma_bf16(afh[mi], bfh[j], acc[mi][ni]);
                    acc[mi][ni] = mfma_bf16(afh[mi], bfl[j], acc[mi][ni]);
                    acc[mi][ni] = mfma_bf16(afl[mi], bfh[j], acc[mi][ni]);
                }
        }
        if (t + 1 < 7) {
            __syncthreads();
            stage((t + 1) << 5);
            FENCE_VM();
            __syncthreads();
        }
    }

    float gv[12], bv2[12], biasv[12], pv[12];
#pragma unroll
    for (int ni = 0; ni < 12; ni++) {
        const int col = ni * 16 + lm;
        gv[ni]    = lng[z * 192 + col];
        bv2[ni]   = lnb[z * 192 + col];
        biasv[ni] = roi_b[z * 192 + col];
        pv[ni]    = pos[z * 192 + col];
    }
#pragma unroll
    for (int mi = 0; mi < 2; mi++) {
#pragma unroll
        for (int r = 0; r < 4; r++) {
            const int brow = m0 + wave * 32 + mi * 16 + quad * 4 + r;
            float vals[12];
            float s = 0.f;
#pragma unroll
            for (int ni = 0; ni < 12; ni++) {
                vals[ni] = acc[mi][ni][r] + biasv[ni];
                s += vals[ni];
            }
            const float mean = row_sum16(s) * (1.f / 192.f);
            float ss = 0.f;
#pragma unroll
            for (int ni = 0; ni < 12; ni++) {
                vals[ni] -= mean;
                ss += vals[ni] * vals[ni];
            }
            const float var = row_sum16(ss) * (1.f / 192.f);
            const float rsr = 1.f / sqrtf(var + 1e-5f);
            const long ob = ((long)brow * 200 + z) * 192;
#pragma unroll
            for (int ni = 0; ni < 12; ni++) {
                const int col = ni * 16 + lm;
                const float y = gelu_exact(vals[ni] * rsr * gv[ni] + bv2[ni]) + pv[ni];
                const u16 hb = f2bf(y);
                hh[ob + col] = hb;
                hl[ob + col] = f2bf(y - bf2f(hb));
            }
        }
    }
}

// ---------------------------------------------------------------------------
// fp32 GEMM (tiny pool GEMMs). Tile 128x64, BK=16.
// ---------------------------------------------------------------------------
template<int EPI>
__global__ __launch_bounds__(256) void gemm_kernel(
    const float* __restrict__ A, int lda, long strideA,
    const float* __restrict__ Bw, long strideB,
    const float* __restrict__ bias, long strideBias,
    float* __restrict__ C, int ldc, long strideC,
    int M, int N, int K, int ldb)
{
    __shared__ float As[16][132];
    __shared__ float Bs[16][68];

    const int z = blockIdx.z;
    const float* Ab    = A    + (long)z * strideA;
    const float* Bb    = Bw   + (long)z * strideB;
    const float* biasb = bias + (long)z * strideBias;
    float*       Cb    = C    + (long)z * strideC;

    const int row0 = blockIdx.x * 128;
    const int col0 = blockIdx.y * 64;
    const int tid  = threadIdx.x;
    const int tm = tid >> 4;
    const int tn = tid & 15;

    const int la_m = tid >> 1;
    const int la_k = (tid & 1) * 8;
    const int lb_k = tid >> 4;
    const int lb_n = (tid & 15) * 4;

    const float* bcol = Bb + (col0 + lb_n);
    const float* arow = Ab + (long)(row0 + la_m) * lda;
    const bool vecA = ((lda & 3) == 0) &&
                      ((((unsigned long long)(const void*)arow) & 15ull) == 0ull);

    float acc[8][4];
#pragma unroll
    for (int i = 0; i < 8; i++)
#pragma unroll
        for (int j = 0; j < 4; j++) acc[i][j] = 0.f;

    for (int k0 = 0; k0 < K; k0 += 16) {
        if (vecA && (k0 + 16 <= K)) {
            float4 v0 = *(const float4*)(arow + k0 + la_k);
            float4 v1 = *(const float4*)(arow + k0 + la_k + 4);
            As[la_k + 0][la_m] = v0.x; As[la_k + 1][la_m] = v0.y;
            As[la_k + 2][la_m] = v0.z; As[la_k + 3][la_m] = v0.w;
            As[la_k + 4][la_m] = v1.x; As[la_k + 5][la_m] = v1.y;
            As[la_k + 6][la_m] = v1.z; As[la_k + 7][la_m] = v1.w;
        } else {
#pragma unroll
            for (int i = 0; i < 8; i++) {
                int k = k0 + la_k + i;
                As[la_k + i][la_m] = (k < K) ? arow[k] : 0.f;
            }
        }
        {
            int k = k0 + lb_k;
            float4 v = make_float4(0.f, 0.f, 0.f, 0.f);
            if (k < K) v = *(const float4*)(bcol + (long)k * ldb);
            *(float4*)&Bs[lb_k][lb_n] = v;
        }
        __syncthreads();
#pragma unroll
        for (int kk = 0; kk < 16; kk++) {
            float4 a0 = *(const float4*)&As[kk][tm * 8];
            float4 a1 = *(const float4*)&As[kk][tm * 8 + 4];
            float4 b4 = *(const float4*)&Bs[kk][tn * 4];
            float av[8] = {a0.x, a0.y, a0.z, a0.w, a1.x, a1.y, a1.z, a1.w};
            float bv[4] = {b4.x, b4.y, b4.z, b4.w};
#pragma unroll
            for (int i = 0; i < 8; i++)
#pragma unroll
                for (int j = 0; j < 4; j++) acc[i][j] += av[i] * bv[j];
        }
        __syncthreads();
    }

    const int gcol = col0 + tn * 4;
    float4 bv4 = *(const float4*)(biasb + gcol);
#pragma unroll
    for (int i = 0; i < 8; i++) {
        int grow = row0 + tm * 8 + i;
        float4 o;
        o.x = acc[i][0] + bv4.x; o.y = acc[i][1] + bv4.y;
        o.z = acc[i][2] + bv4.z; o.w = acc[i][3] + bv4.w;
        if (EPI == 1) {
            o.x = gelu_exact(o.x); o.y = gelu_exact(o.y);
            o.z = gelu_exact(o.z); o.w = gelu_exact(o.w);
        }
        *(float4*)(Cb + (long)grow * ldc + gcol) = o;
    }
}

// ---------------------------------------------------------------------------
// MFMA flash encoder attention.
// LDS 37,888 B (4 blocks/CU). launch_bounds (256,3): cap unified VGPR+AGPR
// at 170/lane so 3 waves/SIMD fit (was ~172 total -> 2 waves/SIMD).
// Watch WRITE_SIZE: if it balloons past ~40MB, this spilled -> revert.
// ---------------------------------------------------------------------------
__global__ __launch_bounds__(256, 3) void attn_enc_mfma(
    const u16* __restrict__ qkvh, const u16* __restrict__ qkvl,
    u16* __restrict__ outh, u16* __restrict__ outl)
{
    __shared__ u16 Ksh[96][40];
    __shared__ u16 Ksl[96][40];
    __shared__ u16 Vth[32][104];
    __shared__ u16 Vtl[32][104];
    __shared__ u32 Pbuf[4][16][36];

    const int bh = blockIdx.x;
    const int b = bh / 6, h = bh % 6;
    const int tid = threadIdx.x;
    const int wave = tid >> 6, lane = tid & 63;
    const int lm = lane & 15, quad = lane >> 4;
    const int nq = (wave == 0) ? 4 : 3;

    uint4 qh[4], ql[4];
#pragma unroll
    for (int i = 0; i < 4; i++) {
        if (i < nq) {
            int qt = wave + 4 * i;
            int qrow = qt * 16 + lm; if (qrow > 199) qrow = 199;
            const long off = (long)(b * 200 + qrow) * 576 + h * 32 + quad * 8;
            qh[i] = *(const uint4*)(qkvh + off);
            ql[i] = *(const uint4*)(qkvl + off);
        }
    }

    float mrow[4][4], lrow[4][4];
    f32x4 accO[4][2];
#pragma unroll
    for (int i = 0; i < 4; i++)
#pragma unroll
        for (int r = 0; r < 4; r++) {
            mrow[i][r] = -1e30f; lrow[i][r] = 0.f;
            accO[i][0][r] = 0.f; accO[i][1][r] = 0.f;
        }

    const float scale = 0.17677669529663688f;

#pragma unroll
    for (int ph = 0; ph < 3; ph++) {
        const int base = (ph == 0) ? 0 : (ph == 1) ? 96 : 192;
        const int ntl  = (ph == 2) ? 2 : 6;
        const int nslot = ntl * 16;

        __syncthreads();
        if (wave < 2) {
            const u16* src = wave ? qkvl : qkvh;
            u16* dst = wave ? &Ksl[0][0] : &Ksh[0][0];
#pragma unroll
            for (int rep = 0; rep < 6; rep++) {
                const int idx = rep * 64 + lane;
                if (idx < nslot * 4) {
                    const int key = idx >> 2, ch = idx & 3;
                    const int gk = base + key;
                    const bool valid = gk < 200;
                    const long roff = (long)(b * 200 + (valid ? gk : 0)) * 576
                                      + h * 32 + 192 + ch * 8;
                    uint4 v = valid ? *(const uint4*)(src + roff)
                                    : make_uint4(0, 0, 0, 0);
                    *(uint4*)(dst + key * 40 + ch * 8) = v;
                }
            }
        } else {
            const u16* src = (wave == 3) ? qkvl : qkvh;
            u16* dst = (wave == 3) ? &Vtl[0][0] : &Vth[0][0];
#pragma unroll
            for (int rep = 0; rep < 3; rep++) {
                const int idx = rep * 64 + lane;
                if (idx < nslot * 2) {
                    const int key = idx >> 1, hf = idx & 1;
                    const int gk = base + key;
                    const bool valid = gk < 200;
                    const long roff = (long)(b * 200 + (valid ? gk : 0)) * 576
                                      + h * 32 + 384 + hf * 16;
                    uint4 v0 = valid ? *(const uint4*)(src + roff)
                                     : make_uint4(0, 0, 0, 0);
                    uint4 v1 = valid ? *(const uint4*)(src + roff + 8)
                                     : make_uint4(0, 0, 0, 0);
                    const u16* p0 = (const u16*)&v0;
                    const u16* p1 = (const u16*)&v1;
#pragma unroll
                    for (int j = 0; j < 8; j++) {
                        dst[(hf * 16 + j) * 104 + key]     = p0[j];
                        dst[(hf * 16 + 8 + j) * 104 + key] = p1[j];
                    }
                }
            }
        }
        __syncthreads();

#pragma unroll
        for (int i = 0; i < 4; i++) {
            if (i >= nq) continue;
            const bf16x8 qhf = *(const bf16x8*)&qh[i];
            const bf16x8 qlf = *(const bf16x8*)&ql[i];
            float s[6][4];
#pragma unroll
            for (int ni = 0; ni < 6; ni++) {
                if (ni >= ntl) continue;
                bf16x8 kh8 = *(const bf16x8*)&Ksh[ni * 16 + lm][quad * 8];
                bf16x8 kl8 = *(const bf16x8*)&Ksl[ni * 16 + lm][quad * 8];
                f32x4 c = {0.f, 0.f, 0.f, 0.f};
                c = mfma_bf16(qhf, kh8, c);
                c = mfma_bf16(qhf, kl8, c);
                c = mfma_bf16(qlf, kh8, c);
                const bool masked = (base + ni * 16 + lm) >= 200;
#pragma unroll
                for (int r = 0; r < 4; r++)
                    s[ni][r] = masked ? -1e30f : c[r] * scale;
            }
            float fac[4];
#pragma unroll
            for (int r = 0; r < 4; r++) {
                float pm = s[0][r];
#pragma unroll
                for (int ni = 1; ni < 6; ni++)
                    if (ni < ntl) pm = fmaxf(pm, s[ni][r]);
                pm = fmaxf(pm, __shfl_xor(pm, 1, 64));
                pm = fmaxf(pm, __shfl_xor(pm, 2, 64));
                pm = fmaxf(pm, __shfl_xor(pm, 4, 64));
                pm = fmaxf(pm, __shfl_xor(pm, 8, 64));
                const float mn = fmaxf(mrow[i][r], pm);
                fac[r] = __expf(mrow[i][r] - mn);
                mrow[i][r] = mn;
                float ps = 0.f;
#pragma unroll
                for (int ni = 0; ni < 6; ni++) {
                    if (ni >= ntl) continue;
                    float e = __expf(s[ni][r] - mn);
                    s[ni][r] = e;
                    ps += e;
                }
                ps += __shfl_xor(ps, 1, 64);
                ps += __shfl_xor(ps, 2, 64);
                ps += __shfl_xor(ps, 4, 64);
                ps += __shfl_xor(ps, 8, 64);
                lrow[i][r] = lrow[i][r] * fac[r] + ps;
                accO[i][0][r] *= fac[r];
                accO[i][1][r] *= fac[r];
            }
#pragma unroll
            for (int ck = 0; ck < 3; ck++) {
                if (ck >= (ntl >> 1)) continue;
                // WAR guard: this wave's prior Pbuf reads must retire.
                FENCE_LGKM();
#pragma unroll
                for (int tl = 0; tl < 2; tl++) {
#pragma unroll
                    for (int r = 0; r < 4; r++) {
                        Pbuf[wave][quad * 4 + r][tl * 16 + lm] =
                            packpair(s[2 * ck + tl][r]);
                    }
                }
                // RAW guard: cross-lane handoff within the wave.
                FENCE_LGKM();
                uint4 w01 = *(const uint4*)&Pbuf[wave][lm][quad * 8];
                uint4 w23 = *(const uint4*)&Pbuf[wave][lm][quad * 8 + 4];
                uint4 hiu, lou;
                unpack8(w01, w23, hiu, lou);
                const bf16x8 phf = *(const bf16x8*)&hiu;
                const bf16x8 plf = *(const bf16x8*)&lou;
#pragma unroll
                for (int nt = 0; nt < 2; nt++) {
                    bf16x8 vh8 = *(const bf16x8*)&Vth[nt * 16 + lm][ck * 32 + quad * 8];
                    bf16x8 vl8 = *(const bf16x8*)&Vtl[nt * 16 + lm][ck * 32 + quad * 8];
                    accO[i][nt] = mfma_bf16(phf, vh8, accO[i][nt]);
                    accO[i][nt] = mfma_bf16(plf, vh8, accO[i][nt]);
                    accO[i][nt] = mfma_bf16(phf, vl8, accO[i][nt]);
                }
            }
        }
    }

#pragma unroll
    for (int i = 0; i < 4; i++) {
        if (i >= nq) continue;
        const int qt = wave + 4 * i;
#pragma unroll
        for (int r = 0; r < 4; r++) {
            const int qrow = qt * 16 + quad * 4 + r;
            if (qrow >= 200) continue;
            const float inv = 1.f / lrow[i][r];
            const long ob = (long)(b * 200 + qrow) * 192 + h * 32 + lm;
            const float v0 = accO[i][0][r] * inv;
            const float v1 = accO[i][1][r] * inv;
            const u16 h0 = f2bf(v0), h1 = f2bf(v1);
            outh[ob]      = h0;
            outl[ob]      = f2bf(v0 - bf2f(h0));
            outh[ob + 16] = h1;
            outl[ob + 16] = f2bf(v1 - bf2f(h1));
        }
    }
}

// ---------------------------------------------------------------------------
__global__ __launch_bounds__(192) void mean_tokens_pair(
    const u16* __restrict__ hh, const u16* __restrict__ hl, float* __restrict__ qmean)
{
    const int b = blockIdx.x, d = threadIdx.x;
    float s = 0.f;
    for (int r = 0; r < 200; r++) {
        const long idx = ((long)b * 200 + r) * 192 + d;
        s += bf2f(hh[idx]) + bf2f(hl[idx]);
    }
    qmean[b * 192 + d] = s * (1.f / 200.f);
}

// ---------------------------------------------------------------------------
__global__ __launch_bounds__(64) void attn_pool(
    const float* __restrict__ qp, const float* __restrict__ kv,
    float* __restrict__ out)
{
    __shared__ float p[200];
    const int b = blockIdx.x / 6, h = blockIdx.x % 6;
    const int lane = threadIdx.x;

    const float* qrow = qp + b * 192 + h * 32;
    float qr[32];
#pragma unroll
    for (int u = 0; u < 8; u++) {
        float4 t = *(const float4*)(qrow + 4 * u);
        qr[4 * u] = t.x; qr[4 * u + 1] = t.y;
        qr[4 * u + 2] = t.z; qr[4 * u + 3] = t.w;
    }
    const float scale = 0.17677669529663688f;
    const float* kb = kv + (long)(b * 200) * 384 + h * 32;
    float s[4];
    float mymax = -1e30f;
#pragma unroll
    for (int g = 0; g < 4; g++) {
        int j = lane + 64 * g;
        if (j < 200) {
            const float* kr = kb + (long)j * 384;
            float acc = 0.f;
#pragma unroll
            for (int u = 0; u < 8; u++) {
                float4 k4 = *(const float4*)(kr + 4 * u);
                acc += qr[4 * u] * k4.x + qr[4 * u + 1] * k4.y +
                       qr[4 * u + 2] * k4.z + qr[4 * u + 3] * k4.w;
            }
            s[g] = acc * scale;
            mymax = fmaxf(mymax, s[g]);
        } else {
            s[g] = -1e30f;
        }
    }
    float mx = wave_max(mymax);
    float psum = 0.f;
#pragma unroll
    for (int g = 0; g < 4; g++) {
        int j = lane + 64 * g;
        if (j < 200) {
            float e = __expf(s[g] - mx);
            p[j] = e;
            psum += e;
        }
    }
    float tot = wave_sum(psum);
    __syncthreads();
    const int half = lane >> 5, d = lane & 31;
    const float* vb = kv + (long)(b * 200) * 384 + 192 + h * 32 + d;
    float acc = 0.f;
    for (int jj = 0; jj < 100; jj++) {
        int j = half * 100 + jj;
        acc += p[j] * vb[(long)j * 384];
    }
    acc += __shfl_xor(acc, 32, 64);
    acc /= tot;
    if (lane < 32) out[b * 192 + h * 32 + d] = acc;
}

// ---------------------------------------------------------------------------
__global__ __launch_bounds__(64) void classifier_kernel(
    const float* __restrict__ pooled,
    const float* __restrict__ g, const float* __restrict__ bt,
    const float* __restrict__ W1, const float* __restrict__ b1,
    const float* __restrict__ W2, const float* __restrict__ b2,
    const float* __restrict__ W3, const float* __restrict__ b3,
    float* __restrict__ out)
{
    __shared__ float z[192];
    __shared__ float z1[96];
    __shared__ float z2[48];
    const int b = blockIdx.x, lane = threadIdx.x;
    const float* pr = pooled + b * 192;
    float x0 = pr[lane], x1 = pr[lane + 64], x2 = pr[lane + 128];
    float m = wave_sum(x0 + x1 + x2) * (1.f / 192.f);
    float d0 = x0 - m, d1 = x1 - m, d2 = x2 - m;
    float v = wave_sum(d0 * d0 + d1 * d1 + d2 * d2) * (1.f / 192.f);
    float rs = 1.f / sqrtf(v + 1e-5f);
    z[lane]       = d0 * rs * g[lane]       + bt[lane];
    z[lane + 64]  = d1 * rs * g[lane + 64]  + bt[lane + 64];
    z[lane + 128] = d2 * rs * g[lane + 128] + bt[lane + 128];
    __syncthreads();
#pragma unroll
    for (int rep = 0; rep < 2; rep++) {
        int j = lane + rep * 64;
        if (j < 96) {
            float a = b1[j];
            for (int k = 0; k < 192; k++) a += z[k] * W1[k * 96 + j];
            z1[j] = gelu_exact(a);
        }
    }
    __syncthreads();
    if (lane < 48) {
        float a = b2[lane];
        for (int k = 0; k < 96; k++) a += z1[k] * W2[k * 48 + lane];
        z2[lane] = gelu_exact(a);
    }
    __syncthreads();
    if (lane < 2) {
        float a = b3[lane];
        for (int k = 0; k < 48; k++) a += z2[k] * W3[k * 2 + lane];
        out[b * 2 + lane] = a;
    }
}

// ---------------------------------------------------------------------------
extern "C" void kernel_launch(void* const* d_in, const int* in_sizes, int n_in,
                              void* d_out, int out_size, void* d_ws, size_t ws_size,
                              hipStream_t stream)
{
    (void)in_sizes; (void)n_in; (void)out_size; (void)ws_size;

    const float* x         = (const float*)d_in[0];
    const float* roi_W     = (const float*)d_in[1];
    const float* roi_b     = (const float*)d_in[2];
    const float* roi_ln_g  = (const float*)d_in[3];
    const float* roi_ln_b  = (const float*)d_in[4];
    const float* pos_emb   = (const float*)d_in[5];
    const float* enc_Wqkv  = (const float*)d_in[6];
    const float* enc_bqkv  = (const float*)d_in[7];
    const float* enc_Wo    = (const float*)d_in[8];
    const float* enc_bo    = (const float*)d_in[9];
    const float* enc_ln1_g = (const float*)d_in[10];
    const float* enc_ln1_b = (const float*)d_in[11];
    const float* enc_W1    = (const float*)d_in[12];
    const float* enc_b1    = (const float*)d_in[13];
    const float* enc_W2    = (const float*)d_in[14];
    const float* enc_b2    = (const float*)d_in[15];
    const float* enc_ln2_g = (const float*)d_in[16];
    const float* enc_ln2_b = (const float*)d_in[17];
    const float* pool_Wqkv = (const float*)d_in[18];
    const float* pool_bqkv = (const float*)d_in[19];
    const float* pool_Wo   = (const float*)d_in[20];
    const float* pool_bo   = (const float*)d_in[21];
    const float* cls_ln_g  = (const float*)d_in[22];
    const float* cls_ln_b  = (const float*)d_in[23];
    const float* cls_W1    = (const float*)d_in[24];
    const float* cls_b1    = (const float*)d_in[25];
    const float* cls_W2    = (const float*)d_in[26];
    const float* cls_b2    = (const float*)d_in[27];
    const float* cls_W3    = (const float*)d_in[28];
    const float* cls_b3    = (const float*)d_in[29];

    char* ws = (char*)d_ws;
    u16*   hh    = (u16*)(ws);                      // [T,192] hi
    u16*   hl    = (u16*)(ws + 19660800);           // [T,192] lo
    char*  bufA  = ws + 39321600;                   // 117,964,800 B
    float* bufAf = (float*)bufA;
    u16*   xh    = (u16*)bufA;
    u16*   xl    = (u16*)(bufA + 22937600);
    u16*   wth   = (u16*)(bufA + 45875200);
    u16*   wtl   = (u16*)(bufA + 63078400);
    u16*   qkvh  = (u16*)bufA;
    u16*   qkvl  = (u16*)(bufA + 58982400);
    u16*   ffh   = (u16*)bufA;
    u16*   ffl   = (u16*)(bufA + 58982400);
    char*  bufB  = ws + 157286400;
    u16*   bBh   = (u16*)bufB;
    u16*   bBl   = (u16*)(bufB + 19660800);
    float* qmean = (float*)(ws + 196608000);
    float* qp    = qmean + 49152;
    float* pattn = qp + 49152;
    float* pooled= pattn + 49152;
    char*  wts   = ws + 197394432;
    u16* WqkvH = (u16*)(wts);
    u16* WqkvL = (u16*)(wts + 663552);
    u16* Wff1H = (u16*)(wts + 1327104);
    u16* Wff1L = (u16*)(wts + 1990656);
    u16* Wff2H = (u16*)(wts + 2654208);
    u16* Wff2L = (u16*)(wts + 3317760);
    u16* WwoH  = (u16*)(wts + 3981312);
    u16* WwoL  = (u16*)(wts + 4202496);
    u16* WkvH  = (u16*)(wts + 4423680);
    u16* WkvL  = (u16*)(wts + 4571136);

    // ---- weight split/transpose (once per call) ----
    conv_wt<<<dim3(144, 1, 9), 256, 0, stream>>>(enc_Wqkv, WqkvH, WqkvL, 192, 192);
    conv_wt<<<dim3(432, 1, 3), 256, 0, stream>>>(enc_W1, Wff1H, Wff1L, 192, 576);
    conv_wt<<<dim3(432, 1, 3), 256, 0, stream>>>(enc_W2, Wff2H, Wff2L, 576, 192);
    conv_wt<<<dim3(144, 1, 3), 256, 0, stream>>>(enc_Wo, WwoH, WwoL, 192, 192);
    conv_wt<<<dim3(144, 1, 2), 256, 0, stream>>>(pool_Wqkv + 36864, WkvH, WkvL, 192, 192);

    // ---- tokenizer ----
    conv_x<<<44800, 256, 0, stream>>>(x, xh, xl);
    conv_roiw<<<dim3(7, 6, 200), dim3(32, 8), 0, stream>>>(roi_W, wth, wtl);
    tok_mfma<<<dim3(2, 200), 256, 0, stream>>>(
        xh, xl, wth, wtl, roi_b, roi_ln_g, roi_ln_b, pos_emb, hh, hl);

    // ---- encoder layers ----
    for (int i = 0; i < 3; i++) {
        gemm_mfma<3, 2><<<dim3(400, 3), 256, 0, stream>>>(
            hh, hl, WqkvH + (long)i * 110592, WqkvL + (long)i * 110592,
            enc_bqkv + i * 576, nullptr, qkvh, qkvl,
            nullptr, nullptr, nullptr, nullptr, 576, 192);
        attn_enc_mfma<<<1536, 256, 0, stream>>>(qkvh, qkvl, bBh, bBl);
        // Wo + fused residual LN1 (BM=64 -> 800 blocks)
        gemm_mfma<5, 1><<<dim3(800, 1), 256, 0, stream>>>(
            bBh, bBl, WwoH + (long)i * 36864, WwoL + (long)i * 36864,
            enc_bo + i * 192, nullptr, nullptr, nullptr,
            hh, hl, enc_ln1_g + i * 192, enc_ln1_b + i * 192, 192, 192);
        gemm_mfma<2, 2><<<dim3(400, 3), 256, 0, stream>>>(
            hh, hl, Wff1H + (long)i * 110592, Wff1L + (long)i * 110592,
            enc_b1 + i * 576, nullptr, ffh, ffl,
            nullptr, nullptr, nullptr, nullptr, 576, 192);
        // ff2 + fused residual LN2 (BM=64 -> 800 blocks)
        gemm_mfma<5, 1><<<dim3(800, 1), 256, 0, stream>>>(
            ffh, ffl, Wff2H + (long)i * 110592, Wff2L + (long)i * 110592,
            enc_b2 + i * 192, nullptr, nullptr, nullptr,
            hh, hl, enc_ln2_g + i * 192, enc_ln2_b + i * 192, 192, 576);
    }

    // ---- pooling ----
    mean_tokens_pair<<<256, 192, 0, stream>>>(hh, hl, qmean);
    gemm_kernel<0><<<dim3(2, 3, 1), 256, 0, stream>>>(
        qmean, 192, 0, pool_Wqkv, 0, pool_bqkv, 0, qp, 192, 0, 256, 192, 192, 192);
    gemm_mfma<0, 2><<<dim3(400, 2), 256, 0, stream>>>(
        hh, hl, WkvH, WkvL, pool_bqkv + 192,
        bufAf, nullptr, nullptr,
        nullptr, nullptr, nullptr, nullptr, 384, 192);
    attn_pool<<<1536, 64, 0, stream>>>(qp, bufAf, pattn);
    gemm_kernel<0><<<dim3(2, 3, 1), 256, 0, stream>>>(
        pattn, 192, 0, pool_Wo, 0, pool_bo, 0, pooled, 192, 0, 256, 192, 192, 192);

    // ---- classifier ----
    classifier_kernel<<<256, 64, 0, stream>>>(
        pooled, cls_ln_g, cls_ln_b,
        cls_W1, cls_b1, cls_W2, cls_b2, cls_W3, cls_b3,
        (float*)d_out);
}

// Round 6
// 1354.965 us; speedup vs baseline: 1.0423x; 1.0423x over previous
//
#include <hip/hip_runtime.h>
#include <math.h>

// B=256, N_ROIS=200, ROI_DIM=199, D=192, H=6, Dh=32, L=3, FF=576, NCLS=2
// T = 51200 tokens.
// GEMMs: bf16x3 split-precision MFMA + global_load_lds width=16 staging.
// R0: fences around Pbuf handoff (race fix). R1: attn LDS 58.4->37.9KB.
// R2/R4 lesson: launch-bound VGPR clamps below natural footprint (~170
// unified) => massive scratch spill (WRITE_SIZE 38->145/244MB). Never cap.
// R3: GEMM chunk-XOR LDS swizzle (neutral, kept). R4: MI=1 + (256,3) both
// regressed -> reverted.
// R5 (this): attn restructured to 8 waves x 512 thr, <=2 q-tiles/wave —
// halves per-wave live state (the legitimate register reduction), Pbuf
// [8][16][36], LDS 47104B, launch_bounds(512,2) (no forced spill).

typedef unsigned short u16;
typedef unsigned int u32;
typedef __attribute__((ext_vector_type(8))) __bf16 bf16x8;
typedef __attribute__((ext_vector_type(4))) float f32x4;

#define GLL16(gp, lp) __builtin_amdgcn_global_load_lds(                 \
    (const __attribute__((address_space(1))) void*)(gp),                \
    (__attribute__((address_space(3))) void*)(lp), 16, 0, 0)

#define FENCE_VM()   do { asm volatile("s_waitcnt vmcnt(0)" ::: "memory");  \
                          __builtin_amdgcn_sched_barrier(0); } while (0)
#define FENCE_LGKM() do { asm volatile("s_waitcnt lgkmcnt(0)" ::: "memory");\
                          __builtin_amdgcn_sched_barrier(0); } while (0)

__device__ __forceinline__ u16 f2bf(float x) {
    u32 u = __float_as_uint(x);
    u = (u + 0x7FFFu + ((u >> 16) & 1u)) >> 16;   // RNE
    return (u16)u;
}
__device__ __forceinline__ float bf2f(u16 h) {
    return __uint_as_float(((u32)h) << 16);
}

__device__ __forceinline__ float gelu_exact(float x) {
    return 0.5f * x * (1.0f + erff(x * 0.7071067811865475f));
}

__device__ __forceinline__ float wave_sum(float v) {
#pragma unroll
    for (int o = 32; o > 0; o >>= 1) v += __shfl_xor(v, o, 64);
    return v;
}
__device__ __forceinline__ float wave_max(float v) {
#pragma unroll
    for (int o = 32; o > 0; o >>= 1) v = fmaxf(v, __shfl_xor(v, o, 64));
    return v;
}
// reduce across the 16 lanes sharing a quad (row of an MFMA C tile)
__device__ __forceinline__ float row_sum16(float v) {
    v += __shfl_xor(v, 1, 64); v += __shfl_xor(v, 2, 64);
    v += __shfl_xor(v, 4, 64); v += __shfl_xor(v, 8, 64);
    return v;
}

__device__ __forceinline__ f32x4 mfma_bf16(bf16x8 a, bf16x8 b, f32x4 c) {
    return __builtin_amdgcn_mfma_f32_16x16x32_bf16(a, b, c, 0, 0, 0);
}

__device__ __forceinline__ void unpack8(uint4 p0, uint4 p1, uint4& hi, uint4& lo) {
    hi.x = __builtin_amdgcn_perm(p0.y, p0.x, 0x07060302u);
    hi.y = __builtin_amdgcn_perm(p0.w, p0.z, 0x07060302u);
    hi.z = __builtin_amdgcn_perm(p1.y, p1.x, 0x07060302u);
    hi.w = __builtin_amdgcn_perm(p1.w, p1.z, 0x07060302u);
    lo.x = __builtin_amdgcn_perm(p0.y, p0.x, 0x05040100u);
    lo.y = __builtin_amdgcn_perm(p0.w, p0.z, 0x05040100u);
    lo.z = __builtin_amdgcn_perm(p1.y, p1.x, 0x05040100u);
    lo.w = __builtin_amdgcn_perm(p1.w, p1.z, 0x05040100u);
}
__device__ __forceinline__ u32 packpair(float x) {
    u32 u = __float_as_uint(x);
    u32 t = (u + 0x7FFFu + ((u >> 16) & 1u)) & 0xFFFF0000u;
    float lo = x - __uint_as_float(t);
    return t | (__float_as_uint(lo) >> 16);
}

// ---------------------------------------------------------------------------
__global__ void conv_wt(const float* __restrict__ W, u16* __restrict__ oh,
                        u16* __restrict__ ol, int K, int N)
{
    const long z = blockIdx.z;
    const int idx = blockIdx.x * 256 + threadIdx.x;
    if (idx >= K * N) return;
    const int k = idx / N, n = idx - k * N;
    const float x = W[z * K * N + idx];
    const u16 h = f2bf(x);
    const u16 l = f2bf(x - bf2f(h));
    oh[z * (long)K * N + (long)n * K + k] = h;
    ol[z * (long)K * N + (long)n * K + k] = l;
}

// ---------------------------------------------------------------------------
__global__ void conv_x(const float* __restrict__ x,
                       u16* __restrict__ xh, u16* __restrict__ xl)
{
    const long idx = (long)blockIdx.x * 256 + threadIdx.x;
    if (idx >= 200L * 256 * 224) return;
    const int k = (int)(idx % 224);
    const long t = idx / 224;
    const int m = (int)(t % 256);
    const int z = (int)(t / 256);
    const float v = (k < 199) ? x[(long)m * 39800 + z * 199 + k] : 0.f;
    const u16 h = f2bf(v);
    xh[idx] = h;
    xl[idx] = f2bf(v - bf2f(h));
}

// ---------------------------------------------------------------------------
__global__ void conv_roiw(const float* __restrict__ W,
                          u16* __restrict__ oh, u16* __restrict__ ol)
{
    __shared__ float tile[32][33];
    const int z = blockIdx.z;
    const int k0 = blockIdx.x * 32;
    const int n0 = blockIdx.y * 32;
    for (int i = threadIdx.y; i < 32; i += 8) {
        const int k = k0 + i, n = n0 + threadIdx.x;
        tile[i][threadIdx.x] = (k < 199) ? W[((long)z * 199 + k) * 192 + n] : 0.f;
    }
    __syncthreads();
    for (int i = threadIdx.y; i < 32; i += 8) {
        const int n = n0 + i, k = k0 + threadIdx.x;
        const float v = tile[threadIdx.x][i];
        const u16 h = f2bf(v);
        const long o = ((long)z * 192 + n) * 224 + k;
        oh[o] = h;
        ol[o] = f2bf(v - bf2f(h));
    }
}

// ---------------------------------------------------------------------------
// bf16x3 MFMA GEMM, GLL staging. Tile 128x192, BK=32, 4 waves on M.
// LDS chunk-XOR swizzle (R3). EPI 0: fp32 C. EPI 2: gelu pair. EPI 3: pair.
// EPI 5: fused residual+LN in place on Hh/Hl (N must be 192).
// ---------------------------------------------------------------------------
template<int EPI>
__global__ __launch_bounds__(256, 3) void gemm_mfma(
    const u16* __restrict__ Ah, const u16* __restrict__ Al,
    const u16* __restrict__ Bh, const u16* __restrict__ Bl,
    const float* __restrict__ bias,
    float* __restrict__ C, u16* __restrict__ Ch, u16* __restrict__ Cl,
    u16* __restrict__ Hh, u16* __restrict__ Hl,
    const float* __restrict__ lng, const float* __restrict__ lnb,
    int N, int K)
{
    __shared__ u16 Ash[128][32];
    __shared__ u16 Als[128][32];
    __shared__ u16 Bsh[192][32];
    __shared__ u16 Bsl[192][32];

    const int tid = threadIdx.x;
    const int wave = tid >> 6, lane = tid & 63;
    const int lm = lane & 15, quad = lane >> 4;
    const long m0 = (long)blockIdx.x * 128;
    const int n0 = blockIdx.y * 192;
    const int lrow = lane >> 2;
    const int lch  = (((lane & 3) ^ (lrow & 3)) * 8);   // staging swizzle
    const int sq   = (quad ^ (lm & 3)) * 8;             // read swizzle

    const u16* pA0h = Ah + (m0 + wave * 32 +  0 + lrow) * K + lch;
    const u16* pA1h = Ah + (m0 + wave * 32 + 16 + lrow) * K + lch;
    const u16* pA0l = Al + (m0 + wave * 32 +  0 + lrow) * K + lch;
    const u16* pA1l = Al + (m0 + wave * 32 + 16 + lrow) * K + lch;
    const u16* pB0h = Bh + (long)(n0 + wave * 48 +  0 + lrow) * K + lch;
    const u16* pB1h = Bh + (long)(n0 + wave * 48 + 16 + lrow) * K + lch;
    const u16* pB2h = Bh + (long)(n0 + wave * 48 + 32 + lrow) * K + lch;
    const u16* pB0l = Bl + (long)(n0 + wave * 48 +  0 + lrow) * K + lch;
    const u16* pB1l = Bl + (long)(n0 + wave * 48 + 16 + lrow) * K + lch;
    const u16* pB2l = Bl + (long)(n0 + wave * 48 + 32 + lrow) * K + lch;

    auto stage = [&](int k0) {
        GLL16(pA0h + k0, &Ash[wave * 32][0]);
        GLL16(pA1h + k0, &Ash[wave * 32 + 16][0]);
        GLL16(pA0l + k0, &Als[wave * 32][0]);
        GLL16(pA1l + k0, &Als[wave * 32 + 16][0]);
        GLL16(pB0h + k0, &Bsh[wave * 48][0]);
        GLL16(pB1h + k0, &Bsh[wave * 48 + 16][0]);
        GLL16(pB2h + k0, &Bsh[wave * 48 + 32][0]);
        GLL16(pB0l + k0, &Bsl[wave * 48][0]);
        GLL16(pB1l + k0, &Bsl[wave * 48 + 16][0]);
        GLL16(pB2l + k0, &Bsl[wave * 48 + 32][0]);
    };

    f32x4 acc[2][12];
#pragma unroll
    for (int i = 0; i < 2; i++)
#pragma unroll
        for (int j = 0; j < 12; j++)
#pragma unroll
            for (int r = 0; r < 4; r++) acc[i][j][r] = 0.f;

    const int kt = K >> 5;
    stage(0);
    FENCE_VM();
    __syncthreads();

    for (int t = 0; t < kt; t++) {
        bf16x8 afh[2], afl[2];
#pragma unroll
        for (int mi = 0; mi < 2; mi++) {
            afh[mi] = *(const bf16x8*)&Ash[wave * 32 + mi * 16 + lm][sq];
            afl[mi] = *(const bf16x8*)&Als[wave * 32 + mi * 16 + lm][sq];
        }
#pragma unroll
        for (int g = 0; g < 4; g++) {
            bf16x8 bfh[3], bfl[3];
#pragma unroll
            for (int j = 0; j < 3; j++) {
                bfh[j] = *(const bf16x8*)&Bsh[g * 48 + j * 16 + lm][sq];
                bfl[j] = *(const bf16x8*)&Bsl[g * 48 + j * 16 + lm][sq];
            }
#pragma unroll
            for (int mi = 0; mi < 2; mi++)
#pragma unroll
                for (int j = 0; j < 3; j++) {
                    const int ni = g * 3 + j;
                    acc[mi][ni] = mfma_bf16(afh[mi], bfh[j], acc[mi][ni]);
                    acc[mi][ni] = mfma_bf16(afh[mi], bfl[j], acc[mi][ni]);
                    acc[mi][ni] = mfma_bf16(afl[mi], bfh[j], acc[mi][ni]);
                }
        }
        if (t + 1 < kt) {
            __syncthreads();
            stage((t + 1) << 5);
            FENCE_VM();
            __syncthreads();
        }
    }

    if (EPI == 5) {
        float gv[12], bv2[12], biasv[12];
#pragma unroll
        for (int ni = 0; ni < 12; ni++) {
            const int col = ni * 16 + lm;
            gv[ni] = lng[col]; bv2[ni] = lnb[col]; biasv[ni] = bias[col];
        }
#pragma unroll
        for (int mi = 0; mi < 2; mi++) {
#pragma unroll
            for (int r = 0; r < 4; r++) {
                const long row = m0 + wave * 32 + mi * 16 + quad * 4 + r;
                const long rb = row * 192;
                float vals[12];
                float s = 0.f;
#pragma unroll
                for (int ni = 0; ni < 12; ni++) {
                    const int col = ni * 16 + lm;
                    const float hval = bf2f(Hh[rb + col]) + bf2f(Hl[rb + col]);
                    vals[ni] = acc[mi][ni][r] + biasv[ni] + hval;
                    s += vals[ni];
                }
                const float mean = row_sum16(s) * (1.f / 192.f);
                float ss = 0.f;
#pragma unroll
                for (int ni = 0; ni < 12; ni++) {
                    vals[ni] -= mean;
                    ss += vals[ni] * vals[ni];
                }
                const float var = row_sum16(ss) * (1.f / 192.f);
                const float rsr = 1.f / sqrtf(var + 1e-5f);
#pragma unroll
                for (int ni = 0; ni < 12; ni++) {
                    const int col = ni * 16 + lm;
                    const float y = vals[ni] * rsr * gv[ni] + bv2[ni];
                    const u16 hb = f2bf(y);
                    Hh[rb + col] = hb;
                    Hl[rb + col] = f2bf(y - bf2f(hb));
                }
            }
        }
        return;
    }

#pragma unroll
    for (int mi = 0; mi < 2; mi++) {
        const long rowb = m0 + wave * 32 + mi * 16 + quad * 4;
#pragma unroll
        for (int ni = 0; ni < 12; ni++) {
            const int col = n0 + ni * 16 + lm;
            const float bv = bias[col];
#pragma unroll
            for (int r = 0; r < 4; r++) {
                float v = acc[mi][ni][r] + bv;
                if (EPI == 0) {
                    C[(rowb + r) * N + col] = v;
                } else {
                    if (EPI == 2) v = gelu_exact(v);
                    const u16 h = f2bf(v);
                    Ch[(rowb + r) * N + col] = h;
                    Cl[(rowb + r) * N + col] = f2bf(v - bf2f(h));
                }
            }
        }
    }
}

// ---------------------------------------------------------------------------
// Tokenizer MFMA: per-z GEMM [256,224]@[192,224]^T, fused epilogue.
// ---------------------------------------------------------------------------
__global__ __launch_bounds__(256, 3) void tok_mfma(
    const u16* __restrict__ xh, const u16* __restrict__ xl,
    const u16* __restrict__ wth, const u16* __restrict__ wtl,
    const float* __restrict__ roi_b,
    const float* __restrict__ lng, const float* __restrict__ lnb,
    const float* __restrict__ pos,
    u16* __restrict__ hh, u16* __restrict__ hl)
{
    __shared__ u16 Ash[128][32];
    __shared__ u16 Als[128][32];
    __shared__ u16 Bsh[192][32];
    __shared__ u16 Bsl[192][32];

    const int tid = threadIdx.x;
    const int wave = tid >> 6, lane = tid & 63;
    const int lm = lane & 15, quad = lane >> 4;
    const int m0 = blockIdx.x * 128;
    const int z = blockIdx.y;
    const int lrow = lane >> 2;
    const int lch  = (((lane & 3) ^ (lrow & 3)) * 8);
    const int sq   = (quad ^ (lm & 3)) * 8;
    const int K = 224;

    const u16* pA0h = xh + ((long)z * 256 + m0 + wave * 32 +  0 + lrow) * K + lch;
    const u16* pA1h = xh + ((long)z * 256 + m0 + wave * 32 + 16 + lrow) * K + lch;
    const u16* pA0l = xl + ((long)z * 256 + m0 + wave * 32 +  0 + lrow) * K + lch;
    const u16* pA1l = xl + ((long)z * 256 + m0 + wave * 32 + 16 + lrow) * K + lch;
    const u16* pB0h = wth + ((long)z * 192 + wave * 48 +  0 + lrow) * K + lch;
    const u16* pB1h = wth + ((long)z * 192 + wave * 48 + 16 + lrow) * K + lch;
    const u16* pB2h = wth + ((long)z * 192 + wave * 48 + 32 + lrow) * K + lch;
    const u16* pB0l = wtl + ((long)z * 192 + wave * 48 +  0 + lrow) * K + lch;
    const u16* pB1l = wtl + ((long)z * 192 + wave * 48 + 16 + lrow) * K + lch;
    const u16* pB2l = wtl + ((long)z * 192 + wave * 48 + 32 + lrow) * K + lch;

    auto stage = [&](int k0) {
        GLL16(pA0h + k0, &Ash[wave * 32][0]);
        GLL16(pA1h + k0, &Ash[wave * 32 + 16][0]);
        GLL16(pA0l + k0, &Als[wave * 32][0]);
        GLL16(pA1l + k0, &Als[wave * 32 + 16][0]);
        GLL16(pB0h + k0, &Bsh[wave * 48][0]);
        GLL16(pB1h + k0, &Bsh[wave * 48 + 16][0]);
        GLL16(pB2h + k0, &Bsh[wave * 48 + 32][0]);
        GLL16(pB0l + k0, &Bsl[wave * 48][0]);
        GLL16(pB1l + k0, &Bsl[wave * 48 + 16][0]);
        GLL16(pB2l + k0, &Bsl[wave * 48 + 32][0]);
    };

    f32x4 acc[2][12];
#pragma unroll
    for (int i = 0; i < 2; i++)
#pragma unroll
        for (int j = 0; j < 12; j++)
#pragma unroll
            for (int r = 0; r < 4; r++) acc[i][j][r] = 0.f;

    stage(0);
    FENCE_VM();
    __syncthreads();
    for (int t = 0; t < 7; t++) {
        bf16x8 afh[2], afl[2];
#pragma unroll
        for (int mi = 0; mi < 2; mi++) {
            afh[mi] = *(const bf16x8*)&Ash[wave * 32 + mi * 16 + lm][sq];
            afl[mi] = *(const bf16x8*)&Als[wave * 32 + mi * 16 + lm][sq];
        }
#pragma unroll
        for (int g = 0; g < 4; g++) {
            bf16x8 bfh[3], bfl[3];
#pragma unroll
            for (int j = 0; j < 3; j++) {
                bfh[j] = *(const bf16x8*)&Bsh[g * 48 + j * 16 + lm][sq];
                bfl[j] = *(const bf16x8*)&Bsl[g * 48 + j * 16 + lm][sq];
            }
#pragma unroll
            for (int mi = 0; mi < 2; mi++)
#pragma unroll
                for (int j = 0; j < 3; j++) {
                    const int ni = g * 3 + j;
                    acc[mi][ni] = mfma_bf16(afh[mi], bfh[j], acc[mi][ni]);
                    acc[mi][ni] = mfma_bf16(afh[mi], bfl[j], acc[mi][ni]);
                    acc[mi][ni] = mfma_bf16(afl[mi], bfh[j], acc[mi][ni]);
                }
        }
        if (t + 1 < 7) {
            __syncthreads();
            stage((t + 1) << 5);
            FENCE_VM();
            __syncthreads();
        }
    }

    float gv[12], bv2[12], biasv[12], pv[12];
#pragma unroll
    for (int ni = 0; ni < 12; ni++) {
        const int col = ni * 16 + lm;
        gv[ni]    = lng[z * 192 + col];
        bv2[ni]   = lnb[z * 192 + col];
        biasv[ni] = roi_b[z * 192 + col];
        pv[ni]    = pos[z * 192 + col];
    }
#pragma unroll
    for (int mi = 0; mi < 2; mi++) {
#pragma unroll
        for (int r = 0; r < 4; r++) {
            const int brow = m0 + wave * 32 + mi * 16 + quad * 4 + r;
            float vals[12];
            float s = 0.f;
#pragma unroll
            for (int ni = 0; ni < 12; ni++) {
                vals[ni] = acc[mi][ni][r] + biasv[ni];
                s += vals[ni];
            }
            const float mean = row_sum16(s) * (1.f / 192.f);
            float ss = 0.f;
#pragma unroll
            for (int ni = 0; ni < 12; ni++) {
                vals[ni] -= mean;
                ss += vals[ni] * vals[ni];
            }
            const float var = row_sum16(ss) * (1.f / 192.f);
            const float rsr = 1.f / sqrtf(var + 1e-5f);
            const long ob = ((long)brow * 200 + z) * 192;
#pragma unroll
            for (int ni = 0; ni < 12; ni++) {
                const int col = ni * 16 + lm;
                const float y = gelu_exact(vals[ni] * rsr * gv[ni] + bv2[ni]) + pv[ni];
                const u16 hb = f2bf(y);
                hh[ob + col] = hb;
                hl[ob + col] = f2bf(y - bf2f(hb));
            }
        }
    }
}

// ---------------------------------------------------------------------------
// fp32 GEMM (tiny pool GEMMs). Tile 128x64, BK=16.
// ---------------------------------------------------------------------------
template<int EPI>
__global__ __launch_bounds__(256) void gemm_kernel(
    const float* __restrict__ A, int lda, long strideA,
    const float* __restrict__ Bw, long strideB,
    const float* __restrict__ bias, long strideBias,
    float* __restrict__ C, int ldc, long strideC,
    int M, int N, int K, int ldb)
{
    __shared__ float As[16][132];
    __shared__ float Bs[16][68];

    const int z = blockIdx.z;
    const float* Ab    = A    + (long)z * strideA;
    const float* Bb    = Bw   + (long)z * strideB;
    const float* biasb = bias + (long)z * strideBias;
    float*       Cb    = C    + (long)z * strideC;

    const int row0 = blockIdx.x * 128;
    const int col0 = blockIdx.y * 64;
    const int tid  = threadIdx.x;
    const int tm = tid >> 4;
    const int tn = tid & 15;

    const int la_m = tid >> 1;
    const int la_k = (tid & 1) * 8;
    const int lb_k = tid >> 4;
    const int lb_n = (tid & 15) * 4;

    const float* bcol = Bb + (col0 + lb_n);
    const float* arow = Ab + (long)(row0 + la_m) * lda;
    const bool vecA = ((lda & 3) == 0) &&
                      ((((unsigned long long)(const void*)arow) & 15ull) == 0ull);

    float acc[8][4];
#pragma unroll
    for (int i = 0; i < 8; i++)
#pragma unroll
        for (int j = 0; j < 4; j++) acc[i][j] = 0.f;

    for (int k0 = 0; k0 < K; k0 += 16) {
        if (vecA && (k0 + 16 <= K)) {
            float4 v0 = *(const float4*)(arow + k0 + la_k);
            float4 v1 = *(const float4*)(arow + k0 + la_k + 4);
            As[la_k + 0][la_m] = v0.x; As[la_k + 1][la_m] = v0.y;
            As[la_k + 2][la_m] = v0.z; As[la_k + 3][la_m] = v0.w;
            As[la_k + 4][la_m] = v1.x; As[la_k + 5][la_m] = v1.y;
            As[la_k + 6][la_m] = v1.z; As[la_k + 7][la_m] = v1.w;
        } else {
#pragma unroll
            for (int i = 0; i < 8; i++) {
                int k = k0 + la_k + i;
                As[la_k + i][la_m] = (k < K) ? arow[k] : 0.f;
            }
        }
        {
            int k = k0 + lb_k;
            float4 v = make_float4(0.f, 0.f, 0.f, 0.f);
            if (k < K) v = *(const float4*)(bcol + (long)k * ldb);
            *(float4*)&Bs[lb_k][lb_n] = v;
        }
        __syncthreads();
#pragma unroll
        for (int kk = 0; kk < 16; kk++) {
            float4 a0 = *(const float4*)&As[kk][tm * 8];
            float4 a1 = *(const float4*)&As[kk][tm * 8 + 4];
            float4 b4 = *(const float4*)&Bs[kk][tn * 4];
            float av[8] = {a0.x, a0.y, a0.z, a0.w, a1.x, a1.y, a1.z, a1.w};
            float bv[4] = {b4.x, b4.y, b4.z, b4.w};
#pragma unroll
            for (int i = 0; i < 8; i++)
#pragma unroll
                for (int j = 0; j < 4; j++) acc[i][j] += av[i] * bv[j];
        }
        __syncthreads();
    }

    const int gcol = col0 + tn * 4;
    float4 bv4 = *(const float4*)(biasb + gcol);
#pragma unroll
    for (int i = 0; i < 8; i++) {
        int grow = row0 + tm * 8 + i;
        float4 o;
        o.x = acc[i][0] + bv4.x; o.y = acc[i][1] + bv4.y;
        o.z = acc[i][2] + bv4.z; o.w = acc[i][3] + bv4.w;
        if (EPI == 1) {
            o.x = gelu_exact(o.x); o.y = gelu_exact(o.y);
            o.z = gelu_exact(o.z); o.w = gelu_exact(o.w);
        }
        *(float4*)(Cb + (long)grow * ldc + gcol) = o;
    }
}

// ---------------------------------------------------------------------------
// MFMA flash encoder attention — R5: 8 waves x 512 threads, <=2 q-tiles/wave.
// Halves per-wave live state (qh/ql, accO, mrow/lrow) vs the 4-wave version;
// LDS = K(15.4K)+V(13.3K)+Pbuf[8](18.4K) = 47,104 B. launch_bounds(512,2)
// caps at 256 VGPR (cannot force spill). Staging split by wave pairs.
// Q-tile map: qt = wave + 8*i, i < nq; nq = (wave<5) ? 2 : 1  (13 tiles).
// ---------------------------------------------------------------------------
__global__ __launch_bounds__(512, 2) void attn_enc_mfma(
    const u16* __restrict__ qkvh, const u16* __restrict__ qkvl,
    u16* __restrict__ outh, u16* __restrict__ outl)
{
    __shared__ u16 Ksh[96][40];
    __shared__ u16 Ksl[96][40];
    __shared__ u16 Vth[32][104];
    __shared__ u16 Vtl[32][104];
    __shared__ u32 Pbuf[8][16][36];

    const int bh = blockIdx.x;
    const int b = bh / 6, h = bh % 6;
    const int tid = threadIdx.x;
    const int wave = tid >> 6, lane = tid & 63;
    const int lm = lane & 15, quad = lane >> 4;
    const int nq = (wave < 5) ? 2 : 1;

    uint4 qh[2], ql[2];
#pragma unroll
    for (int i = 0; i < 2; i++) {
        if (i < nq) {
            int qt = wave + 8 * i;
            int qrow = qt * 16 + lm; if (qrow > 199) qrow = 199;
            const long off = (long)(b * 200 + qrow) * 576 + h * 32 + quad * 8;
            qh[i] = *(const uint4*)(qkvh + off);
            ql[i] = *(const uint4*)(qkvl + off);
        }
    }

    float mrow[2][4], lrow[2][4];
    f32x4 accO[2][2];
#pragma unroll
    for (int i = 0; i < 2; i++)
#pragma unroll
        for (int r = 0; r < 4; r++) {
            mrow[i][r] = -1e30f; lrow[i][r] = 0.f;
            accO[i][0][r] = 0.f; accO[i][1][r] = 0.f;
        }

    const float scale = 0.17677669529663688f;

#pragma unroll
    for (int ph = 0; ph < 3; ph++) {
        const int base = (ph == 0) ? 0 : (ph == 1) ? 96 : 192;
        const int ntl  = (ph == 2) ? 2 : 6;
        const int nslot = ntl * 16;

        __syncthreads();
        // ---- staging: 8 waves in 4 pairs; 128 lanes per plane ----
        {
            const int wid2 = wave >> 1;                    // 0..3
            const int sub  = ((wave & 1) << 6) | lane;     // 0..127
            if (wid2 < 2) {
                // K plane: pair 0 = hi, pair 1 = lo. nslot keys x 4 uint4.
                const u16* src = (wid2 == 1) ? qkvl : qkvh;
                u16* dst = (wid2 == 1) ? &Ksl[0][0] : &Ksh[0][0];
#pragma unroll
                for (int rep = 0; rep < 3; rep++) {
                    const int idx = rep * 128 + sub;
                    if (idx < nslot * 4) {
                        const int key = idx >> 2, ch = idx & 3;
                        const int gk = base + key;
                        const bool valid = gk < 200;
                        const long roff = (long)(b * 200 + (valid ? gk : 0)) * 576
                                          + h * 32 + 192 + ch * 8;
                        uint4 v = valid ? *(const uint4*)(src + roff)
                                        : make_uint4(0, 0, 0, 0);
                        *(uint4*)(dst + key * 40 + ch * 8) = v;
                    }
                }
            } else {
                // V plane transpose: pair 2 = hi, pair 3 = lo.
                const u16* src = (wid2 == 3) ? qkvl : qkvh;
                u16* dst = (wid2 == 3) ? &Vtl[0][0] : &Vth[0][0];
#pragma unroll
                for (int rep = 0; rep < 2; rep++) {
                    const int idx = rep * 128 + sub;
                    if (idx < nslot * 2) {
                        const int key = idx >> 1, hf = idx & 1;
                        const int gk = base + key;
                        const bool valid = gk < 200;
                        const long roff = (long)(b * 200 + (valid ? gk : 0)) * 576
                                          + h * 32 + 384 + hf * 16;
                        uint4 v0 = valid ? *(const uint4*)(src + roff)
                                         : make_uint4(0, 0, 0, 0);
                        uint4 v1 = valid ? *(const uint4*)(src + roff + 8)
                                         : make_uint4(0, 0, 0, 0);
                        const u16* p0 = (const u16*)&v0;
                        const u16* p1 = (const u16*)&v1;
#pragma unroll
                        for (int j = 0; j < 8; j++) {
                            dst[(hf * 16 + j) * 104 + key]     = p0[j];
                            dst[(hf * 16 + 8 + j) * 104 + key] = p1[j];
                        }
                    }
                }
            }
        }
        __syncthreads();

#pragma unroll
        for (int i = 0; i < 2; i++) {
            if (i >= nq) continue;
            const bf16x8 qhf = *(const bf16x8*)&qh[i];
            const bf16x8 qlf = *(const bf16x8*)&ql[i];
            float s[6][4];
#pragma unroll
            for (int ni = 0; ni < 6; ni++) {
                if (ni >= ntl) continue;
                bf16x8 kh8 = *(const bf16x8*)&Ksh[ni * 16 + lm][quad * 8];
                bf16x8 kl8 = *(const bf16x8*)&Ksl[ni * 16 + lm][quad * 8];
                f32x4 c = {0.f, 0.f, 0.f, 0.f};
                c = mfma_bf16(qhf, kh8, c);
                c = mfma_bf16(qhf, kl8, c);
                c = mfma_bf16(qlf, kh8, c);
                const bool masked = (base + ni * 16 + lm) >= 200;
#pragma unroll
                for (int r = 0; r < 4; r++)
                    s[ni][r] = masked ? -1e30f : c[r] * scale;
            }
            float fac[4];
#pragma unroll
            for (int r = 0; r < 4; r++) {
                float pm = s[0][r];
#pragma unroll
                for (int ni = 1; ni < 6; ni++)
                    if (ni < ntl) pm = fmaxf(pm, s[ni][r]);
                pm = fmaxf(pm, __shfl_xor(pm, 1, 64));
                pm = fmaxf(pm, __shfl_xor(pm, 2, 64));
                pm = fmaxf(pm, __shfl_xor(pm, 4, 64));
                pm = fmaxf(pm, __shfl_xor(pm, 8, 64));
                const float mn = fmaxf(mrow[i][r], pm);
                fac[r] = __expf(mrow[i][r] - mn);
                mrow[i][r] = mn;
                float ps = 0.f;
#pragma unroll
                for (int ni = 0; ni < 6; ni++) {
                    if (ni >= ntl) continue;
                    float e = __expf(s[ni][r] - mn);
                    s[ni][r] = e;
                    ps += e;
                }
                ps += __shfl_xor(ps, 1, 64);
                ps += __shfl_xor(ps, 2, 64);
                ps += __shfl_xor(ps, 4, 64);
                ps += __shfl_xor(ps, 8, 64);
                lrow[i][r] = lrow[i][r] * fac[r] + ps;
                accO[i][0][r] *= fac[r];
                accO[i][1][r] *= fac[r];
            }
            // P handoff streamed per 32-key chunk through the small Pbuf.
#pragma unroll
            for (int ck = 0; ck < 3; ck++) {
                if (ck >= (ntl >> 1)) continue;
                // WAR guard: this wave's prior Pbuf reads must retire.
                FENCE_LGKM();
#pragma unroll
                for (int tl = 0; tl < 2; tl++) {
#pragma unroll
                    for (int r = 0; r < 4; r++) {
                        Pbuf[wave][quad * 4 + r][tl * 16 + lm] =
                            packpair(s[2 * ck + tl][r]);
                    }
                }
                // RAW guard: cross-lane handoff within the wave.
                FENCE_LGKM();
                uint4 w01 = *(const uint4*)&Pbuf[wave][lm][quad * 8];
                uint4 w23 = *(const uint4*)&Pbuf[wave][lm][quad * 8 + 4];
                uint4 hiu, lou;
                unpack8(w01, w23, hiu, lou);
                const bf16x8 phf = *(const bf16x8*)&hiu;
                const bf16x8 plf = *(const bf16x8*)&lou;
#pragma unroll
                for (int nt = 0; nt < 2; nt++) {
                    bf16x8 vh8 = *(const bf16x8*)&Vth[nt * 16 + lm][ck * 32 + quad * 8];
                    bf16x8 vl8 = *(const bf16x8*)&Vtl[nt * 16 + lm][ck * 32 + quad * 8];
                    accO[i][nt] = mfma_bf16(phf, vh8, accO[i][nt]);
                    accO[i][nt] = mfma_bf16(plf, vh8, accO[i][nt]);
                    accO[i][nt] = mfma_bf16(phf, vl8, accO[i][nt]);
                }
            }
        }
    }

#pragma unroll
    for (int i = 0; i < 2; i++) {
        if (i >= nq) continue;
        const int qt = wave + 8 * i;
#pragma unroll
        for (int r = 0; r < 4; r++) {
            const int qrow = qt * 16 + quad * 4 + r;
            if (qrow >= 200) continue;
            const float inv = 1.f / lrow[i][r];
            const long ob = (long)(b * 200 + qrow) * 192 + h * 32 + lm;
            const float v0 = accO[i][0][r] * inv;
            const float v1 = accO[i][1][r] * inv;
            const u16 h0 = f2bf(v0), h1 = f2bf(v1);
            outh[ob]      = h0;
            outl[ob]      = f2bf(v0 - bf2f(h0));
            outh[ob + 16] = h1;
            outl[ob + 16] = f2bf(v1 - bf2f(h1));
        }
    }
}

// ---------------------------------------------------------------------------
__global__ __launch_bounds__(192) void mean_tokens_pair(
    const u16* __restrict__ hh, const u16* __restrict__ hl, float* __restrict__ qmean)
{
    const int b = blockIdx.x, d = threadIdx.x;
    float s = 0.f;
    for (int r = 0; r < 200; r++) {
        const long idx = ((long)b * 200 + r) * 192 + d;
        s += bf2f(hh[idx]) + bf2f(hl[idx]);
    }
    qmean[b * 192 + d] = s * (1.f / 200.f);
}

// ---------------------------------------------------------------------------
__global__ __launch_bounds__(64) void attn_pool(
    const float* __restrict__ qp, const float* __restrict__ kv,
    float* __restrict__ out)
{
    __shared__ float p[200];
    const int b = blockIdx.x / 6, h = blockIdx.x % 6;
    const int lane = threadIdx.x;

    const float* qrow = qp + b * 192 + h * 32;
    float qr[32];
#pragma unroll
    for (int u = 0; u < 8; u++) {
        float4 t = *(const float4*)(qrow + 4 * u);
        qr[4 * u] = t.x; qr[4 * u + 1] = t.y;
        qr[4 * u + 2] = t.z; qr[4 * u + 3] = t.w;
    }
    const float scale = 0.17677669529663688f;
    const float* kb = kv + (long)(b * 200) * 384 + h * 32;
    float s[4];
    float mymax = -1e30f;
#pragma unroll
    for (int g = 0; g < 4; g++) {
        int j = lane + 64 * g;
        if (j < 200) {
            const float* kr = kb + (long)j * 384;
            float acc = 0.f;
#pragma unroll
            for (int u = 0; u < 8; u++) {
                float4 k4 = *(const float4*)(kr + 4 * u);
                acc += qr[4 * u] * k4.x + qr[4 * u + 1] * k4.y +
                       qr[4 * u + 2] * k4.z + qr[4 * u + 3] * k4.w;
            }
            s[g] = acc * scale;
            mymax = fmaxf(mymax, s[g]);
        } else {
            s[g] = -1e30f;
        }
    }
    float mx = wave_max(mymax);
    float psum = 0.f;
#pragma unroll
    for (int g = 0; g < 4; g++) {
        int j = lane + 64 * g;
        if (j < 200) {
            float e = __expf(s[g] - mx);
            p[j] = e;
            psum += e;
        }
    }
    float tot = wave_sum(psum);
    __syncthreads();
    const int half = lane >> 5, d = lane & 31;
    const float* vb = kv + (long)(b * 200) * 384 + 192 + h * 32 + d;
    float acc = 0.f;
    for (int jj = 0; jj < 100; jj++) {
        int j = half * 100 + jj;
        acc += p[j] * vb[(long)j * 384];
    }
    acc += __shfl_xor(acc, 32, 64);
    acc /= tot;
    if (lane < 32) out[b * 192 + h * 32 + d] = acc;
}

// ---------------------------------------------------------------------------
__global__ __launch_bounds__(64) void classifier_kernel(
    const float* __restrict__ pooled,
    const float* __restrict__ g, const float* __restrict__ bt,
    const float* __restrict__ W1, const float* __restrict__ b1,
    const float* __restrict__ W2, const float* __restrict__ b2,
    const float* __restrict__ W3, const float* __restrict__ b3,
    float* __restrict__ out)
{
    __shared__ float z[192];
    __shared__ float z1[96];
    __shared__ float z2[48];
    const int b = blockIdx.x, lane = threadIdx.x;
    const float* pr = pooled + b * 192;
    float x0 = pr[lane], x1 = pr[lane + 64], x2 = pr[lane + 128];
    float m = wave_sum(x0 + x1 + x2) * (1.f / 192.f);
    float d0 = x0 - m, d1 = x1 - m, d2 = x2 - m;
    float v = wave_sum(d0 * d0 + d1 * d1 + d2 * d2) * (1.f / 192.f);
    float rs = 1.f / sqrtf(v + 1e-5f);
    z[lane]       = d0 * rs * g[lane]       + bt[lane];
    z[lane + 64]  = d1 * rs * g[lane + 64]  + bt[lane + 64];
    z[lane + 128] = d2 * rs * g[lane + 128] + bt[lane + 128];
    __syncthreads();
#pragma unroll
    for (int rep = 0; rep < 2; rep++) {
        int j = lane + rep * 64;
        if (j < 96) {
            float a = b1[j];
            for (int k = 0; k < 192; k++) a += z[k] * W1[k * 96 + j];
            z1[j] = gelu_exact(a);
        }
    }
    __syncthreads();
    if (lane < 48) {
        float a = b2[lane];
        for (int k = 0; k < 96; k++) a += z1[k] * W2[k * 48 + lane];
        z2[lane] = gelu_exact(a);
    }
    __syncthreads();
    if (lane < 2) {
        float a = b3[lane];
        for (int k = 0; k < 48; k++) a += z2[k] * W3[k * 2 + lane];
        out[b * 2 + lane] = a;
    }
}

// ---------------------------------------------------------------------------
extern "C" void kernel_launch(void* const* d_in, const int* in_sizes, int n_in,
                              void* d_out, int out_size, void* d_ws, size_t ws_size,
                              hipStream_t stream)
{
    (void)in_sizes; (void)n_in; (void)out_size; (void)ws_size;

    const float* x         = (const float*)d_in[0];
    const float* roi_W     = (const float*)d_in[1];
    const float* roi_b     = (const float*)d_in[2];
    const float* roi_ln_g  = (const float*)d_in[3];
    const float* roi_ln_b  = (const float*)d_in[4];
    const float* pos_emb   = (const float*)d_in[5];
    const float* enc_Wqkv  = (const float*)d_in[6];
    const float* enc_bqkv  = (const float*)d_in[7];
    const float* enc_Wo    = (const float*)d_in[8];
    const float* enc_bo    = (const float*)d_in[9];
    const float* enc_ln1_g = (const float*)d_in[10];
    const float* enc_ln1_b = (const float*)d_in[11];
    const float* enc_W1    = (const float*)d_in[12];
    const float* enc_b1    = (const float*)d_in[13];
    const float* enc_W2    = (const float*)d_in[14];
    const float* enc_b2    = (const float*)d_in[15];
    const float* enc_ln2_g = (const float*)d_in[16];
    const float* enc_ln2_b = (const float*)d_in[17];
    const float* pool_Wqkv = (const float*)d_in[18];
    const float* pool_bqkv = (const float*)d_in[19];
    const float* pool_Wo   = (const float*)d_in[20];
    const float* pool_bo   = (const float*)d_in[21];
    const float* cls_ln_g  = (const float*)d_in[22];
    const float* cls_ln_b  = (const float*)d_in[23];
    const float* cls_W1    = (const float*)d_in[24];
    const float* cls_b1    = (const float*)d_in[25];
    const float* cls_W2    = (const float*)d_in[26];
    const float* cls_b2    = (const float*)d_in[27];
    const float* cls_W3    = (const float*)d_in[28];
    const float* cls_b3    = (const float*)d_in[29];

    char* ws = (char*)d_ws;
    u16*   hh    = (u16*)(ws);                      // [T,192] hi
    u16*   hl    = (u16*)(ws + 19660800);           // [T,192] lo
    char*  bufA  = ws + 39321600;                   // 117,964,800 B
    float* bufAf = (float*)bufA;
    u16*   xh    = (u16*)bufA;
    u16*   xl    = (u16*)(bufA + 22937600);
    u16*   wth   = (u16*)(bufA + 45875200);
    u16*   wtl   = (u16*)(bufA + 63078400);
    u16*   qkvh  = (u16*)bufA;
    u16*   qkvl  = (u16*)(bufA + 58982400);
    u16*   ffh   = (u16*)bufA;
    u16*   ffl   = (u16*)(bufA + 58982400);
    char*  bufB  = ws + 157286400;
    u16*   bBh   = (u16*)bufB;
    u16*   bBl   = (u16*)(bufB + 19660800);
    float* qmean = (float*)(ws + 196608000);
    float* qp    = qmean + 49152;
    float* pattn = qp + 49152;
    float* pooled= pattn + 49152;
    char*  wts   = ws + 197394432;
    u16* WqkvH = (u16*)(wts);
    u16* WqkvL = (u16*)(wts + 663552);
    u16* Wff1H = (u16*)(wts + 1327104);
    u16* Wff1L = (u16*)(wts + 1990656);
    u16* Wff2H = (u16*)(wts + 2654208);
    u16* Wff2L = (u16*)(wts + 3317760);
    u16* WwoH  = (u16*)(wts + 3981312);
    u16* WwoL  = (u16*)(wts + 4202496);
    u16* WkvH  = (u16*)(wts + 4423680);
    u16* WkvL  = (u16*)(wts + 4571136);

    // ---- weight split/transpose (once per call) ----
    conv_wt<<<dim3(144, 1, 9), 256, 0, stream>>>(enc_Wqkv, WqkvH, WqkvL, 192, 192);
    conv_wt<<<dim3(432, 1, 3), 256, 0, stream>>>(enc_W1, Wff1H, Wff1L, 192, 576);
    conv_wt<<<dim3(432, 1, 3), 256, 0, stream>>>(enc_W2, Wff2H, Wff2L, 576, 192);
    conv_wt<<<dim3(144, 1, 3), 256, 0, stream>>>(enc_Wo, WwoH, WwoL, 192, 192);
    conv_wt<<<dim3(144, 1, 2), 256, 0, stream>>>(pool_Wqkv + 36864, WkvH, WkvL, 192, 192);

    // ---- tokenizer ----
    conv_x<<<44800, 256, 0, stream>>>(x, xh, xl);
    conv_roiw<<<dim3(7, 6, 200), dim3(32, 8), 0, stream>>>(roi_W, wth, wtl);
    tok_mfma<<<dim3(2, 200), 256, 0, stream>>>(
        xh, xl, wth, wtl, roi_b, roi_ln_g, roi_ln_b, pos_emb, hh, hl);

    // ---- encoder layers ----
    for (int i = 0; i < 3; i++) {
        gemm_mfma<3><<<dim3(400, 3), 256, 0, stream>>>(
            hh, hl, WqkvH + (long)i * 110592, WqkvL + (long)i * 110592,
            enc_bqkv + i * 576, nullptr, qkvh, qkvl,
            nullptr, nullptr, nullptr, nullptr, 576, 192);
        attn_enc_mfma<<<1536, 512, 0, stream>>>(qkvh, qkvl, bBh, bBl);
        gemm_mfma<5><<<dim3(400, 1), 256, 0, stream>>>(
            bBh, bBl, WwoH + (long)i * 36864, WwoL + (long)i * 36864,
            enc_bo + i * 192, nullptr, nullptr, nullptr,
            hh, hl, enc_ln1_g + i * 192, enc_ln1_b + i * 192, 192, 192);
        gemm_mfma<2><<<dim3(400, 3), 256, 0, stream>>>(
            hh, hl, Wff1H + (long)i * 110592, Wff1L + (long)i * 110592,
            enc_b1 + i * 576, nullptr, ffh, ffl,
            nullptr, nullptr, nullptr, nullptr, 576, 192);
        gemm_mfma<5><<<dim3(400, 1), 256, 0, stream>>>(
            ffh, ffl, Wff2H + (long)i * 110592, Wff2L + (long)i * 110592,
            enc_b2 + i * 192, nullptr, nullptr, nullptr,
            hh, hl, enc_ln2_g + i * 192, enc_ln2_b + i * 192, 192, 576);
    }

    // ---- pooling ----
    mean_tokens_pair<<<256, 192, 0, stream>>>(hh, hl, qmean);
    gemm_kernel<0><<<dim3(2, 3, 1), 256, 0, stream>>>(
        qmean, 192, 0, pool_Wqkv, 0, pool_bqkv, 0, qp, 192, 0, 256, 192, 192, 192);
    gemm_mfma<0><<<dim3(400, 2), 256, 0, stream>>>(
        hh, hl, WkvH, WkvL, pool_bqkv + 192,
        bufAf, nullptr, nullptr,
        nullptr, nullptr, nullptr, nullptr, 384, 192);
    attn_pool<<<1536, 64, 0, stream>>>(qp, bufAf, pattn);
    gemm_kernel<0><<<dim3(2, 3, 1), 256, 0, stream>>>(
        pattn, 192, 0, pool_Wo, 0, pool_bo, 0, pooled, 192, 0, 256, 192, 192, 192);

    // ---- classifier ----
    classifier_kernel<<<256, 64, 0, stream>>>(
        pooled, cls_ln_g, cls_ln_b,
        cls_W1, cls_b1, cls_W2, cls_b2, cls_W3, cls_b3,
        (float*)d_out);
}

// Round 7
// 1232.486 us; speedup vs baseline: 1.1459x; 1.0994x over previous
//
#include <hip/hip_runtime.h>
#include <math.h>

// B=256, N_ROIS=200, ROI_DIM=199, D=192, H=6, Dh=32, L=3, FF=576, NCLS=2
// T = 51200 tokens.
// R0: fences around Pbuf handoff (race fix). R1: attn LDS 58.4->37.9KB.
// R2/R4/R5 lessons: attn occupancy ~20% is structural (not resource-bound);
// VGPR clamps below natural footprint spill catastrophically. attn stays at
// the R3 4-wave/256-thr form (103us, VGPR 124, no spill).
// R3: GEMM chunk-XOR LDS swizzle (kept).
// R6 (this): GEMMs drop the B-lo plane — bf16 "x2" scheme (ah+al)*bh.
// Error/product rises 2^-18 -> ~2^-9 (x512); measured absmax was 1.49e-8
// vs 8.48e-5 threshold (5700x margin) -> predicted ~7.6e-6, 11x margin.
// Cuts MFMAs 3->2, staging GLLs 10->7, LDS 40->28.7KB per GEMM block.

typedef unsigned short u16;
typedef unsigned int u32;
typedef __attribute__((ext_vector_type(8))) __bf16 bf16x8;
typedef __attribute__((ext_vector_type(4))) float f32x4;

#define GLL16(gp, lp) __builtin_amdgcn_global_load_lds(                 \
    (const __attribute__((address_space(1))) void*)(gp),                \
    (__attribute__((address_space(3))) void*)(lp), 16, 0, 0)

#define FENCE_VM()   do { asm volatile("s_waitcnt vmcnt(0)" ::: "memory");  \
                          __builtin_amdgcn_sched_barrier(0); } while (0)
#define FENCE_LGKM() do { asm volatile("s_waitcnt lgkmcnt(0)" ::: "memory");\
                          __builtin_amdgcn_sched_barrier(0); } while (0)

__device__ __forceinline__ u16 f2bf(float x) {
    u32 u = __float_as_uint(x);
    u = (u + 0x7FFFu + ((u >> 16) & 1u)) >> 16;   // RNE
    return (u16)u;
}
__device__ __forceinline__ float bf2f(u16 h) {
    return __uint_as_float(((u32)h) << 16);
}

__device__ __forceinline__ float gelu_exact(float x) {
    return 0.5f * x * (1.0f + erff(x * 0.7071067811865475f));
}

__device__ __forceinline__ float wave_sum(float v) {
#pragma unroll
    for (int o = 32; o > 0; o >>= 1) v += __shfl_xor(v, o, 64);
    return v;
}
__device__ __forceinline__ float wave_max(float v) {
#pragma unroll
    for (int o = 32; o > 0; o >>= 1) v = fmaxf(v, __shfl_xor(v, o, 64));
    return v;
}
// reduce across the 16 lanes sharing a quad (row of an MFMA C tile)
__device__ __forceinline__ float row_sum16(float v) {
    v += __shfl_xor(v, 1, 64); v += __shfl_xor(v, 2, 64);
    v += __shfl_xor(v, 4, 64); v += __shfl_xor(v, 8, 64);
    return v;
}

__device__ __forceinline__ f32x4 mfma_bf16(bf16x8 a, bf16x8 b, f32x4 c) {
    return __builtin_amdgcn_mfma_f32_16x16x32_bf16(a, b, c, 0, 0, 0);
}

__device__ __forceinline__ void unpack8(uint4 p0, uint4 p1, uint4& hi, uint4& lo) {
    hi.x = __builtin_amdgcn_perm(p0.y, p0.x, 0x07060302u);
    hi.y = __builtin_amdgcn_perm(p0.w, p0.z, 0x07060302u);
    hi.z = __builtin_amdgcn_perm(p1.y, p1.x, 0x07060302u);
    hi.w = __builtin_amdgcn_perm(p1.w, p1.z, 0x07060302u);
    lo.x = __builtin_amdgcn_perm(p0.y, p0.x, 0x05040100u);
    lo.y = __builtin_amdgcn_perm(p0.w, p0.z, 0x05040100u);
    lo.z = __builtin_amdgcn_perm(p1.y, p1.x, 0x05040100u);
    lo.w = __builtin_amdgcn_perm(p1.w, p1.z, 0x05040100u);
}
__device__ __forceinline__ u32 packpair(float x) {
    u32 u = __float_as_uint(x);
    u32 t = (u + 0x7FFFu + ((u >> 16) & 1u)) & 0xFFFF0000u;
    float lo = x - __uint_as_float(t);
    return t | (__float_as_uint(lo) >> 16);
}

// ---------------------------------------------------------------------------
// Weight prep: W fp32 [K,N] (blockIdx.z batches) -> transposed bf16 hi/lo [N][K]
// ---------------------------------------------------------------------------
__global__ void conv_wt(const float* __restrict__ W, u16* __restrict__ oh,
                        u16* __restrict__ ol, int K, int N)
{
    const long z = blockIdx.z;
    const int idx = blockIdx.x * 256 + threadIdx.x;
    if (idx >= K * N) return;
    const int k = idx / N, n = idx - k * N;
    const float x = W[z * K * N + idx];
    const u16 h = f2bf(x);
    const u16 l = f2bf(x - bf2f(h));
    oh[z * (long)K * N + (long)n * K + k] = h;
    ol[z * (long)K * N + (long)n * K + k] = l;
}

// ---------------------------------------------------------------------------
// x [256][39800] fp32 -> xh/xl [200][256][224] u16 (k>=199 -> 0)
// ---------------------------------------------------------------------------
__global__ void conv_x(const float* __restrict__ x,
                       u16* __restrict__ xh, u16* __restrict__ xl)
{
    const long idx = (long)blockIdx.x * 256 + threadIdx.x;
    if (idx >= 200L * 256 * 224) return;
    const int k = (int)(idx % 224);
    const long t = idx / 224;
    const int m = (int)(t % 256);
    const int z = (int)(t / 256);
    const float v = (k < 199) ? x[(long)m * 39800 + z * 199 + k] : 0.f;
    const u16 h = f2bf(v);
    xh[idx] = h;
    xl[idx] = f2bf(v - bf2f(h));
}

// ---------------------------------------------------------------------------
// roi_W [200][199][192] fp32 -> wth/wtl [200][192][224] (LDS-tiled transpose)
// ---------------------------------------------------------------------------
__global__ void conv_roiw(const float* __restrict__ W,
                          u16* __restrict__ oh, u16* __restrict__ ol)
{
    __shared__ float tile[32][33];
    const int z = blockIdx.z;
    const int k0 = blockIdx.x * 32;
    const int n0 = blockIdx.y * 32;
    for (int i = threadIdx.y; i < 32; i += 8) {
        const int k = k0 + i, n = n0 + threadIdx.x;
        tile[i][threadIdx.x] = (k < 199) ? W[((long)z * 199 + k) * 192 + n] : 0.f;
    }
    __syncthreads();
    for (int i = threadIdx.y; i < 32; i += 8) {
        const int n = n0 + i, k = k0 + threadIdx.x;
        const float v = tile[threadIdx.x][i];
        const u16 h = f2bf(v);
        const long o = ((long)z * 192 + n) * 224 + k;
        oh[o] = h;
        ol[o] = f2bf(v - bf2f(h));
    }
}

// ---------------------------------------------------------------------------
// bf16x2 MFMA GEMM (R6): C = (Ah+Al) * Bh. B-lo plane dropped (error ~2^-9
// per product, covered by 5700x precision margin). Tile 128x192, BK=32,
// 4 waves on M. 48 MFMAs + 7 GLL16s per wave per K-step. LDS 28.7KB.
// LDS chunk-XOR swizzle (R3). EPI 0: fp32 C. EPI 2: gelu pair. EPI 3: pair.
// EPI 5: fused residual+LN in place on Hh/Hl (N must be 192).
// ---------------------------------------------------------------------------
template<int EPI>
__global__ __launch_bounds__(256, 3) void gemm_mfma(
    const u16* __restrict__ Ah, const u16* __restrict__ Al,
    const u16* __restrict__ Bh,
    const float* __restrict__ bias,
    float* __restrict__ C, u16* __restrict__ Ch, u16* __restrict__ Cl,
    u16* __restrict__ Hh, u16* __restrict__ Hl,
    const float* __restrict__ lng, const float* __restrict__ lnb,
    int N, int K)
{
    __shared__ u16 Ash[128][32];
    __shared__ u16 Als[128][32];
    __shared__ u16 Bsh[192][32];

    const int tid = threadIdx.x;
    const int wave = tid >> 6, lane = tid & 63;
    const int lm = lane & 15, quad = lane >> 4;
    const long m0 = (long)blockIdx.x * 128;
    const int n0 = blockIdx.y * 192;
    const int lrow = lane >> 2;
    const int lch  = (((lane & 3) ^ (lrow & 3)) * 8);   // staging swizzle
    const int sq   = (quad ^ (lm & 3)) * 8;             // read swizzle

    const u16* pA0h = Ah + (m0 + wave * 32 +  0 + lrow) * K + lch;
    const u16* pA1h = Ah + (m0 + wave * 32 + 16 + lrow) * K + lch;
    const u16* pA0l = Al + (m0 + wave * 32 +  0 + lrow) * K + lch;
    const u16* pA1l = Al + (m0 + wave * 32 + 16 + lrow) * K + lch;
    const u16* pB0h = Bh + (long)(n0 + wave * 48 +  0 + lrow) * K + lch;
    const u16* pB1h = Bh + (long)(n0 + wave * 48 + 16 + lrow) * K + lch;
    const u16* pB2h = Bh + (long)(n0 + wave * 48 + 32 + lrow) * K + lch;

    auto stage = [&](int k0) {
        GLL16(pA0h + k0, &Ash[wave * 32][0]);
        GLL16(pA1h + k0, &Ash[wave * 32 + 16][0]);
        GLL16(pA0l + k0, &Als[wave * 32][0]);
        GLL16(pA1l + k0, &Als[wave * 32 + 16][0]);
        GLL16(pB0h + k0, &Bsh[wave * 48][0]);
        GLL16(pB1h + k0, &Bsh[wave * 48 + 16][0]);
        GLL16(pB2h + k0, &Bsh[wave * 48 + 32][0]);
    };

    f32x4 acc[2][12];
#pragma unroll
    for (int i = 0; i < 2; i++)
#pragma unroll
        for (int j = 0; j < 12; j++)
#pragma unroll
            for (int r = 0; r < 4; r++) acc[i][j][r] = 0.f;

    const int kt = K >> 5;
    stage(0);
    FENCE_VM();
    __syncthreads();

    for (int t = 0; t < kt; t++) {
        bf16x8 afh[2], afl[2];
#pragma unroll
        for (int mi = 0; mi < 2; mi++) {
            afh[mi] = *(const bf16x8*)&Ash[wave * 32 + mi * 16 + lm][sq];
            afl[mi] = *(const bf16x8*)&Als[wave * 32 + mi * 16 + lm][sq];
        }
#pragma unroll
        for (int g = 0; g < 4; g++) {
            bf16x8 bfh[3];
#pragma unroll
            for (int j = 0; j < 3; j++)
                bfh[j] = *(const bf16x8*)&Bsh[g * 48 + j * 16 + lm][sq];
#pragma unroll
            for (int mi = 0; mi < 2; mi++)
#pragma unroll
                for (int j = 0; j < 3; j++) {
                    const int ni = g * 3 + j;
                    acc[mi][ni] = mfma_bf16(afh[mi], bfh[j], acc[mi][ni]);
                    acc[mi][ni] = mfma_bf16(afl[mi], bfh[j], acc[mi][ni]);
                }
        }
        if (t + 1 < kt) {
            __syncthreads();
            stage((t + 1) << 5);
            FENCE_VM();
            __syncthreads();
        }
    }

    if (EPI == 5) {
        float gv[12], bv2[12], biasv[12];
#pragma unroll
        for (int ni = 0; ni < 12; ni++) {
            const int col = ni * 16 + lm;
            gv[ni] = lng[col]; bv2[ni] = lnb[col]; biasv[ni] = bias[col];
        }
#pragma unroll
        for (int mi = 0; mi < 2; mi++) {
#pragma unroll
            for (int r = 0; r < 4; r++) {
                const long row = m0 + wave * 32 + mi * 16 + quad * 4 + r;
                const long rb = row * 192;
                float vals[12];
                float s = 0.f;
#pragma unroll
                for (int ni = 0; ni < 12; ni++) {
                    const int col = ni * 16 + lm;
                    const float hval = bf2f(Hh[rb + col]) + bf2f(Hl[rb + col]);
                    vals[ni] = acc[mi][ni][r] + biasv[ni] + hval;
                    s += vals[ni];
                }
                const float mean = row_sum16(s) * (1.f / 192.f);
                float ss = 0.f;
#pragma unroll
                for (int ni = 0; ni < 12; ni++) {
                    vals[ni] -= mean;
                    ss += vals[ni] * vals[ni];
                }
                const float var = row_sum16(ss) * (1.f / 192.f);
                const float rsr = 1.f / sqrtf(var + 1e-5f);
#pragma unroll
                for (int ni = 0; ni < 12; ni++) {
                    const int col = ni * 16 + lm;
                    const float y = vals[ni] * rsr * gv[ni] + bv2[ni];
                    const u16 hb = f2bf(y);
                    Hh[rb + col] = hb;
                    Hl[rb + col] = f2bf(y - bf2f(hb));
                }
            }
        }
        return;
    }

#pragma unroll
    for (int mi = 0; mi < 2; mi++) {
        const long rowb = m0 + wave * 32 + mi * 16 + quad * 4;
#pragma unroll
        for (int ni = 0; ni < 12; ni++) {
            const int col = n0 + ni * 16 + lm;
            const float bv = bias[col];
#pragma unroll
            for (int r = 0; r < 4; r++) {
                float v = acc[mi][ni][r] + bv;
                if (EPI == 0) {
                    C[(rowb + r) * N + col] = v;
                } else {
                    if (EPI == 2) v = gelu_exact(v);
                    const u16 h = f2bf(v);
                    Ch[(rowb + r) * N + col] = h;
                    Cl[(rowb + r) * N + col] = f2bf(v - bf2f(h));
                }
            }
        }
    }
}

// ---------------------------------------------------------------------------
// Tokenizer MFMA (R6: same bf16x2 scheme — wt lo plane dropped).
// per-z GEMM [256,224]@[192,224]^T with fused bias+LN+gelu+pos epilogue.
// ---------------------------------------------------------------------------
__global__ __launch_bounds__(256, 3) void tok_mfma(
    const u16* __restrict__ xh, const u16* __restrict__ xl,
    const u16* __restrict__ wth,
    const float* __restrict__ roi_b,
    const float* __restrict__ lng, const float* __restrict__ lnb,
    const float* __restrict__ pos,
    u16* __restrict__ hh, u16* __restrict__ hl)
{
    __shared__ u16 Ash[128][32];
    __shared__ u16 Als[128][32];
    __shared__ u16 Bsh[192][32];

    const int tid = threadIdx.x;
    const int wave = tid >> 6, lane = tid & 63;
    const int lm = lane & 15, quad = lane >> 4;
    const int m0 = blockIdx.x * 128;
    const int z = blockIdx.y;
    const int lrow = lane >> 2;
    const int lch  = (((lane & 3) ^ (lrow & 3)) * 8);
    const int sq   = (quad ^ (lm & 3)) * 8;
    const int K = 224;

    const u16* pA0h = xh + ((long)z * 256 + m0 + wave * 32 +  0 + lrow) * K + lch;
    const u16* pA1h = xh + ((long)z * 256 + m0 + wave * 32 + 16 + lrow) * K + lch;
    const u16* pA0l = xl + ((long)z * 256 + m0 + wave * 32 +  0 + lrow) * K + lch;
    const u16* pA1l = xl + ((long)z * 256 + m0 + wave * 32 + 16 + lrow) * K + lch;
    const u16* pB0h = wth + ((long)z * 192 + wave * 48 +  0 + lrow) * K + lch;
    const u16* pB1h = wth + ((long)z * 192 + wave * 48 + 16 + lrow) * K + lch;
    const u16* pB2h = wth + ((long)z * 192 + wave * 48 + 32 + lrow) * K + lch;

    auto stage = [&](int k0) {
        GLL16(pA0h + k0, &Ash[wave * 32][0]);
        GLL16(pA1h + k0, &Ash[wave * 32 + 16][0]);
        GLL16(pA0l + k0, &Als[wave * 32][0]);
        GLL16(pA1l + k0, &Als[wave * 32 + 16][0]);
        GLL16(pB0h + k0, &Bsh[wave * 48][0]);
        GLL16(pB1h + k0, &Bsh[wave * 48 + 16][0]);
        GLL16(pB2h + k0, &Bsh[wave * 48 + 32][0]);
    };

    f32x4 acc[2][12];
#pragma unroll
    for (int i = 0; i < 2; i++)
#pragma unroll
        for (int j = 0; j < 12; j++)
#pragma unroll
            for (int r = 0; r < 4; r++) acc[i][j][r] = 0.f;

    stage(0);
    FENCE_VM();
    __syncthreads();
    for (int t = 0; t < 7; t++) {
        bf16x8 afh[2], afl[2];
#pragma unroll
        for (int mi = 0; mi < 2; mi++) {
            afh[mi] = *(const bf16x8*)&Ash[wave * 32 + mi * 16 + lm][sq];
            afl[mi] = *(const bf16x8*)&Als[wave * 32 + mi * 16 + lm][sq];
        }
#pragma unroll
        for (int g = 0; g < 4; g++) {
            bf16x8 bfh[3];
#pragma unroll
            for (int j = 0; j < 3; j++)
                bfh[j] = *(const bf16x8*)&Bsh[g * 48 + j * 16 + lm][sq];
#pragma unroll
            for (int mi = 0; mi < 2; mi++)
#pragma unroll
                for (int j = 0; j < 3; j++) {
                    const int ni = g * 3 + j;
                    acc[mi][ni] = mfma_bf16(afh[mi], bfh[j], acc[mi][ni]);
                    acc[mi][ni] = mfma_bf16(afl[mi], bfh[j], acc[mi][ni]);
                }
        }
        if (t + 1 < 7) {
            __syncthreads();
            stage((t + 1) << 5);
            FENCE_VM();
            __syncthreads();
        }
    }

    float gv[12], bv2[12], biasv[12], pv[12];
#pragma unroll
    for (int ni = 0; ni < 12; ni++) {
        const int col = ni * 16 + lm;
        gv[ni]    = lng[z * 192 + col];
        bv2[ni]   = lnb[z * 192 + col];
        biasv[ni] = roi_b[z * 192 + col];
        pv[ni]    = pos[z * 192 + col];
    }
#pragma unroll
    for (int mi = 0; mi < 2; mi++) {
#pragma unroll
        for (int r = 0; r < 4; r++) {
            const int brow = m0 + wave * 32 + mi * 16 + quad * 4 + r;
            float vals[12];
            float s = 0.f;
#pragma unroll
            for (int ni = 0; ni < 12; ni++) {
                vals[ni] = acc[mi][ni][r] + biasv[ni];
                s += vals[ni];
            }
            const float mean = row_sum16(s) * (1.f / 192.f);
            float ss = 0.f;
#pragma unroll
            for (int ni = 0; ni < 12; ni++) {
                vals[ni] -= mean;
                ss += vals[ni] * vals[ni];
            }
            const float var = row_sum16(ss) * (1.f / 192.f);
            const float rsr = 1.f / sqrtf(var + 1e-5f);
            const long ob = ((long)brow * 200 + z) * 192;
#pragma unroll
            for (int ni = 0; ni < 12; ni++) {
                const int col = ni * 16 + lm;
                const float y = gelu_exact(vals[ni] * rsr * gv[ni] + bv2[ni]) + pv[ni];
                const u16 hb = f2bf(y);
                hh[ob + col] = hb;
                hl[ob + col] = f2bf(y - bf2f(hb));
            }
        }
    }
}

// ---------------------------------------------------------------------------
// fp32 GEMM (tiny pool GEMMs). Tile 128x64, BK=16.
// ---------------------------------------------------------------------------
template<int EPI>
__global__ __launch_bounds__(256) void gemm_kernel(
    const float* __restrict__ A, int lda, long strideA,
    const float* __restrict__ Bw, long strideB,
    const float* __restrict__ bias, long strideBias,
    float* __restrict__ C, int ldc, long strideC,
    int M, int N, int K, int ldb)
{
    __shared__ float As[16][132];
    __shared__ float Bs[16][68];

    const int z = blockIdx.z;
    const float* Ab    = A    + (long)z * strideA;
    const float* Bb    = Bw   + (long)z * strideB;
    const float* biasb = bias + (long)z * strideBias;
    float*       Cb    = C    + (long)z * strideC;

    const int row0 = blockIdx.x * 128;
    const int col0 = blockIdx.y * 64;
    const int tid  = threadIdx.x;
    const int tm = tid >> 4;
    const int tn = tid & 15;

    const int la_m = tid >> 1;
    const int la_k = (tid & 1) * 8;
    const int lb_k = tid >> 4;
    const int lb_n = (tid & 15) * 4;

    const float* bcol = Bb + (col0 + lb_n);
    const float* arow = Ab + (long)(row0 + la_m) * lda;
    const bool vecA = ((lda & 3) == 0) &&
                      ((((unsigned long long)(const void*)arow) & 15ull) == 0ull);

    float acc[8][4];
#pragma unroll
    for (int i = 0; i < 8; i++)
#pragma unroll
        for (int j = 0; j < 4; j++) acc[i][j] = 0.f;

    for (int k0 = 0; k0 < K; k0 += 16) {
        if (vecA && (k0 + 16 <= K)) {
            float4 v0 = *(const float4*)(arow + k0 + la_k);
            float4 v1 = *(const float4*)(arow + k0 + la_k + 4);
            As[la_k + 0][la_m] = v0.x; As[la_k + 1][la_m] = v0.y;
            As[la_k + 2][la_m] = v0.z; As[la_k + 3][la_m] = v0.w;
            As[la_k + 4][la_m] = v1.x; As[la_k + 5][la_m] = v1.y;
            As[la_k + 6][la_m] = v1.z; As[la_k + 7][la_m] = v1.w;
        } else {
#pragma unroll
            for (int i = 0; i < 8; i++) {
                int k = k0 + la_k + i;
                As[la_k + i][la_m] = (k < K) ? arow[k] : 0.f;
            }
        }
        {
            int k = k0 + lb_k;
            float4 v = make_float4(0.f, 0.f, 0.f, 0.f);
            if (k < K) v = *(const float4*)(bcol + (long)k * ldb);
            *(float4*)&Bs[lb_k][lb_n] = v;
        }
        __syncthreads();
#pragma unroll
        for (int kk = 0; kk < 16; kk++) {
            float4 a0 = *(const float4*)&As[kk][tm * 8];
            float4 a1 = *(const float4*)&As[kk][tm * 8 + 4];
            float4 b4 = *(const float4*)&Bs[kk][tn * 4];
            float av[8] = {a0.x, a0.y, a0.z, a0.w, a1.x, a1.y, a1.z, a1.w};
            float bv[4] = {b4.x, b4.y, b4.z, b4.w};
#pragma unroll
            for (int i = 0; i < 8; i++)
#pragma unroll
                for (int j = 0; j < 4; j++) acc[i][j] += av[i] * bv[j];
        }
        __syncthreads();
    }

    const int gcol = col0 + tn * 4;
    float4 bv4 = *(const float4*)(biasb + gcol);
#pragma unroll
    for (int i = 0; i < 8; i++) {
        int grow = row0 + tm * 8 + i;
        float4 o;
        o.x = acc[i][0] + bv4.x; o.y = acc[i][1] + bv4.y;
        o.z = acc[i][2] + bv4.z; o.w = acc[i][3] + bv4.w;
        if (EPI == 1) {
            o.x = gelu_exact(o.x); o.y = gelu_exact(o.y);
            o.z = gelu_exact(o.z); o.w = gelu_exact(o.w);
        }
        *(float4*)(Cb + (long)grow * ldc + gcol) = o;
    }
}

// ---------------------------------------------------------------------------
// MFMA flash encoder attention — R3 form (best known: 103us, VGPR 124).
// LDS = K(15.4K) + V(13.3K) + Pbuf(9.2K) = 37,888 B. 4 waves, 256 thr.
// Staging split across waves (w0/w1: K hi/lo uint4; w2/w3: V hi/lo transp).
// P handoff streamed per-32-key chunk, wave-level lgkmcnt fences.
// ---------------------------------------------------------------------------
__global__ __launch_bounds__(256, 2) void attn_enc_mfma(
    const u16* __restrict__ qkvh, const u16* __restrict__ qkvl,
    u16* __restrict__ outh, u16* __restrict__ outl)
{
    __shared__ u16 Ksh[96][40];
    __shared__ u16 Ksl[96][40];
    __shared__ u16 Vth[32][104];
    __shared__ u16 Vtl[32][104];
    __shared__ u32 Pbuf[4][16][36];

    const int bh = blockIdx.x;
    const int b = bh / 6, h = bh % 6;
    const int tid = threadIdx.x;
    const int wave = tid >> 6, lane = tid & 63;
    const int lm = lane & 15, quad = lane >> 4;
    const int nq = (wave == 0) ? 4 : 3;

    uint4 qh[4], ql[4];
#pragma unroll
    for (int i = 0; i < 4; i++) {
        if (i < nq) {
            int qt = wave + 4 * i;
            int qrow = qt * 16 + lm; if (qrow > 199) qrow = 199;
            const long off = (long)(b * 200 + qrow) * 576 + h * 32 + quad * 8;
            qh[i] = *(const uint4*)(qkvh + off);
            ql[i] = *(const uint4*)(qkvl + off);
        }
    }

    float mrow[4][4], lrow[4][4];
    f32x4 accO[4][2];
#pragma unroll
    for (int i = 0; i < 4; i++)
#pragma unroll
        for (int r = 0; r < 4; r++) {
            mrow[i][r] = -1e30f; lrow[i][r] = 0.f;
            accO[i][0][r] = 0.f; accO[i][1][r] = 0.f;
        }

    const float scale = 0.17677669529663688f;

#pragma unroll
    for (int ph = 0; ph < 3; ph++) {
        const int base = (ph == 0) ? 0 : (ph == 1) ? 96 : 192;
        const int ntl  = (ph == 2) ? 2 : 6;
        const int nslot = ntl * 16;

        __syncthreads();
        if (wave < 2) {
            const u16* src = wave ? qkvl : qkvh;
            u16* dst = wave ? &Ksl[0][0] : &Ksh[0][0];
#pragma unroll
            for (int rep = 0; rep < 6; rep++) {
                const int idx = rep * 64 + lane;
                if (idx < nslot * 4) {
                    const int key = idx >> 2, ch = idx & 3;
                    const int gk = base + key;
                    const bool valid = gk < 200;
                    const long roff = (long)(b * 200 + (valid ? gk : 0)) * 576
                                      + h * 32 + 192 + ch * 8;
                    uint4 v = valid ? *(const uint4*)(src + roff)
                                    : make_uint4(0, 0, 0, 0);
                    *(uint4*)(dst + key * 40 + ch * 8) = v;
                }
            }
        } else {
            const u16* src = (wave == 3) ? qkvl : qkvh;
            u16* dst = (wave == 3) ? &Vtl[0][0] : &Vth[0][0];
#pragma unroll
            for (int rep = 0; rep < 3; rep++) {
                const int idx = rep * 64 + lane;
                if (idx < nslot * 2) {
                    const int key = idx >> 1, hf = idx & 1;
                    const int gk = base + key;
                    const bool valid = gk < 200;
                    const long roff = (long)(b * 200 + (valid ? gk : 0)) * 576
                                      + h * 32 + 384 + hf * 16;
                    uint4 v0 = valid ? *(const uint4*)(src + roff)
                                     : make_uint4(0, 0, 0, 0);
                    uint4 v1 = valid ? *(const uint4*)(src + roff + 8)
                                     : make_uint4(0, 0, 0, 0);
                    const u16* p0 = (const u16*)&v0;
                    const u16* p1 = (const u16*)&v1;
#pragma unroll
                    for (int j = 0; j < 8; j++) {
                        dst[(hf * 16 + j) * 104 + key]     = p0[j];
                        dst[(hf * 16 + 8 + j) * 104 + key] = p1[j];
                    }
                }
            }
        }
        __syncthreads();

#pragma unroll
        for (int i = 0; i < 4; i++) {
            if (i >= nq) continue;
            const bf16x8 qhf = *(const bf16x8*)&qh[i];
            const bf16x8 qlf = *(const bf16x8*)&ql[i];
            float s[6][4];
#pragma unroll
            for (int ni = 0; ni < 6; ni++) {
                if (ni >= ntl) continue;
                bf16x8 kh8 = *(const bf16x8*)&Ksh[ni * 16 + lm][quad * 8];
                bf16x8 kl8 = *(const bf16x8*)&Ksl[ni * 16 + lm][quad * 8];
                f32x4 c = {0.f, 0.f, 0.f, 0.f};
                c = mfma_bf16(qhf, kh8, c);
                c = mfma_bf16(qhf, kl8, c);
                c = mfma_bf16(qlf, kh8, c);
                const bool masked = (base + ni * 16 + lm) >= 200;
#pragma unroll
                for (int r = 0; r < 4; r++)
                    s[ni][r] = masked ? -1e30f : c[r] * scale;
            }
            float fac[4];
#pragma unroll
            for (int r = 0; r < 4; r++) {
                float pm = s[0][r];
#pragma unroll
                for (int ni = 1; ni < 6; ni++)
                    if (ni < ntl) pm = fmaxf(pm, s[ni][r]);
                pm = fmaxf(pm, __shfl_xor(pm, 1, 64));
                pm = fmaxf(pm, __shfl_xor(pm, 2, 64));
                pm = fmaxf(pm, __shfl_xor(pm, 4, 64));
                pm = fmaxf(pm, __shfl_xor(pm, 8, 64));
                const float mn = fmaxf(mrow[i][r], pm);
                fac[r] = __expf(mrow[i][r] - mn);
                mrow[i][r] = mn;
                float ps = 0.f;
#pragma unroll
                for (int ni = 0; ni < 6; ni++) {
                    if (ni >= ntl) continue;
                    float e = __expf(s[ni][r] - mn);
                    s[ni][r] = e;
                    ps += e;
                }
                ps += __shfl_xor(ps, 1, 64);
                ps += __shfl_xor(ps, 2, 64);
                ps += __shfl_xor(ps, 4, 64);
                ps += __shfl_xor(ps, 8, 64);
                lrow[i][r] = lrow[i][r] * fac[r] + ps;
                accO[i][0][r] *= fac[r];
                accO[i][1][r] *= fac[r];
            }
            // P handoff streamed per 32-key chunk through the small Pbuf.
#pragma unroll
            for (int ck = 0; ck < 3; ck++) {
                if (ck >= (ntl >> 1)) continue;
                // WAR guard: this wave's prior Pbuf reads must retire.
                FENCE_LGKM();
#pragma unroll
                for (int tl = 0; tl < 2; tl++) {
#pragma unroll
                    for (int r = 0; r < 4; r++) {
                        Pbuf[wave][quad * 4 + r][tl * 16 + lm] =
                            packpair(s[2 * ck + tl][r]);
                    }
                }
                // RAW guard: cross-lane handoff within the wave.
                FENCE_LGKM();
                uint4 w01 = *(const uint4*)&Pbuf[wave][lm][quad * 8];
                uint4 w23 = *(const uint4*)&Pbuf[wave][lm][quad * 8 + 4];
                uint4 hiu, lou;
                unpack8(w01, w23, hiu, lou);
                const bf16x8 phf = *(const bf16x8*)&hiu;
                const bf16x8 plf = *(const bf16x8*)&lou;
#pragma unroll
                for (int nt = 0; nt < 2; nt++) {
                    bf16x8 vh8 = *(const bf16x8*)&Vth[nt * 16 + lm][ck * 32 + quad * 8];
                    bf16x8 vl8 = *(const bf16x8*)&Vtl[nt * 16 + lm][ck * 32 + quad * 8];
                    accO[i][nt] = mfma_bf16(phf, vh8, accO[i][nt]);
                    accO[i][nt] = mfma_bf16(plf, vh8, accO[i][nt]);
                    accO[i][nt] = mfma_bf16(phf, vl8, accO[i][nt]);
                }
            }
        }
    }

#pragma unroll
    for (int i = 0; i < 4; i++) {
        if (i >= nq) continue;
        const int qt = wave + 4 * i;
#pragma unroll
        for (int r = 0; r < 4; r++) {
            const int qrow = qt * 16 + quad * 4 + r;
            if (qrow >= 200) continue;
            const float inv = 1.f / lrow[i][r];
            const long ob = (long)(b * 200 + qrow) * 192 + h * 32 + lm;
            const float v0 = accO[i][0][r] * inv;
            const float v1 = accO[i][1][r] * inv;
            const u16 h0 = f2bf(v0), h1 = f2bf(v1);
            outh[ob]      = h0;
            outl[ob]      = f2bf(v0 - bf2f(h0));
            outh[ob + 16] = h1;
            outl[ob + 16] = f2bf(v1 - bf2f(h1));
        }
    }
}

// ---------------------------------------------------------------------------
__global__ __launch_bounds__(192) void mean_tokens_pair(
    const u16* __restrict__ hh, const u16* __restrict__ hl, float* __restrict__ qmean)
{
    const int b = blockIdx.x, d = threadIdx.x;
    float s = 0.f;
    for (int r = 0; r < 200; r++) {
        const long idx = ((long)b * 200 + r) * 192 + d;
        s += bf2f(hh[idx]) + bf2f(hl[idx]);
    }
    qmean[b * 192 + d] = s * (1.f / 200.f);
}

// ---------------------------------------------------------------------------
__global__ __launch_bounds__(64) void attn_pool(
    const float* __restrict__ qp, const float* __restrict__ kv,
    float* __restrict__ out)
{
    __shared__ float p[200];
    const int b = blockIdx.x / 6, h = blockIdx.x % 6;
    const int lane = threadIdx.x;

    const float* qrow = qp + b * 192 + h * 32;
    float qr[32];
#pragma unroll
    for (int u = 0; u < 8; u++) {
        float4 t = *(const float4*)(qrow + 4 * u);
        qr[4 * u] = t.x; qr[4 * u + 1] = t.y;
        qr[4 * u + 2] = t.z; qr[4 * u + 3] = t.w;
    }
    const float scale = 0.17677669529663688f;
    const float* kb = kv + (long)(b * 200) * 384 + h * 32;
    float s[4];
    float mymax = -1e30f;
#pragma unroll
    for (int g = 0; g < 4; g++) {
        int j = lane + 64 * g;
        if (j < 200) {
            const float* kr = kb + (long)j * 384;
            float acc = 0.f;
#pragma unroll
            for (int u = 0; u < 8; u++) {
                float4 k4 = *(const float4*)(kr + 4 * u);
                acc += qr[4 * u] * k4.x + qr[4 * u + 1] * k4.y +
                       qr[4 * u + 2] * k4.z + qr[4 * u + 3] * k4.w;
            }
            s[g] = acc * scale;
            mymax = fmaxf(mymax, s[g]);
        } else {
            s[g] = -1e30f;
        }
    }
    float mx = wave_max(mymax);
    float psum = 0.f;
#pragma unroll
    for (int g = 0; g < 4; g++) {
        int j = lane + 64 * g;
        if (j < 200) {
            float e = __expf(s[g] - mx);
            p[j] = e;
            psum += e;
        }
    }
    float tot = wave_sum(psum);
    __syncthreads();
    const int half = lane >> 5, d = lane & 31;
    const float* vb = kv + (long)(b * 200) * 384 + 192 + h * 32 + d;
    float acc = 0.f;
    for (int jj = 0; jj < 100; jj++) {
        int j = half * 100 + jj;
        acc += p[j] * vb[(long)j * 384];
    }
    acc += __shfl_xor(acc, 32, 64);
    acc /= tot;
    if (lane < 32) out[b * 192 + h * 32 + d] = acc;
}

// ---------------------------------------------------------------------------
__global__ __launch_bounds__(64) void classifier_kernel(
    const float* __restrict__ pooled,
    const float* __restrict__ g, const float* __restrict__ bt,
    const float* __restrict__ W1, const float* __restrict__ b1,
    const float* __restrict__ W2, const float* __restrict__ b2,
    const float* __restrict__ W3, const float* __restrict__ b3,
    float* __restrict__ out)
{
    __shared__ float z[192];
    __shared__ float z1[96];
    __shared__ float z2[48];
    const int b = blockIdx.x, lane = threadIdx.x;
    const float* pr = pooled + b * 192;
    float x0 = pr[lane], x1 = pr[lane + 64], x2 = pr[lane + 128];
    float m = wave_sum(x0 + x1 + x2) * (1.f / 192.f);
    float d0 = x0 - m, d1 = x1 - m, d2 = x2 - m;
    float v = wave_sum(d0 * d0 + d1 * d1 + d2 * d2) * (1.f / 192.f);
    float rs = 1.f / sqrtf(v + 1e-5f);
    z[lane]       = d0 * rs * g[lane]       + bt[lane];
    z[lane + 64]  = d1 * rs * g[lane + 64]  + bt[lane + 64];
    z[lane + 128] = d2 * rs * g[lane + 128] + bt[lane + 128];
    __syncthreads();
#pragma unroll
    for (int rep = 0; rep < 2; rep++) {
        int j = lane + rep * 64;
        if (j < 96) {
            float a = b1[j];
            for (int k = 0; k < 192; k++) a += z[k] * W1[k * 96 + j];
            z1[j] = gelu_exact(a);
        }
    }
    __syncthreads();
    if (lane < 48) {
        float a = b2[lane];
        for (int k = 0; k < 96; k++) a += z1[k] * W2[k * 48 + lane];
        z2[lane] = gelu_exact(a);
    }
    __syncthreads();
    if (lane < 2) {
        float a = b3[lane];
        for (int k = 0; k < 48; k++) a += z2[k] * W3[k * 2 + lane];
        out[b * 2 + lane] = a;
    }
}

// ---------------------------------------------------------------------------
extern "C" void kernel_launch(void* const* d_in, const int* in_sizes, int n_in,
                              void* d_out, int out_size, void* d_ws, size_t ws_size,
                              hipStream_t stream)
{
    (void)in_sizes; (void)n_in; (void)out_size; (void)ws_size;

    const float* x         = (const float*)d_in[0];
    const float* roi_W     = (const float*)d_in[1];
    const float* roi_b     = (const float*)d_in[2];
    const float* roi_ln_g  = (const float*)d_in[3];
    const float* roi_ln_b  = (const float*)d_in[4];
    const float* pos_emb   = (const float*)d_in[5];
    const float* enc_Wqkv  = (const float*)d_in[6];
    const float* enc_bqkv  = (const float*)d_in[7];
    const float* enc_Wo    = (const float*)d_in[8];
    const float* enc_bo    = (const float*)d_in[9];
    const float* enc_ln1_g = (const float*)d_in[10];
    const float* enc_ln1_b = (const float*)d_in[11];
    const float* enc_W1    = (const float*)d_in[12];
    const float* enc_b1    = (const float*)d_in[13];
    const float* enc_W2    = (const float*)d_in[14];
    const float* enc_b2    = (const float*)d_in[15];
    const float* enc_ln2_g = (const float*)d_in[16];
    const float* enc_ln2_b = (const float*)d_in[17];
    const float* pool_Wqkv = (const float*)d_in[18];
    const float* pool_bqkv = (const float*)d_in[19];
    const float* pool_Wo   = (const float*)d_in[20];
    const float* pool_bo   = (const float*)d_in[21];
    const float* cls_ln_g  = (const float*)d_in[22];
    const float* cls_ln_b  = (const float*)d_in[23];
    const float* cls_W1    = (const float*)d_in[24];
    const float* cls_b1    = (const float*)d_in[25];
    const float* cls_W2    = (const float*)d_in[26];
    const float* cls_b2    = (const float*)d_in[27];
    const float* cls_W3    = (const float*)d_in[28];
    const float* cls_b3    = (const float*)d_in[29];

    char* ws = (char*)d_ws;
    u16*   hh    = (u16*)(ws);                      // [T,192] hi
    u16*   hl    = (u16*)(ws + 19660800);           // [T,192] lo
    char*  bufA  = ws + 39321600;                   // 117,964,800 B
    float* bufAf = (float*)bufA;
    u16*   xh    = (u16*)bufA;
    u16*   xl    = (u16*)(bufA + 22937600);
    u16*   wth   = (u16*)(bufA + 45875200);
    u16*   wtl   = (u16*)(bufA + 63078400);
    u16*   qkvh  = (u16*)bufA;
    u16*   qkvl  = (u16*)(bufA + 58982400);
    u16*   ffh   = (u16*)bufA;
    u16*   ffl   = (u16*)(bufA + 58982400);
    char*  bufB  = ws + 157286400;
    u16*   bBh   = (u16*)bufB;
    u16*   bBl   = (u16*)(bufB + 19660800);
    float* qmean = (float*)(ws + 196608000);
    float* qp    = qmean + 49152;
    float* pattn = qp + 49152;
    float* pooled= pattn + 49152;
    char*  wts   = ws + 197394432;
    u16* WqkvH = (u16*)(wts);
    u16* WqkvL = (u16*)(wts + 663552);
    u16* Wff1H = (u16*)(wts + 1327104);
    u16* Wff1L = (u16*)(wts + 1990656);
    u16* Wff2H = (u16*)(wts + 2654208);
    u16* Wff2L = (u16*)(wts + 3317760);
    u16* WwoH  = (u16*)(wts + 3981312);
    u16* WwoL  = (u16*)(wts + 4202496);
    u16* WkvH  = (u16*)(wts + 4423680);
    u16* WkvL  = (u16*)(wts + 4571136);

    // ---- weight split/transpose (once per call) ----
    conv_wt<<<dim3(144, 1, 9), 256, 0, stream>>>(enc_Wqkv, WqkvH, WqkvL, 192, 192);
    conv_wt<<<dim3(432, 1, 3), 256, 0, stream>>>(enc_W1, Wff1H, Wff1L, 192, 576);
    conv_wt<<<dim3(432, 1, 3), 256, 0, stream>>>(enc_W2, Wff2H, Wff2L, 576, 192);
    conv_wt<<<dim3(144, 1, 3), 256, 0, stream>>>(enc_Wo, WwoH, WwoL, 192, 192);
    conv_wt<<<dim3(144, 1, 2), 256, 0, stream>>>(pool_Wqkv + 36864, WkvH, WkvL, 192, 192);

    // ---- tokenizer ----
    conv_x<<<44800, 256, 0, stream>>>(x, xh, xl);
    conv_roiw<<<dim3(7, 6, 200), dim3(32, 8), 0, stream>>>(roi_W, wth, wtl);
    tok_mfma<<<dim3(2, 200), 256, 0, stream>>>(
        xh, xl, wth, roi_b, roi_ln_g, roi_ln_b, pos_emb, hh, hl);

    // ---- encoder layers ----
    for (int i = 0; i < 3; i++) {
        gemm_mfma<3><<<dim3(400, 3), 256, 0, stream>>>(
            hh, hl, WqkvH + (long)i * 110592,
            enc_bqkv + i * 576, nullptr, qkvh, qkvl,
            nullptr, nullptr, nullptr, nullptr, 576, 192);
        attn_enc_mfma<<<1536, 256, 0, stream>>>(qkvh, qkvl, bBh, bBl);
        gemm_mfma<5><<<dim3(400, 1), 256, 0, stream>>>(
            bBh, bBl, WwoH + (long)i * 36864,
            enc_bo + i * 192, nullptr, nullptr, nullptr,
            hh, hl, enc_ln1_g + i * 192, enc_ln1_b + i * 192, 192, 192);
        gemm_mfma<2><<<dim3(400, 3), 256, 0, stream>>>(
            hh, hl, Wff1H + (long)i * 110592,
            enc_b1 + i * 576, nullptr, ffh, ffl,
            nullptr, nullptr, nullptr, nullptr, 576, 192);
        gemm_mfma<5><<<dim3(400, 1), 256, 0, stream>>>(
            ffh, ffl, Wff2H + (long)i * 110592,
            enc_b2 + i * 192, nullptr, nullptr, nullptr,
            hh, hl, enc_ln2_g + i * 192, enc_ln2_b + i * 192, 192, 576);
    }

    // ---- pooling ----
    mean_tokens_pair<<<256, 192, 0, stream>>>(hh, hl, qmean);
    gemm_kernel<0><<<dim3(2, 3, 1), 256, 0, stream>>>(
        qmean, 192, 0, pool_Wqkv, 0, pool_bqkv, 0, qp, 192, 0, 256, 192, 192, 192);
    gemm_mfma<0><<<dim3(400, 2), 256, 0, stream>>>(
        hh, hl, WkvH, pool_bqkv + 192,
        bufAf, nullptr, nullptr,
        nullptr, nullptr, nullptr, nullptr, 384, 192);
    attn_pool<<<1536, 64, 0, stream>>>(qp, bufAf, pattn);
    gemm_kernel<0><<<dim3(2, 3, 1), 256, 0, stream>>>(
        pattn, 192, 0, pool_Wo, 0, pool_bo, 0, pooled, 192, 0, 256, 192, 192, 192);

    // ---- classifier ----
    classifier_kernel<<<256, 64, 0, stream>>>(
        pooled, cls_ln_g, cls_ln_b,
        cls_W1, cls_b1, cls_W2, cls_b2, cls_W3, cls_b3,
        (float*)d_out);
}

// Round 8
// 1041.420 us; speedup vs baseline: 1.3562x; 1.1835x over previous
//
#include <hip/hip_runtime.h>
#include <math.h>

// B=256, N_ROIS=200, ROI_DIM=199, D=192, H=6, Dh=32, L=3, FF=576, NCLS=2
// T = 51200 tokens.
// R0: fences around Pbuf handoff (race fix). R1: attn LDS 58.4->37.9KB.
// R2/R4/R5: never clamp VGPR below natural footprint; attn occupancy ~20%
// is structural -> attn frozen at R3 4-wave form (103us, VGPR 124).
// R3: GEMM chunk-XOR LDS swizzle (kept).
// R6: dropped B-lo plane in GEMMs -> absmax 1.49e-8 -> 1.53e-5 (threshold
// 8.48e-5), -110us. Error model now calibrated empirically.
// R7 (this): drop A-lo plane too -> pure-bf16 GEMM operands (attention's
// internal bf16x3 math and the fp32-pair residual Hh/Hl stay). Predicted
// absmax ~3e-5 (2.7x margin). MFMAs halve, staging 7->5 GLLs, LDS 20.5KB,
// ff1 out single-plane (-59MB), attn writes only outh, prep kernels strip
// lo planes.

typedef unsigned short u16;
typedef unsigned int u32;
typedef __attribute__((ext_vector_type(8))) __bf16 bf16x8;
typedef __attribute__((ext_vector_type(4))) float f32x4;

#define GLL16(gp, lp) __builtin_amdgcn_global_load_lds(                 \
    (const __attribute__((address_space(1))) void*)(gp),                \
    (__attribute__((address_space(3))) void*)(lp), 16, 0, 0)

#define FENCE_VM()   do { asm volatile("s_waitcnt vmcnt(0)" ::: "memory");  \
                          __builtin_amdgcn_sched_barrier(0); } while (0)
#define FENCE_LGKM() do { asm volatile("s_waitcnt lgkmcnt(0)" ::: "memory");\
                          __builtin_amdgcn_sched_barrier(0); } while (0)

__device__ __forceinline__ u16 f2bf(float x) {
    u32 u = __float_as_uint(x);
    u = (u + 0x7FFFu + ((u >> 16) & 1u)) >> 16;   // RNE
    return (u16)u;
}
__device__ __forceinline__ float bf2f(u16 h) {
    return __uint_as_float(((u32)h) << 16);
}

__device__ __forceinline__ float gelu_exact(float x) {
    return 0.5f * x * (1.0f + erff(x * 0.7071067811865475f));
}

__device__ __forceinline__ float wave_sum(float v) {
#pragma unroll
    for (int o = 32; o > 0; o >>= 1) v += __shfl_xor(v, o, 64);
    return v;
}
__device__ __forceinline__ float wave_max(float v) {
#pragma unroll
    for (int o = 32; o > 0; o >>= 1) v = fmaxf(v, __shfl_xor(v, o, 64));
    return v;
}
// reduce across the 16 lanes sharing a quad (row of an MFMA C tile)
__device__ __forceinline__ float row_sum16(float v) {
    v += __shfl_xor(v, 1, 64); v += __shfl_xor(v, 2, 64);
    v += __shfl_xor(v, 4, 64); v += __shfl_xor(v, 8, 64);
    return v;
}

__device__ __forceinline__ f32x4 mfma_bf16(bf16x8 a, bf16x8 b, f32x4 c) {
    return __builtin_amdgcn_mfma_f32_16x16x32_bf16(a, b, c, 0, 0, 0);
}

__device__ __forceinline__ void unpack8(uint4 p0, uint4 p1, uint4& hi, uint4& lo) {
    hi.x = __builtin_amdgcn_perm(p0.y, p0.x, 0x07060302u);
    hi.y = __builtin_amdgcn_perm(p0.w, p0.z, 0x07060302u);
    hi.z = __builtin_amdgcn_perm(p1.y, p1.x, 0x07060302u);
    hi.w = __builtin_amdgcn_perm(p1.w, p1.z, 0x07060302u);
    lo.x = __builtin_amdgcn_perm(p0.y, p0.x, 0x05040100u);
    lo.y = __builtin_amdgcn_perm(p0.w, p0.z, 0x05040100u);
    lo.z = __builtin_amdgcn_perm(p1.y, p1.x, 0x05040100u);
    lo.w = __builtin_amdgcn_perm(p1.w, p1.z, 0x05040100u);
}
__device__ __forceinline__ u32 packpair(float x) {
    u32 u = __float_as_uint(x);
    u32 t = (u + 0x7FFFu + ((u >> 16) & 1u)) & 0xFFFF0000u;
    float lo = x - __uint_as_float(t);
    return t | (__float_as_uint(lo) >> 16);
}

// ---------------------------------------------------------------------------
// Weight prep: W fp32 [K,N] (blockIdx.z batches) -> transposed bf16 hi [N][K]
// (lo plane dead since R7 — GEMMs are pure bf16 on both operands)
// ---------------------------------------------------------------------------
__global__ void conv_wt(const float* __restrict__ W, u16* __restrict__ oh,
                        int K, int N)
{
    const long z = blockIdx.z;
    const int idx = blockIdx.x * 256 + threadIdx.x;
    if (idx >= K * N) return;
    const int k = idx / N, n = idx - k * N;
    const float x = W[z * K * N + idx];
    oh[z * (long)K * N + (long)n * K + k] = f2bf(x);
}

// ---------------------------------------------------------------------------
// x [256][39800] fp32 -> xh [200][256][224] u16 (k>=199 -> 0)
// ---------------------------------------------------------------------------
__global__ void conv_x(const float* __restrict__ x, u16* __restrict__ xh)
{
    const long idx = (long)blockIdx.x * 256 + threadIdx.x;
    if (idx >= 200L * 256 * 224) return;
    const int k = (int)(idx % 224);
    const long t = idx / 224;
    const int m = (int)(t % 256);
    const int z = (int)(t / 256);
    const float v = (k < 199) ? x[(long)m * 39800 + z * 199 + k] : 0.f;
    xh[idx] = f2bf(v);
}

// ---------------------------------------------------------------------------
// roi_W [200][199][192] fp32 -> wth [200][192][224] (LDS-tiled transpose)
// ---------------------------------------------------------------------------
__global__ void conv_roiw(const float* __restrict__ W, u16* __restrict__ oh)
{
    __shared__ float tile[32][33];
    const int z = blockIdx.z;
    const int k0 = blockIdx.x * 32;
    const int n0 = blockIdx.y * 32;
    for (int i = threadIdx.y; i < 32; i += 8) {
        const int k = k0 + i, n = n0 + threadIdx.x;
        tile[i][threadIdx.x] = (k < 199) ? W[((long)z * 199 + k) * 192 + n] : 0.f;
    }
    __syncthreads();
    for (int i = threadIdx.y; i < 32; i += 8) {
        const int n = n0 + i, k = k0 + threadIdx.x;
        const float v = tile[threadIdx.x][i];
        oh[((long)z * 192 + n) * 224 + k] = f2bf(v);
    }
}

// ---------------------------------------------------------------------------
// Pure-bf16 MFMA GEMM (R7): C = Ah * Bh. Tile 128x192, BK=32, 4 waves on M.
// 24 MFMAs + 5 GLL16s per wave per K-step. LDS 20.5KB.
// LDS chunk-XOR swizzle (R3). EPI 0: fp32 C. EPI 2: gelu hi-only.
// EPI 3: hi/lo pair (qkv -> attention needs both planes).
// EPI 5: fused residual+LN in place on Hh/Hl (N must be 192).
// ---------------------------------------------------------------------------
template<int EPI>
__global__ __launch_bounds__(256, 3) void gemm_mfma(
    const u16* __restrict__ Ah,
    const u16* __restrict__ Bh,
    const float* __restrict__ bias,
    float* __restrict__ C, u16* __restrict__ Ch, u16* __restrict__ Cl,
    u16* __restrict__ Hh, u16* __restrict__ Hl,
    const float* __restrict__ lng, const float* __restrict__ lnb,
    int N, int K)
{
    __shared__ u16 Ash[128][32];
    __shared__ u16 Bsh[192][32];

    const int tid = threadIdx.x;
    const int wave = tid >> 6, lane = tid & 63;
    const int lm = lane & 15, quad = lane >> 4;
    const long m0 = (long)blockIdx.x * 128;
    const int n0 = blockIdx.y * 192;
    const int lrow = lane >> 2;
    const int lch  = (((lane & 3) ^ (lrow & 3)) * 8);   // staging swizzle
    const int sq   = (quad ^ (lm & 3)) * 8;             // read swizzle

    const u16* pA0h = Ah + (m0 + wave * 32 +  0 + lrow) * K + lch;
    const u16* pA1h = Ah + (m0 + wave * 32 + 16 + lrow) * K + lch;
    const u16* pB0h = Bh + (long)(n0 + wave * 48 +  0 + lrow) * K + lch;
    const u16* pB1h = Bh + (long)(n0 + wave * 48 + 16 + lrow) * K + lch;
    const u16* pB2h = Bh + (long)(n0 + wave * 48 + 32 + lrow) * K + lch;

    auto stage = [&](int k0) {
        GLL16(pA0h + k0, &Ash[wave * 32][0]);
        GLL16(pA1h + k0, &Ash[wave * 32 + 16][0]);
        GLL16(pB0h + k0, &Bsh[wave * 48][0]);
        GLL16(pB1h + k0, &Bsh[wave * 48 + 16][0]);
        GLL16(pB2h + k0, &Bsh[wave * 48 + 32][0]);
    };

    f32x4 acc[2][12];
#pragma unroll
    for (int i = 0; i < 2; i++)
#pragma unroll
        for (int j = 0; j < 12; j++)
#pragma unroll
            for (int r = 0; r < 4; r++) acc[i][j][r] = 0.f;

    const int kt = K >> 5;
    stage(0);
    FENCE_VM();
    __syncthreads();

    for (int t = 0; t < kt; t++) {
        bf16x8 afh[2];
#pragma unroll
        for (int mi = 0; mi < 2; mi++)
            afh[mi] = *(const bf16x8*)&Ash[wave * 32 + mi * 16 + lm][sq];
#pragma unroll
        for (int g = 0; g < 4; g++) {
            bf16x8 bfh[3];
#pragma unroll
            for (int j = 0; j < 3; j++)
                bfh[j] = *(const bf16x8*)&Bsh[g * 48 + j * 16 + lm][sq];
#pragma unroll
            for (int mi = 0; mi < 2; mi++)
#pragma unroll
                for (int j = 0; j < 3; j++) {
                    const int ni = g * 3 + j;
                    acc[mi][ni] = mfma_bf16(afh[mi], bfh[j], acc[mi][ni]);
                }
        }
        if (t + 1 < kt) {
            __syncthreads();
            stage((t + 1) << 5);
            FENCE_VM();
            __syncthreads();
        }
    }

    if (EPI == 5) {
        float gv[12], bv2[12], biasv[12];
#pragma unroll
        for (int ni = 0; ni < 12; ni++) {
            const int col = ni * 16 + lm;
            gv[ni] = lng[col]; bv2[ni] = lnb[col]; biasv[ni] = bias[col];
        }
#pragma unroll
        for (int mi = 0; mi < 2; mi++) {
#pragma unroll
            for (int r = 0; r < 4; r++) {
                const long row = m0 + wave * 32 + mi * 16 + quad * 4 + r;
                const long rb = row * 192;
                float vals[12];
                float s = 0.f;
#pragma unroll
                for (int ni = 0; ni < 12; ni++) {
                    const int col = ni * 16 + lm;
                    const float hval = bf2f(Hh[rb + col]) + bf2f(Hl[rb + col]);
                    vals[ni] = acc[mi][ni][r] + biasv[ni] + hval;
                    s += vals[ni];
                }
                const float mean = row_sum16(s) * (1.f / 192.f);
                float ss = 0.f;
#pragma unroll
                for (int ni = 0; ni < 12; ni++) {
                    vals[ni] -= mean;
                    ss += vals[ni] * vals[ni];
                }
                const float var = row_sum16(ss) * (1.f / 192.f);
                const float rsr = 1.f / sqrtf(var + 1e-5f);
#pragma unroll
                for (int ni = 0; ni < 12; ni++) {
                    const int col = ni * 16 + lm;
                    const float y = vals[ni] * rsr * gv[ni] + bv2[ni];
                    const u16 hb = f2bf(y);
                    Hh[rb + col] = hb;
                    Hl[rb + col] = f2bf(y - bf2f(hb));
                }
            }
        }
        return;
    }

#pragma unroll
    for (int mi = 0; mi < 2; mi++) {
        const long rowb = m0 + wave * 32 + mi * 16 + quad * 4;
#pragma unroll
        for (int ni = 0; ni < 12; ni++) {
            const int col = n0 + ni * 16 + lm;
            const float bv = bias[col];
#pragma unroll
            for (int r = 0; r < 4; r++) {
                float v = acc[mi][ni][r] + bv;
                if (EPI == 0) {
                    C[(rowb + r) * N + col] = v;
                } else {
                    if (EPI == 2) v = gelu_exact(v);
                    const u16 h = f2bf(v);
                    Ch[(rowb + r) * N + col] = h;
                    if (EPI == 3)
                        Cl[(rowb + r) * N + col] = f2bf(v - bf2f(h));
                }
            }
        }
    }
}

// ---------------------------------------------------------------------------
// Tokenizer MFMA (R7: pure bf16 A and B).
// per-z GEMM [256,224]@[192,224]^T with fused bias+LN+gelu+pos epilogue.
// ---------------------------------------------------------------------------
__global__ __launch_bounds__(256, 3) void tok_mfma(
    const u16* __restrict__ xh,
    const u16* __restrict__ wth,
    const float* __restrict__ roi_b,
    const float* __restrict__ lng, const float* __restrict__ lnb,
    const float* __restrict__ pos,
    u16* __restrict__ hh, u16* __restrict__ hl)
{
    __shared__ u16 Ash[128][32];
    __shared__ u16 Bsh[192][32];

    const int tid = threadIdx.x;
    const int wave = tid >> 6, lane = tid & 63;
    const int lm = lane & 15, quad = lane >> 4;
    const int m0 = blockIdx.x * 128;
    const int z = blockIdx.y;
    const int lrow = lane >> 2;
    const int lch  = (((lane & 3) ^ (lrow & 3)) * 8);
    const int sq   = (quad ^ (lm & 3)) * 8;
    const int K = 224;

    const u16* pA0h = xh + ((long)z * 256 + m0 + wave * 32 +  0 + lrow) * K + lch;
    const u16* pA1h = xh + ((long)z * 256 + m0 + wave * 32 + 16 + lrow) * K + lch;
    const u16* pB0h = wth + ((long)z * 192 + wave * 48 +  0 + lrow) * K + lch;
    const u16* pB1h = wth + ((long)z * 192 + wave * 48 + 16 + lrow) * K + lch;
    const u16* pB2h = wth + ((long)z * 192 + wave * 48 + 32 + lrow) * K + lch;

    auto stage = [&](int k0) {
        GLL16(pA0h + k0, &Ash[wave * 32][0]);
        GLL16(pA1h + k0, &Ash[wave * 32 + 16][0]);
        GLL16(pB0h + k0, &Bsh[wave * 48][0]);
        GLL16(pB1h + k0, &Bsh[wave * 48 + 16][0]);
        GLL16(pB2h + k0, &Bsh[wave * 48 + 32][0]);
    };

    f32x4 acc[2][12];
#pragma unroll
    for (int i = 0; i < 2; i++)
#pragma unroll
        for (int j = 0; j < 12; j++)
#pragma unroll
            for (int r = 0; r < 4; r++) acc[i][j][r] = 0.f;

    stage(0);
    FENCE_VM();
    __syncthreads();
    for (int t = 0; t < 7; t++) {
        bf16x8 afh[2];
#pragma unroll
        for (int mi = 0; mi < 2; mi++)
            afh[mi] = *(const bf16x8*)&Ash[wave * 32 + mi * 16 + lm][sq];
#pragma unroll
        for (int g = 0; g < 4; g++) {
            bf16x8 bfh[3];
#pragma unroll
            for (int j = 0; j < 3; j++)
                bfh[j] = *(const bf16x8*)&Bsh[g * 48 + j * 16 + lm][sq];
#pragma unroll
            for (int mi = 0; mi < 2; mi++)
#pragma unroll
                for (int j = 0; j < 3; j++) {
                    const int ni = g * 3 + j;
                    acc[mi][ni] = mfma_bf16(afh[mi], bfh[j], acc[mi][ni]);
                }
        }
        if (t + 1 < 7) {
            __syncthreads();
            stage((t + 1) << 5);
            FENCE_VM();
            __syncthreads();
        }
    }

    float gv[12], bv2[12], biasv[12], pv[12];
#pragma unroll
    for (int ni = 0; ni < 12; ni++) {
        const int col = ni * 16 + lm;
        gv[ni]    = lng[z * 192 + col];
        bv2[ni]   = lnb[z * 192 + col];
        biasv[ni] = roi_b[z * 192 + col];
        pv[ni]    = pos[z * 192 + col];
    }
#pragma unroll
    for (int mi = 0; mi < 2; mi++) {
#pragma unroll
        for (int r = 0; r < 4; r++) {
            const int brow = m0 + wave * 32 + mi * 16 + quad * 4 + r;
            float vals[12];
            float s = 0.f;
#pragma unroll
            for (int ni = 0; ni < 12; ni++) {
                vals[ni] = acc[mi][ni][r] + biasv[ni];
                s += vals[ni];
            }
            const float mean = row_sum16(s) * (1.f / 192.f);
            float ss = 0.f;
#pragma unroll
            for (int ni = 0; ni < 12; ni++) {
                vals[ni] -= mean;
                ss += vals[ni] * vals[ni];
            }
            const float var = row_sum16(ss) * (1.f / 192.f);
            const float rsr = 1.f / sqrtf(var + 1e-5f);
            const long ob = ((long)brow * 200 + z) * 192;
#pragma unroll
            for (int ni = 0; ni < 12; ni++) {
                const int col = ni * 16 + lm;
                const float y = gelu_exact(vals[ni] * rsr * gv[ni] + bv2[ni]) + pv[ni];
                const u16 hb = f2bf(y);
                hh[ob + col] = hb;
                hl[ob + col] = f2bf(y - bf2f(hb));
            }
        }
    }
}

// ---------------------------------------------------------------------------
// fp32 GEMM (tiny pool GEMMs). Tile 128x64, BK=16.
// ---------------------------------------------------------------------------
template<int EPI>
__global__ __launch_bounds__(256) void gemm_kernel(
    const float* __restrict__ A, int lda, long strideA,
    const float* __restrict__ Bw, long strideB,
    const float* __restrict__ bias, long strideBias,
    float* __restrict__ C, int ldc, long strideC,
    int M, int N, int K, int ldb)
{
    __shared__ float As[16][132];
    __shared__ float Bs[16][68];

    const int z = blockIdx.z;
    const float* Ab    = A    + (long)z * strideA;
    const float* Bb    = Bw   + (long)z * strideB;
    const float* biasb = bias + (long)z * strideBias;
    float*       Cb    = C    + (long)z * strideC;

    const int row0 = blockIdx.x * 128;
    const int col0 = blockIdx.y * 64;
    const int tid  = threadIdx.x;
    const int tm = tid >> 4;
    const int tn = tid & 15;

    const int la_m = tid >> 1;
    const int la_k = (tid & 1) * 8;
    const int lb_k = tid >> 4;
    const int lb_n = (tid & 15) * 4;

    const float* bcol = Bb + (col0 + lb_n);
    const float* arow = Ab + (long)(row0 + la_m) * lda;
    const bool vecA = ((lda & 3) == 0) &&
                      ((((unsigned long long)(const void*)arow) & 15ull) == 0ull);

    float acc[8][4];
#pragma unroll
    for (int i = 0; i < 8; i++)
#pragma unroll
        for (int j = 0; j < 4; j++) acc[i][j] = 0.f;

    for (int k0 = 0; k0 < K; k0 += 16) {
        if (vecA && (k0 + 16 <= K)) {
            float4 v0 = *(const float4*)(arow + k0 + la_k);
            float4 v1 = *(const float4*)(arow + k0 + la_k + 4);
            As[la_k + 0][la_m] = v0.x; As[la_k + 1][la_m] = v0.y;
            As[la_k + 2][la_m] = v0.z; As[la_k + 3][la_m] = v0.w;
            As[la_k + 4][la_m] = v1.x; As[la_k + 5][la_m] = v1.y;
            As[la_k + 6][la_m] = v1.z; As[la_k + 7][la_m] = v1.w;
        } else {
#pragma unroll
            for (int i = 0; i < 8; i++) {
                int k = k0 + la_k + i;
                As[la_k + i][la_m] = (k < K) ? arow[k] : 0.f;
            }
        }
        {
            int k = k0 + lb_k;
            float4 v = make_float4(0.f, 0.f, 0.f, 0.f);
            if (k < K) v = *(const float4*)(bcol + (long)k * ldb);
            *(float4*)&Bs[lb_k][lb_n] = v;
        }
        __syncthreads();
#pragma unroll
        for (int kk = 0; kk < 16; kk++) {
            float4 a0 = *(const float4*)&As[kk][tm * 8];
            float4 a1 = *(const float4*)&As[kk][tm * 8 + 4];
            float4 b4 = *(const float4*)&Bs[kk][tn * 4];
            float av[8] = {a0.x, a0.y, a0.z, a0.w, a1.x, a1.y, a1.z, a1.w};
            float bv[4] = {b4.x, b4.y, b4.z, b4.w};
#pragma unroll
            for (int i = 0; i < 8; i++)
#pragma unroll
                for (int j = 0; j < 4; j++) acc[i][j] += av[i] * bv[j];
        }
        __syncthreads();
    }

    const int gcol = col0 + tn * 4;
    float4 bv4 = *(const float4*)(biasb + gcol);
#pragma unroll
    for (int i = 0; i < 8; i++) {
        int grow = row0 + tm * 8 + i;
        float4 o;
        o.x = acc[i][0] + bv4.x; o.y = acc[i][1] + bv4.y;
        o.z = acc[i][2] + bv4.z; o.w = acc[i][3] + bv4.w;
        if (EPI == 1) {
            o.x = gelu_exact(o.x); o.y = gelu_exact(o.y);
            o.z = gelu_exact(o.z); o.w = gelu_exact(o.w);
        }
        *(float4*)(Cb + (long)grow * ldc + gcol) = o;
    }
}

// ---------------------------------------------------------------------------
// MFMA flash encoder attention — R3 form (best known: 103us, VGPR 124).
// LDS = K(15.4K) + V(13.3K) + Pbuf(9.2K) = 37,888 B. 4 waves, 256 thr.
// Internal math stays bf16x3 on qkv pairs. R7: output only outh (the lo
// plane is no longer consumed by the pure-bf16 Wo GEMM).
// ---------------------------------------------------------------------------
__global__ __launch_bounds__(256, 2) void attn_enc_mfma(
    const u16* __restrict__ qkvh, const u16* __restrict__ qkvl,
    u16* __restrict__ outh)
{
    __shared__ u16 Ksh[96][40];
    __shared__ u16 Ksl[96][40];
    __shared__ u16 Vth[32][104];
    __shared__ u16 Vtl[32][104];
    __shared__ u32 Pbuf[4][16][36];

    const int bh = blockIdx.x;
    const int b = bh / 6, h = bh % 6;
    const int tid = threadIdx.x;
    const int wave = tid >> 6, lane = tid & 63;
    const int lm = lane & 15, quad = lane >> 4;
    const int nq = (wave == 0) ? 4 : 3;

    uint4 qh[4], ql[4];
#pragma unroll
    for (int i = 0; i < 4; i++) {
        if (i < nq) {
            int qt = wave + 4 * i;
            int qrow = qt * 16 + lm; if (qrow > 199) qrow = 199;
            const long off = (long)(b * 200 + qrow) * 576 + h * 32 + quad * 8;
            qh[i] = *(const uint4*)(qkvh + off);
            ql[i] = *(const uint4*)(qkvl + off);
        }
    }

    float mrow[4][4], lrow[4][4];
    f32x4 accO[4][2];
#pragma unroll
    for (int i = 0; i < 4; i++)
#pragma unroll
        for (int r = 0; r < 4; r++) {
            mrow[i][r] = -1e30f; lrow[i][r] = 0.f;
            accO[i][0][r] = 0.f; accO[i][1][r] = 0.f;
        }

    const float scale = 0.17677669529663688f;

#pragma unroll
    for (int ph = 0; ph < 3; ph++) {
        const int base = (ph == 0) ? 0 : (ph == 1) ? 96 : 192;
        const int ntl  = (ph == 2) ? 2 : 6;
        const int nslot = ntl * 16;

        __syncthreads();
        if (wave < 2) {
            const u16* src = wave ? qkvl : qkvh;
            u16* dst = wave ? &Ksl[0][0] : &Ksh[0][0];
#pragma unroll
            for (int rep = 0; rep < 6; rep++) {
                const int idx = rep * 64 + lane;
                if (idx < nslot * 4) {
                    const int key = idx >> 2, ch = idx & 3;
                    const int gk = base + key;
                    const bool valid = gk < 200;
                    const long roff = (long)(b * 200 + (valid ? gk : 0)) * 576
                                      + h * 32 + 192 + ch * 8;
                    uint4 v = valid ? *(const uint4*)(src + roff)
                                    : make_uint4(0, 0, 0, 0);
                    *(uint4*)(dst + key * 40 + ch * 8) = v;
                }
            }
        } else {
            const u16* src = (wave == 3) ? qkvl : qkvh;
            u16* dst = (wave == 3) ? &Vtl[0][0] : &Vth[0][0];
#pragma unroll
            for (int rep = 0; rep < 3; rep++) {
                const int idx = rep * 64 + lane;
                if (idx < nslot * 2) {
                    const int key = idx >> 1, hf = idx & 1;
                    const int gk = base + key;
                    const bool valid = gk < 200;
                    const long roff = (long)(b * 200 + (valid ? gk : 0)) * 576
                                      + h * 32 + 384 + hf * 16;
                    uint4 v0 = valid ? *(const uint4*)(src + roff)
                                     : make_uint4(0, 0, 0, 0);
                    uint4 v1 = valid ? *(const uint4*)(src + roff + 8)
                                     : make_uint4(0, 0, 0, 0);
                    const u16* p0 = (const u16*)&v0;
                    const u16* p1 = (const u16*)&v1;
#pragma unroll
                    for (int j = 0; j < 8; j++) {
                        dst[(hf * 16 + j) * 104 + key]     = p0[j];
                        dst[(hf * 16 + 8 + j) * 104 + key] = p1[j];
                    }
                }
            }
        }
        __syncthreads();

#pragma unroll
        for (int i = 0; i < 4; i++) {
            if (i >= nq) continue;
            const bf16x8 qhf = *(const bf16x8*)&qh[i];
            const bf16x8 qlf = *(const bf16x8*)&ql[i];
            float s[6][4];
#pragma unroll
            for (int ni = 0; ni < 6; ni++) {
                if (ni >= ntl) continue;
                bf16x8 kh8 = *(const bf16x8*)&Ksh[ni * 16 + lm][quad * 8];
                bf16x8 kl8 = *(const bf16x8*)&Ksl[ni * 16 + lm][quad * 8];
                f32x4 c = {0.f, 0.f, 0.f, 0.f};
                c = mfma_bf16(qhf, kh8, c);
                c = mfma_bf16(qhf, kl8, c);
                c = mfma_bf16(qlf, kh8, c);
                const bool masked = (base + ni * 16 + lm) >= 200;
#pragma unroll
                for (int r = 0; r < 4; r++)
                    s[ni][r] = masked ? -1e30f : c[r] * scale;
            }
            float fac[4];
#pragma unroll
            for (int r = 0; r < 4; r++) {
                float pm = s[0][r];
#pragma unroll
                for (int ni = 1; ni < 6; ni++)
                    if (ni < ntl) pm = fmaxf(pm, s[ni][r]);
                pm = fmaxf(pm, __shfl_xor(pm, 1, 64));
                pm = fmaxf(pm, __shfl_xor(pm, 2, 64));
                pm = fmaxf(pm, __shfl_xor(pm, 4, 64));
                pm = fmaxf(pm, __shfl_xor(pm, 8, 64));
                const float mn = fmaxf(mrow[i][r], pm);
                fac[r] = __expf(mrow[i][r] - mn);
                mrow[i][r] = mn;
                float ps = 0.f;
#pragma unroll
                for (int ni = 0; ni < 6; ni++) {
                    if (ni >= ntl) continue;
                    float e = __expf(s[ni][r] - mn);
                    s[ni][r] = e;
                    ps += e;
                }
                ps += __shfl_xor(ps, 1, 64);
                ps += __shfl_xor(ps, 2, 64);
                ps += __shfl_xor(ps, 4, 64);
                ps += __shfl_xor(ps, 8, 64);
                lrow[i][r] = lrow[i][r] * fac[r] + ps;
                accO[i][0][r] *= fac[r];
                accO[i][1][r] *= fac[r];
            }
            // P handoff streamed per 32-key chunk through the small Pbuf.
#pragma unroll
            for (int ck = 0; ck < 3; ck++) {
                if (ck >= (ntl >> 1)) continue;
                // WAR guard: this wave's prior Pbuf reads must retire.
                FENCE_LGKM();
#pragma unroll
                for (int tl = 0; tl < 2; tl++) {
#pragma unroll
                    for (int r = 0; r < 4; r++) {
                        Pbuf[wave][quad * 4 + r][tl * 16 + lm] =
                            packpair(s[2 * ck + tl][r]);
                    }
                }
                // RAW guard: cross-lane handoff within the wave.
                FENCE_LGKM();
                uint4 w01 = *(const uint4*)&Pbuf[wave][lm][quad * 8];
                uint4 w23 = *(const uint4*)&Pbuf[wave][lm][quad * 8 + 4];
                uint4 hiu, lou;
                unpack8(w01, w23, hiu, lou);
                const bf16x8 phf = *(const bf16x8*)&hiu;
                const bf16x8 plf = *(const bf16x8*)&lou;
#pragma unroll
                for (int nt = 0; nt < 2; nt++) {
                    bf16x8 vh8 = *(const bf16x8*)&Vth[nt * 16 + lm][ck * 32 + quad * 8];
                    bf16x8 vl8 = *(const bf16x8*)&Vtl[nt * 16 + lm][ck * 32 + quad * 8];
                    accO[i][nt] = mfma_bf16(phf, vh8, accO[i][nt]);
                    accO[i][nt] = mfma_bf16(plf, vh8, accO[i][nt]);
                    accO[i][nt] = mfma_bf16(phf, vl8, accO[i][nt]);
                }
            }
        }
    }

#pragma unroll
    for (int i = 0; i < 4; i++) {
        if (i >= nq) continue;
        const int qt = wave + 4 * i;
#pragma unroll
        for (int r = 0; r < 4; r++) {
            const int qrow = qt * 16 + quad * 4 + r;
            if (qrow >= 200) continue;
            const float inv = 1.f / lrow[i][r];
            const long ob = (long)(b * 200 + qrow) * 192 + h * 32 + lm;
            outh[ob]      = f2bf(accO[i][0][r] * inv);
            outh[ob + 16] = f2bf(accO[i][1][r] * inv);
        }
    }
}

// ---------------------------------------------------------------------------
__global__ __launch_bounds__(192) void mean_tokens_pair(
    const u16* __restrict__ hh, const u16* __restrict__ hl, float* __restrict__ qmean)
{
    const int b = blockIdx.x, d = threadIdx.x;
    float s = 0.f;
    for (int r = 0; r < 200; r++) {
        const long idx = ((long)b * 200 + r) * 192 + d;
        s += bf2f(hh[idx]) + bf2f(hl[idx]);
    }
    qmean[b * 192 + d] = s * (1.f / 200.f);
}

// ---------------------------------------------------------------------------
__global__ __launch_bounds__(64) void attn_pool(
    const float* __restrict__ qp, const float* __restrict__ kv,
    float* __restrict__ out)
{
    __shared__ float p[200];
    const int b = blockIdx.x / 6, h = blockIdx.x % 6;
    const int lane = threadIdx.x;

    const float* qrow = qp + b * 192 + h * 32;
    float qr[32];
#pragma unroll
    for (int u = 0; u < 8; u++) {
        float4 t = *(const float4*)(qrow + 4 * u);
        qr[4 * u] = t.x; qr[4 * u + 1] = t.y;
        qr[4 * u + 2] = t.z; qr[4 * u + 3] = t.w;
    }
    const float scale = 0.17677669529663688f;
    const float* kb = kv + (long)(b * 200) * 384 + h * 32;
    float s[4];
    float mymax = -1e30f;
#pragma unroll
    for (int g = 0; g < 4; g++) {
        int j = lane + 64 * g;
        if (j < 200) {
            const float* kr = kb + (long)j * 384;
            float acc = 0.f;
#pragma unroll
            for (int u = 0; u < 8; u++) {
                float4 k4 = *(const float4*)(kr + 4 * u);
                acc += qr[4 * u] * k4.x + qr[4 * u + 1] * k4.y +
                       qr[4 * u + 2] * k4.z + qr[4 * u + 3] * k4.w;
            }
            s[g] = acc * scale;
            mymax = fmaxf(mymax, s[g]);
        } else {
            s[g] = -1e30f;
        }
    }
    float mx = wave_max(mymax);
    float psum = 0.f;
#pragma unroll
    for (int g = 0; g < 4; g++) {
        int j = lane + 64 * g;
        if (j < 200) {
            float e = __expf(s[g] - mx);
            p[j] = e;
            psum += e;
        }
    }
    float tot = wave_sum(psum);
    __syncthreads();
    const int half = lane >> 5, d = lane & 31;
    const float* vb = kv + (long)(b * 200) * 384 + 192 + h * 32 + d;
    float acc = 0.f;
    for (int jj = 0; jj < 100; jj++) {
        int j = half * 100 + jj;
        acc += p[j] * vb[(long)j * 384];
    }
    acc += __shfl_xor(acc, 32, 64);
    acc /= tot;
    if (lane < 32) out[b * 192 + h * 32 + d] = acc;
}

// ---------------------------------------------------------------------------
__global__ __launch_bounds__(64) void classifier_kernel(
    const float* __restrict__ pooled,
    const float* __restrict__ g, const float* __restrict__ bt,
    const float* __restrict__ W1, const float* __restrict__ b1,
    const float* __restrict__ W2, const float* __restrict__ b2,
    const float* __restrict__ W3, const float* __restrict__ b3,
    float* __restrict__ out)
{
    __shared__ float z[192];
    __shared__ float z1[96];
    __shared__ float z2[48];
    const int b = blockIdx.x, lane = threadIdx.x;
    const float* pr = pooled + b * 192;
    float x0 = pr[lane], x1 = pr[lane + 64], x2 = pr[lane + 128];
    float m = wave_sum(x0 + x1 + x2) * (1.f / 192.f);
    float d0 = x0 - m, d1 = x1 - m, d2 = x2 - m;
    float v = wave_sum(d0 * d0 + d1 * d1 + d2 * d2) * (1.f / 192.f);
    float rs = 1.f / sqrtf(v + 1e-5f);
    z[lane]       = d0 * rs * g[lane]       + bt[lane];
    z[lane + 64]  = d1 * rs * g[lane + 64]  + bt[lane + 64];
    z[lane + 128] = d2 * rs * g[lane + 128] + bt[lane + 128];
    __syncthreads();
#pragma unroll
    for (int rep = 0; rep < 2; rep++) {
        int j = lane + rep * 64;
        if (j < 96) {
            float a = b1[j];
            for (int k = 0; k < 192; k++) a += z[k] * W1[k * 96 + j];
            z1[j] = gelu_exact(a);
        }
    }
    __syncthreads();
    if (lane < 48) {
        float a = b2[lane];
        for (int k = 0; k < 96; k++) a += z1[k] * W2[k * 48 + lane];
        z2[lane] = gelu_exact(a);
    }
    __syncthreads();
    if (lane < 2) {
        float a = b3[lane];
        for (int k = 0; k < 48; k++) a += z2[k] * W3[k * 2 + lane];
        out[b * 2 + lane] = a;
    }
}

// ---------------------------------------------------------------------------
extern "C" void kernel_launch(void* const* d_in, const int* in_sizes, int n_in,
                              void* d_out, int out_size, void* d_ws, size_t ws_size,
                              hipStream_t stream)
{
    (void)in_sizes; (void)n_in; (void)out_size; (void)ws_size;

    const float* x         = (const float*)d_in[0];
    const float* roi_W     = (const float*)d_in[1];
    const float* roi_b     = (const float*)d_in[2];
    const float* roi_ln_g  = (const float*)d_in[3];
    const float* roi_ln_b  = (const float*)d_in[4];
    const float* pos_emb   = (const float*)d_in[5];
    const float* enc_Wqkv  = (const float*)d_in[6];
    const float* enc_bqkv  = (const float*)d_in[7];
    const float* enc_Wo    = (const float*)d_in[8];
    const float* enc_bo    = (const float*)d_in[9];
    const float* enc_ln1_g = (const float*)d_in[10];
    const float* enc_ln1_b = (const float*)d_in[11];
    const float* enc_W1    = (const float*)d_in[12];
    const float* enc_b1    = (const float*)d_in[13];
    const float* enc_W2    = (const float*)d_in[14];
    const float* enc_b2    = (const float*)d_in[15];
    const float* enc_ln2_g = (const float*)d_in[16];
    const float* enc_ln2_b = (const float*)d_in[17];
    const float* pool_Wqkv = (const float*)d_in[18];
    const float* pool_bqkv = (const float*)d_in[19];
    const float* pool_Wo   = (const float*)d_in[20];
    const float* pool_bo   = (const float*)d_in[21];
    const float* cls_ln_g  = (const float*)d_in[22];
    const float* cls_ln_b  = (const float*)d_in[23];
    const float* cls_W1    = (const float*)d_in[24];
    const float* cls_b1    = (const float*)d_in[25];
    const float* cls_W2    = (const float*)d_in[26];
    const float* cls_b2    = (const float*)d_in[27];
    const float* cls_W3    = (const float*)d_in[28];
    const float* cls_b3    = (const float*)d_in[29];

    char* ws = (char*)d_ws;
    u16*   hh    = (u16*)(ws);                      // [T,192] hi
    u16*   hl    = (u16*)(ws + 19660800);           // [T,192] lo
    char*  bufA  = ws + 39321600;                   // 117,964,800 B
    float* bufAf = (float*)bufA;
    // tokenizer-phase layout of bufA:
    u16*   xh    = (u16*)bufA;                      // 200*256*224 u16
    u16*   wth   = (u16*)(bufA + 45875200);         // 200*192*224 u16
    // encoder-phase layout of bufA:
    u16*   qkvh  = (u16*)bufA;                      // [T,576] hi
    u16*   qkvl  = (u16*)(bufA + 58982400);         // [T,576] lo
    u16*   ffh   = (u16*)bufA;                      // [T,576] (hi only)
    char*  bufB  = ws + 157286400;
    u16*   bBh   = (u16*)bufB;                      // attn out (hi only)
    float* qmean = (float*)(ws + 196608000);
    float* qp    = qmean + 49152;
    float* pattn = qp + 49152;
    float* pooled= pattn + 49152;
    char*  wts   = ws + 197394432;
    u16* WqkvH = (u16*)(wts);
    u16* Wff1H = (u16*)(wts + 1327104);
    u16* Wff2H = (u16*)(wts + 2654208);
    u16* WwoH  = (u16*)(wts + 3981312);
    u16* WkvH  = (u16*)(wts + 4423680);

    // ---- weight split/transpose (once per call, hi plane only) ----
    conv_wt<<<dim3(144, 1, 9), 256, 0, stream>>>(enc_Wqkv, WqkvH, 192, 192);
    conv_wt<<<dim3(432, 1, 3), 256, 0, stream>>>(enc_W1, Wff1H, 192, 576);
    conv_wt<<<dim3(432, 1, 3), 256, 0, stream>>>(enc_W2, Wff2H, 576, 192);
    conv_wt<<<dim3(144, 1, 3), 256, 0, stream>>>(enc_Wo, WwoH, 192, 192);
    conv_wt<<<dim3(144, 1, 2), 256, 0, stream>>>(pool_Wqkv + 36864, WkvH, 192, 192);

    // ---- tokenizer ----
    conv_x<<<44800, 256, 0, stream>>>(x, xh);
    conv_roiw<<<dim3(7, 6, 200), dim3(32, 8), 0, stream>>>(roi_W, wth);
    tok_mfma<<<dim3(2, 200), 256, 0, stream>>>(
        xh, wth, roi_b, roi_ln_g, roi_ln_b, pos_emb, hh, hl);

    // ---- encoder layers ----
    for (int i = 0; i < 3; i++) {
        // qkv: pair output (attention needs hi+lo)
        gemm_mfma<3><<<dim3(400, 3), 256, 0, stream>>>(
            hh, WqkvH + (long)i * 110592,
            enc_bqkv + i * 576, nullptr, qkvh, qkvl,
            nullptr, nullptr, nullptr, nullptr, 576, 192);
        attn_enc_mfma<<<1536, 256, 0, stream>>>(qkvh, qkvl, bBh);
        // Wo + fused residual LN1 (in place on hh/hl)
        gemm_mfma<5><<<dim3(400, 1), 256, 0, stream>>>(
            bBh, WwoH + (long)i * 36864,
            enc_bo + i * 192, nullptr, nullptr, nullptr,
            hh, hl, enc_ln1_g + i * 192, enc_ln1_b + i * 192, 192, 192);
        // ff1 gelu -> ffh (hi only)
        gemm_mfma<2><<<dim3(400, 3), 256, 0, stream>>>(
            hh, Wff1H + (long)i * 110592,
            enc_b1 + i * 576, nullptr, ffh, nullptr,
            nullptr, nullptr, nullptr, nullptr, 576, 192);
        // ff2 + fused residual LN2 (in place on hh/hl)
        gemm_mfma<5><<<dim3(400, 1), 256, 0, stream>>>(
            ffh, Wff2H + (long)i * 110592,
            enc_b2 + i * 192, nullptr, nullptr, nullptr,
            hh, hl, enc_ln2_g + i * 192, enc_ln2_b + i * 192, 192, 576);
    }

    // ---- pooling ----
    mean_tokens_pair<<<256, 192, 0, stream>>>(hh, hl, qmean);
    gemm_kernel<0><<<dim3(2, 3, 1), 256, 0, stream>>>(
        qmean, 192, 0, pool_Wqkv, 0, pool_bqkv, 0, qp, 192, 0, 256, 192, 192, 192);
    gemm_mfma<0><<<dim3(400, 2), 256, 0, stream>>>(
        hh, WkvH, pool_bqkv + 192,
        bufAf, nullptr, nullptr,
        nullptr, nullptr, nullptr, nullptr, 384, 192);
    attn_pool<<<1536, 64, 0, stream>>>(qp, bufAf, pattn);
    gemm_kernel<0><<<dim3(2, 3, 1), 256, 0, stream>>>(
        pattn, 192, 0, pool_Wo, 0, pool_bo, 0, pooled, 192, 0, 256, 192, 192, 192);

    // ---- classifier ----
    classifier_kernel<<<256, 64, 0, stream>>>(
        pooled, cls_ln_g, cls_ln_b,
        cls_W1, cls_b1, cls_W2, cls_b2, cls_W3, cls_b3,
        (float*)d_out);
}

// Round 9
// 941.685 us; speedup vs baseline: 1.4998x; 1.1059x over previous
//
#include <hip/hip_runtime.h>
#include <math.h>

// B=256, N_ROIS=200, ROI_DIM=199, D=192, H=6, Dh=32, L=3, FF=576, NCLS=2
// T = 51200 tokens.
// R0: fences around Pbuf handoff (race fix). R1: attn LDS shrink.
// R2/R4/R5: never clamp VGPR below natural footprint; attn occupancy ~20%
// is structural. R3: GEMM chunk-XOR LDS swizzle (kept).
// R6: dropped B-lo in GEMMs (absmax 1.5e-5, threshold 8.5e-5). R7: dropped
// A-lo too (pure-bf16 GEMMs) — absmax UNCHANGED at 2^-16: the residual
// bf16-pair floor dominates; GEMM bf16 errors attenuate ~100x via LN +
// 0.02-scale classifier. 1041us.
// R8 (this): attn internals pure-bf16 too — QK 1 MFMA (was 3), PV 1 MFMA
// (was 3), K/V staged hi-plane only (FETCH ~halves), P handoff as plain
// u16 bf16 Pbuf (no packpair/perm), LDS 37.9->19.5KB. qkv GEMM outputs
// hi only (EPI 3 = plain hi store; qkvl dead). Predicted absmax 2-4e-5.

typedef unsigned short u16;
typedef unsigned int u32;
typedef __attribute__((ext_vector_type(8))) __bf16 bf16x8;
typedef __attribute__((ext_vector_type(4))) float f32x4;

#define GLL16(gp, lp) __builtin_amdgcn_global_load_lds(                 \
    (const __attribute__((address_space(1))) void*)(gp),                \
    (__attribute__((address_space(3))) void*)(lp), 16, 0, 0)

#define FENCE_VM()   do { asm volatile("s_waitcnt vmcnt(0)" ::: "memory");  \
                          __builtin_amdgcn_sched_barrier(0); } while (0)
#define FENCE_LGKM() do { asm volatile("s_waitcnt lgkmcnt(0)" ::: "memory");\
                          __builtin_amdgcn_sched_barrier(0); } while (0)

__device__ __forceinline__ u16 f2bf(float x) {
    u32 u = __float_as_uint(x);
    u = (u + 0x7FFFu + ((u >> 16) & 1u)) >> 16;   // RNE
    return (u16)u;
}
__device__ __forceinline__ float bf2f(u16 h) {
    return __uint_as_float(((u32)h) << 16);
}

__device__ __forceinline__ float gelu_exact(float x) {
    return 0.5f * x * (1.0f + erff(x * 0.7071067811865475f));
}

__device__ __forceinline__ float wave_sum(float v) {
#pragma unroll
    for (int o = 32; o > 0; o >>= 1) v += __shfl_xor(v, o, 64);
    return v;
}
__device__ __forceinline__ float wave_max(float v) {
#pragma unroll
    for (int o = 32; o > 0; o >>= 1) v = fmaxf(v, __shfl_xor(v, o, 64));
    return v;
}
// reduce across the 16 lanes sharing a quad (row of an MFMA C tile)
__device__ __forceinline__ float row_sum16(float v) {
    v += __shfl_xor(v, 1, 64); v += __shfl_xor(v, 2, 64);
    v += __shfl_xor(v, 4, 64); v += __shfl_xor(v, 8, 64);
    return v;
}

__device__ __forceinline__ f32x4 mfma_bf16(bf16x8 a, bf16x8 b, f32x4 c) {
    return __builtin_amdgcn_mfma_f32_16x16x32_bf16(a, b, c, 0, 0, 0);
}

// ---------------------------------------------------------------------------
// Weight prep: W fp32 [K,N] (blockIdx.z batches) -> transposed bf16 hi [N][K]
// ---------------------------------------------------------------------------
__global__ void conv_wt(const float* __restrict__ W, u16* __restrict__ oh,
                        int K, int N)
{
    const long z = blockIdx.z;
    const int idx = blockIdx.x * 256 + threadIdx.x;
    if (idx >= K * N) return;
    const int k = idx / N, n = idx - k * N;
    const float x = W[z * K * N + idx];
    oh[z * (long)K * N + (long)n * K + k] = f2bf(x);
}

// ---------------------------------------------------------------------------
// x [256][39800] fp32 -> xh [200][256][224] u16 (k>=199 -> 0)
// ---------------------------------------------------------------------------
__global__ void conv_x(const float* __restrict__ x, u16* __restrict__ xh)
{
    const long idx = (long)blockIdx.x * 256 + threadIdx.x;
    if (idx >= 200L * 256 * 224) return;
    const int k = (int)(idx % 224);
    const long t = idx / 224;
    const int m = (int)(t % 256);
    const int z = (int)(t / 256);
    const float v = (k < 199) ? x[(long)m * 39800 + z * 199 + k] : 0.f;
    xh[idx] = f2bf(v);
}

// ---------------------------------------------------------------------------
// roi_W [200][199][192] fp32 -> wth [200][192][224] (LDS-tiled transpose)
// ---------------------------------------------------------------------------
__global__ void conv_roiw(const float* __restrict__ W, u16* __restrict__ oh)
{
    __shared__ float tile[32][33];
    const int z = blockIdx.z;
    const int k0 = blockIdx.x * 32;
    const int n0 = blockIdx.y * 32;
    for (int i = threadIdx.y; i < 32; i += 8) {
        const int k = k0 + i, n = n0 + threadIdx.x;
        tile[i][threadIdx.x] = (k < 199) ? W[((long)z * 199 + k) * 192 + n] : 0.f;
    }
    __syncthreads();
    for (int i = threadIdx.y; i < 32; i += 8) {
        const int n = n0 + i, k = k0 + threadIdx.x;
        const float v = tile[threadIdx.x][i];
        oh[((long)z * 192 + n) * 224 + k] = f2bf(v);
    }
}

// ---------------------------------------------------------------------------
// Pure-bf16 MFMA GEMM: C = Ah * Bh. Tile 128x192, BK=32, 4 waves on M.
// LDS chunk-XOR swizzle (R3). EPI 0: fp32 C. EPI 2: gelu, hi store.
// EPI 3: plain hi store. EPI 5: fused residual+LN in place on Hh/Hl.
// ---------------------------------------------------------------------------
template<int EPI>
__global__ __launch_bounds__(256, 3) void gemm_mfma(
    const u16* __restrict__ Ah,
    const u16* __restrict__ Bh,
    const float* __restrict__ bias,
    float* __restrict__ C, u16* __restrict__ Ch,
    u16* __restrict__ Hh, u16* __restrict__ Hl,
    const float* __restrict__ lng, const float* __restrict__ lnb,
    int N, int K)
{
    __shared__ u16 Ash[128][32];
    __shared__ u16 Bsh[192][32];

    const int tid = threadIdx.x;
    const int wave = tid >> 6, lane = tid & 63;
    const int lm = lane & 15, quad = lane >> 4;
    const long m0 = (long)blockIdx.x * 128;
    const int n0 = blockIdx.y * 192;
    const int lrow = lane >> 2;
    const int lch  = (((lane & 3) ^ (lrow & 3)) * 8);   // staging swizzle
    const int sq   = (quad ^ (lm & 3)) * 8;             // read swizzle

    const u16* pA0h = Ah + (m0 + wave * 32 +  0 + lrow) * K + lch;
    const u16* pA1h = Ah + (m0 + wave * 32 + 16 + lrow) * K + lch;
    const u16* pB0h = Bh + (long)(n0 + wave * 48 +  0 + lrow) * K + lch;
    const u16* pB1h = Bh + (long)(n0 + wave * 48 + 16 + lrow) * K + lch;
    const u16* pB2h = Bh + (long)(n0 + wave * 48 + 32 + lrow) * K + lch;

    auto stage = [&](int k0) {
        GLL16(pA0h + k0, &Ash[wave * 32][0]);
        GLL16(pA1h + k0, &Ash[wave * 32 + 16][0]);
        GLL16(pB0h + k0, &Bsh[wave * 48][0]);
        GLL16(pB1h + k0, &Bsh[wave * 48 + 16][0]);
        GLL16(pB2h + k0, &Bsh[wave * 48 + 32][0]);
    };

    f32x4 acc[2][12];
#pragma unroll
    for (int i = 0; i < 2; i++)
#pragma unroll
        for (int j = 0; j < 12; j++)
#pragma unroll
            for (int r = 0; r < 4; r++) acc[i][j][r] = 0.f;

    const int kt = K >> 5;
    stage(0);
    FENCE_VM();
    __syncthreads();

    for (int t = 0; t < kt; t++) {
        bf16x8 afh[2];
#pragma unroll
        for (int mi = 0; mi < 2; mi++)
            afh[mi] = *(const bf16x8*)&Ash[wave * 32 + mi * 16 + lm][sq];
#pragma unroll
        for (int g = 0; g < 4; g++) {
            bf16x8 bfh[3];
#pragma unroll
            for (int j = 0; j < 3; j++)
                bfh[j] = *(const bf16x8*)&Bsh[g * 48 + j * 16 + lm][sq];
#pragma unroll
            for (int mi = 0; mi < 2; mi++)
#pragma unroll
                for (int j = 0; j < 3; j++) {
                    const int ni = g * 3 + j;
                    acc[mi][ni] = mfma_bf16(afh[mi], bfh[j], acc[mi][ni]);
                }
        }
        if (t + 1 < kt) {
            __syncthreads();
            stage((t + 1) << 5);
            FENCE_VM();
            __syncthreads();
        }
    }

    if (EPI == 5) {
        float gv[12], bv2[12], biasv[12];
#pragma unroll
        for (int ni = 0; ni < 12; ni++) {
            const int col = ni * 16 + lm;
            gv[ni] = lng[col]; bv2[ni] = lnb[col]; biasv[ni] = bias[col];
        }
#pragma unroll
        for (int mi = 0; mi < 2; mi++) {
#pragma unroll
            for (int r = 0; r < 4; r++) {
                const long row = m0 + wave * 32 + mi * 16 + quad * 4 + r;
                const long rb = row * 192;
                float vals[12];
                float s = 0.f;
#pragma unroll
                for (int ni = 0; ni < 12; ni++) {
                    const int col = ni * 16 + lm;
                    const float hval = bf2f(Hh[rb + col]) + bf2f(Hl[rb + col]);
                    vals[ni] = acc[mi][ni][r] + biasv[ni] + hval;
                    s += vals[ni];
                }
                const float mean = row_sum16(s) * (1.f / 192.f);
                float ss = 0.f;
#pragma unroll
                for (int ni = 0; ni < 12; ni++) {
                    vals[ni] -= mean;
                    ss += vals[ni] * vals[ni];
                }
                const float var = row_sum16(ss) * (1.f / 192.f);
                const float rsr = 1.f / sqrtf(var + 1e-5f);
#pragma unroll
                for (int ni = 0; ni < 12; ni++) {
                    const int col = ni * 16 + lm;
                    const float y = vals[ni] * rsr * gv[ni] + bv2[ni];
                    const u16 hb = f2bf(y);
                    Hh[rb + col] = hb;
                    Hl[rb + col] = f2bf(y - bf2f(hb));
                }
            }
        }
        return;
    }

#pragma unroll
    for (int mi = 0; mi < 2; mi++) {
        const long rowb = m0 + wave * 32 + mi * 16 + quad * 4;
#pragma unroll
        for (int ni = 0; ni < 12; ni++) {
            const int col = n0 + ni * 16 + lm;
            const float bv = bias[col];
#pragma unroll
            for (int r = 0; r < 4; r++) {
                float v = acc[mi][ni][r] + bv;
                if (EPI == 0) {
                    C[(rowb + r) * N + col] = v;
                } else {
                    if (EPI == 2) v = gelu_exact(v);
                    Ch[(rowb + r) * N + col] = f2bf(v);
                }
            }
        }
    }
}

// ---------------------------------------------------------------------------
// Tokenizer MFMA (pure bf16 A and B).
// per-z GEMM [256,224]@[192,224]^T with fused bias+LN+gelu+pos epilogue.
// ---------------------------------------------------------------------------
__global__ __launch_bounds__(256, 3) void tok_mfma(
    const u16* __restrict__ xh,
    const u16* __restrict__ wth,
    const float* __restrict__ roi_b,
    const float* __restrict__ lng, const float* __restrict__ lnb,
    const float* __restrict__ pos,
    u16* __restrict__ hh, u16* __restrict__ hl)
{
    __shared__ u16 Ash[128][32];
    __shared__ u16 Bsh[192][32];

    const int tid = threadIdx.x;
    const int wave = tid >> 6, lane = tid & 63;
    const int lm = lane & 15, quad = lane >> 4;
    const int m0 = blockIdx.x * 128;
    const int z = blockIdx.y;
    const int lrow = lane >> 2;
    const int lch  = (((lane & 3) ^ (lrow & 3)) * 8);
    const int sq   = (quad ^ (lm & 3)) * 8;
    const int K = 224;

    const u16* pA0h = xh + ((long)z * 256 + m0 + wave * 32 +  0 + lrow) * K + lch;
    const u16* pA1h = xh + ((long)z * 256 + m0 + wave * 32 + 16 + lrow) * K + lch;
    const u16* pB0h = wth + ((long)z * 192 + wave * 48 +  0 + lrow) * K + lch;
    const u16* pB1h = wth + ((long)z * 192 + wave * 48 + 16 + lrow) * K + lch;
    const u16* pB2h = wth + ((long)z * 192 + wave * 48 + 32 + lrow) * K + lch;

    auto stage = [&](int k0) {
        GLL16(pA0h + k0, &Ash[wave * 32][0]);
        GLL16(pA1h + k0, &Ash[wave * 32 + 16][0]);
        GLL16(pB0h + k0, &Bsh[wave * 48][0]);
        GLL16(pB1h + k0, &Bsh[wave * 48 + 16][0]);
        GLL16(pB2h + k0, &Bsh[wave * 48 + 32][0]);
    };

    f32x4 acc[2][12];
#pragma unroll
    for (int i = 0; i < 2; i++)
#pragma unroll
        for (int j = 0; j < 12; j++)
#pragma unroll
            for (int r = 0; r < 4; r++) acc[i][j][r] = 0.f;

    stage(0);
    FENCE_VM();
    __syncthreads();
    for (int t = 0; t < 7; t++) {
        bf16x8 afh[2];
#pragma unroll
        for (int mi = 0; mi < 2; mi++)
            afh[mi] = *(const bf16x8*)&Ash[wave * 32 + mi * 16 + lm][sq];
#pragma unroll
        for (int g = 0; g < 4; g++) {
            bf16x8 bfh[3];
#pragma unroll
            for (int j = 0; j < 3; j++)
                bfh[j] = *(const bf16x8*)&Bsh[g * 48 + j * 16 + lm][sq];
#pragma unroll
            for (int mi = 0; mi < 2; mi++)
#pragma unroll
                for (int j = 0; j < 3; j++) {
                    const int ni = g * 3 + j;
                    acc[mi][ni] = mfma_bf16(afh[mi], bfh[j], acc[mi][ni]);
                }
        }
        if (t + 1 < 7) {
            __syncthreads();
            stage((t + 1) << 5);
            FENCE_VM();
            __syncthreads();
        }
    }

    float gv[12], bv2[12], biasv[12], pv[12];
#pragma unroll
    for (int ni = 0; ni < 12; ni++) {
        const int col = ni * 16 + lm;
        gv[ni]    = lng[z * 192 + col];
        bv2[ni]   = lnb[z * 192 + col];
        biasv[ni] = roi_b[z * 192 + col];
        pv[ni]    = pos[z * 192 + col];
    }
#pragma unroll
    for (int mi = 0; mi < 2; mi++) {
#pragma unroll
        for (int r = 0; r < 4; r++) {
            const int brow = m0 + wave * 32 + mi * 16 + quad * 4 + r;
            float vals[12];
            float s = 0.f;
#pragma unroll
            for (int ni = 0; ni < 12; ni++) {
                vals[ni] = acc[mi][ni][r] + biasv[ni];
                s += vals[ni];
            }
            const float mean = row_sum16(s) * (1.f / 192.f);
            float ss = 0.f;
#pragma unroll
            for (int ni = 0; ni < 12; ni++) {
                vals[ni] -= mean;
                ss += vals[ni] * vals[ni];
            }
            const float var = row_sum16(ss) * (1.f / 192.f);
            const float rsr = 1.f / sqrtf(var + 1e-5f);
            const long ob = ((long)brow * 200 + z) * 192;
#pragma unroll
            for (int ni = 0; ni < 12; ni++) {
                const int col = ni * 16 + lm;
                const float y = gelu_exact(vals[ni] * rsr * gv[ni] + bv2[ni]) + pv[ni];
                const u16 hb = f2bf(y);
                hh[ob + col] = hb;
                hl[ob + col] = f2bf(y - bf2f(hb));
            }
        }
    }
}

// ---------------------------------------------------------------------------
// fp32 GEMM (tiny pool GEMMs). Tile 128x64, BK=16.
// ---------------------------------------------------------------------------
template<int EPI>
__global__ __launch_bounds__(256) void gemm_kernel(
    const float* __restrict__ A, int lda, long strideA,
    const float* __restrict__ Bw, long strideB,
    const float* __restrict__ bias, long strideBias,
    float* __restrict__ C, int ldc, long strideC,
    int M, int N, int K, int ldb)
{
    __shared__ float As[16][132];
    __shared__ float Bs[16][68];

    const int z = blockIdx.z;
    const float* Ab    = A    + (long)z * strideA;
    const float* Bb    = Bw   + (long)z * strideB;
    const float* biasb = bias + (long)z * strideBias;
    float*       Cb    = C    + (long)z * strideC;

    const int row0 = blockIdx.x * 128;
    const int col0 = blockIdx.y * 64;
    const int tid  = threadIdx.x;
    const int tm = tid >> 4;
    const int tn = tid & 15;

    const int la_m = tid >> 1;
    const int la_k = (tid & 1) * 8;
    const int lb_k = tid >> 4;
    const int lb_n = (tid & 15) * 4;

    const float* bcol = Bb + (col0 + lb_n);
    const float* arow = Ab + (long)(row0 + la_m) * lda;
    const bool vecA = ((lda & 3) == 0) &&
                      ((((unsigned long long)(const void*)arow) & 15ull) == 0ull);

    float acc[8][4];
#pragma unroll
    for (int i = 0; i < 8; i++)
#pragma unroll
        for (int j = 0; j < 4; j++) acc[i][j] = 0.f;

    for (int k0 = 0; k0 < K; k0 += 16) {
        if (vecA && (k0 + 16 <= K)) {
            float4 v0 = *(const float4*)(arow + k0 + la_k);
            float4 v1 = *(const float4*)(arow + k0 + la_k + 4);
            As[la_k + 0][la_m] = v0.x; As[la_k + 1][la_m] = v0.y;
            As[la_k + 2][la_m] = v0.z; As[la_k + 3][la_m] = v0.w;
            As[la_k + 4][la_m] = v1.x; As[la_k + 5][la_m] = v1.y;
            As[la_k + 6][la_m] = v1.z; As[la_k + 7][la_m] = v1.w;
        } else {
#pragma unroll
            for (int i = 0; i < 8; i++) {
                int k = k0 + la_k + i;
                As[la_k + i][la_m] = (k < K) ? arow[k] : 0.f;
            }
        }
        {
            int k = k0 + lb_k;
            float4 v = make_float4(0.f, 0.f, 0.f, 0.f);
            if (k < K) v = *(const float4*)(bcol + (long)k * ldb);
            *(float4*)&Bs[lb_k][lb_n] = v;
        }
        __syncthreads();
#pragma unroll
        for (int kk = 0; kk < 16; kk++) {
            float4 a0 = *(const float4*)&As[kk][tm * 8];
            float4 a1 = *(const float4*)&As[kk][tm * 8 + 4];
            float4 b4 = *(const float4*)&Bs[kk][tn * 4];
            float av[8] = {a0.x, a0.y, a0.z, a0.w, a1.x, a1.y, a1.z, a1.w};
            float bv[4] = {b4.x, b4.y, b4.z, b4.w};
#pragma unroll
            for (int i = 0; i < 8; i++)
#pragma unroll
                for (int j = 0; j < 4; j++) acc[i][j] += av[i] * bv[j];
        }
        __syncthreads();
    }

    const int gcol = col0 + tn * 4;
    float4 bv4 = *(const float4*)(biasb + gcol);
#pragma unroll
    for (int i = 0; i < 8; i++) {
        int grow = row0 + tm * 8 + i;
        float4 o;
        o.x = acc[i][0] + bv4.x; o.y = acc[i][1] + bv4.y;
        o.z = acc[i][2] + bv4.z; o.w = acc[i][3] + bv4.w;
        if (EPI == 1) {
            o.x = gelu_exact(o.x); o.y = gelu_exact(o.y);
            o.z = gelu_exact(o.z); o.w = gelu_exact(o.w);
        }
        *(float4*)(Cb + (long)grow * ldc + gcol) = o;
    }
}

// ---------------------------------------------------------------------------
// MFMA flash encoder attention — R8: pure bf16 internals.
// QK = 1 MFMA (qh*kh), PV = 1 MFMA (p*vh). K/V staged hi-plane only.
// LDS = Ksh 7.7K + Vth 6.7K + Pbuf(u16 [4][16][40]) 5.1K = 19,456 B.
// P handoff: plain u16 bf16 stores, aligned b128 reads (row stride 80B =
// 16B-multiple), wave-level lgkmcnt fences kept (R0 lesson).
// 4 waves, 256 thr, launch_bounds (256,2) — natural regs, no clamp.
// ---------------------------------------------------------------------------
__global__ __launch_bounds__(256, 2) void attn_enc_mfma(
    const u16* __restrict__ qkvh, u16* __restrict__ outh)
{
    __shared__ u16 Ksh[96][40];
    __shared__ u16 Vth[32][104];
    __shared__ u16 Pbuf[4][16][40];

    const int bh = blockIdx.x;
    const int b = bh / 6, h = bh % 6;
    const int tid = threadIdx.x;
    const int wave = tid >> 6, lane = tid & 63;
    const int lm = lane & 15, quad = lane >> 4;
    const int nq = (wave == 0) ? 4 : 3;

    uint4 qh[4];
#pragma unroll
    for (int i = 0; i < 4; i++) {
        if (i < nq) {
            int qt = wave + 4 * i;
            int qrow = qt * 16 + lm; if (qrow > 199) qrow = 199;
            const long off = (long)(b * 200 + qrow) * 576 + h * 32 + quad * 8;
            qh[i] = *(const uint4*)(qkvh + off);
        }
    }

    float mrow[4][4], lrow[4][4];
    f32x4 accO[4][2];
#pragma unroll
    for (int i = 0; i < 4; i++)
#pragma unroll
        for (int r = 0; r < 4; r++) {
            mrow[i][r] = -1e30f; lrow[i][r] = 0.f;
            accO[i][0][r] = 0.f; accO[i][1][r] = 0.f;
        }

    const float scale = 0.17677669529663688f;

#pragma unroll
    for (int ph = 0; ph < 3; ph++) {
        const int base = (ph == 0) ? 0 : (ph == 1) ? 96 : 192;
        const int ntl  = (ph == 2) ? 2 : 6;
        const int nslot = ntl * 16;

        __syncthreads();
        // ---- staging: waves 0-1 -> K (hi), waves 2-3 -> V transpose (hi) ----
        if (wave < 2) {
            const int sub = wave * 64 + lane;            // 0..127
#pragma unroll
            for (int rep = 0; rep < 3; rep++) {
                const int idx = rep * 128 + sub;
                if (idx < nslot * 4) {
                    const int key = idx >> 2, ch = idx & 3;
                    const int gk = base + key;
                    const bool valid = gk < 200;
                    const long roff = (long)(b * 200 + (valid ? gk : 0)) * 576
                                      + h * 32 + 192 + ch * 8;
                    uint4 v = valid ? *(const uint4*)(qkvh + roff)
                                    : make_uint4(0, 0, 0, 0);
                    *(uint4*)(&Ksh[0][0] + key * 40 + ch * 8) = v;
                }
            }
        } else {
            const int sub = (wave - 2) * 64 + lane;      // 0..127
#pragma unroll
            for (int rep = 0; rep < 2; rep++) {
                const int idx = rep * 128 + sub;
                if (idx < nslot * 2) {
                    const int key = idx >> 1, hf = idx & 1;
                    const int gk = base + key;
                    const bool valid = gk < 200;
                    const long roff = (long)(b * 200 + (valid ? gk : 0)) * 576
                                      + h * 32 + 384 + hf * 16;
                    uint4 v0 = valid ? *(const uint4*)(qkvh + roff)
                                     : make_uint4(0, 0, 0, 0);
                    uint4 v1 = valid ? *(const uint4*)(qkvh + roff + 8)
                                     : make_uint4(0, 0, 0, 0);
                    const u16* p0 = (const u16*)&v0;
                    const u16* p1 = (const u16*)&v1;
#pragma unroll
                    for (int j = 0; j < 8; j++) {
                        Vth[hf * 16 + j][key]     = p0[j];
                        Vth[hf * 16 + 8 + j][key] = p1[j];
                    }
                }
            }
        }
        __syncthreads();

#pragma unroll
        for (int i = 0; i < 4; i++) {
            if (i >= nq) continue;
            const bf16x8 qhf = *(const bf16x8*)&qh[i];
            float s[6][4];
#pragma unroll
            for (int ni = 0; ni < 6; ni++) {
                if (ni >= ntl) continue;
                bf16x8 kh8 = *(const bf16x8*)&Ksh[ni * 16 + lm][quad * 8];
                f32x4 c = {0.f, 0.f, 0.f, 0.f};
                c = mfma_bf16(qhf, kh8, c);
                const bool masked = (base + ni * 16 + lm) >= 200;
#pragma unroll
                for (int r = 0; r < 4; r++)
                    s[ni][r] = masked ? -1e30f : c[r] * scale;
            }
            float fac[4];
#pragma unroll
            for (int r = 0; r < 4; r++) {
                float pm = s[0][r];
#pragma unroll
                for (int ni = 1; ni < 6; ni++)
                    if (ni < ntl) pm = fmaxf(pm, s[ni][r]);
                pm = fmaxf(pm, __shfl_xor(pm, 1, 64));
                pm = fmaxf(pm, __shfl_xor(pm, 2, 64));
                pm = fmaxf(pm, __shfl_xor(pm, 4, 64));
                pm = fmaxf(pm, __shfl_xor(pm, 8, 64));
                const float mn = fmaxf(mrow[i][r], pm);
                fac[r] = __expf(mrow[i][r] - mn);
                mrow[i][r] = mn;
                float ps = 0.f;
#pragma unroll
                for (int ni = 0; ni < 6; ni++) {
                    if (ni >= ntl) continue;
                    float e = __expf(s[ni][r] - mn);
                    s[ni][r] = e;
                    ps += e;
                }
                ps += __shfl_xor(ps, 1, 64);
                ps += __shfl_xor(ps, 2, 64);
                ps += __shfl_xor(ps, 4, 64);
                ps += __shfl_xor(ps, 8, 64);
                lrow[i][r] = lrow[i][r] * fac[r] + ps;
                accO[i][0][r] *= fac[r];
                accO[i][1][r] *= fac[r];
            }
            // P handoff streamed per 32-key chunk through the u16 Pbuf.
#pragma unroll
            for (int ck = 0; ck < 3; ck++) {
                if (ck >= (ntl >> 1)) continue;
                // WAR guard: this wave's prior Pbuf reads must retire.
                FENCE_LGKM();
#pragma unroll
                for (int tl = 0; tl < 2; tl++) {
#pragma unroll
                    for (int r = 0; r < 4; r++) {
                        Pbuf[wave][quad * 4 + r][tl * 16 + lm] =
                            f2bf(s[2 * ck + tl][r]);
                    }
                }
                // RAW guard: cross-lane handoff within the wave.
                FENCE_LGKM();
                const bf16x8 pa = *(const bf16x8*)&Pbuf[wave][lm][quad * 8];
#pragma unroll
                for (int nt = 0; nt < 2; nt++) {
                    bf16x8 vh8 = *(const bf16x8*)&Vth[nt * 16 + lm][ck * 32 + quad * 8];
                    accO[i][nt] = mfma_bf16(pa, vh8, accO[i][nt]);
                }
            }
        }
    }

#pragma unroll
    for (int i = 0; i < 4; i++) {
        if (i >= nq) continue;
        const int qt = wave + 4 * i;
#pragma unroll
        for (int r = 0; r < 4; r++) {
            const int qrow = qt * 16 + quad * 4 + r;
            if (qrow >= 200) continue;
            const float inv = 1.f / lrow[i][r];
            const long ob = (long)(b * 200 + qrow) * 192 + h * 32 + lm;
            outh[ob]      = f2bf(accO[i][0][r] * inv);
            outh[ob + 16] = f2bf(accO[i][1][r] * inv);
        }
    }
}

// ---------------------------------------------------------------------------
__global__ __launch_bounds__(192) void mean_tokens_pair(
    const u16* __restrict__ hh, const u16* __restrict__ hl, float* __restrict__ qmean)
{
    const int b = blockIdx.x, d = threadIdx.x;
    float s = 0.f;
    for (int r = 0; r < 200; r++) {
        const long idx = ((long)b * 200 + r) * 192 + d;
        s += bf2f(hh[idx]) + bf2f(hl[idx]);
    }
    qmean[b * 192 + d] = s * (1.f / 200.f);
}

// ---------------------------------------------------------------------------
__global__ __launch_bounds__(64) void attn_pool(
    const float* __restrict__ qp, const float* __restrict__ kv,
    float* __restrict__ out)
{
    __shared__ float p[200];
    const int b = blockIdx.x / 6, h = blockIdx.x % 6;
    const int lane = threadIdx.x;

    const float* qrow = qp + b * 192 + h * 32;
    float qr[32];
#pragma unroll
    for (int u = 0; u < 8; u++) {
        float4 t = *(const float4*)(qrow + 4 * u);
        qr[4 * u] = t.x; qr[4 * u + 1] = t.y;
        qr[4 * u + 2] = t.z; qr[4 * u + 3] = t.w;
    }
    const float scale = 0.17677669529663688f;
    const float* kb = kv + (long)(b * 200) * 384 + h * 32;
    float s[4];
    float mymax = -1e30f;
#pragma unroll
    for (int g = 0; g < 4; g++) {
        int j = lane + 64 * g;
        if (j < 200) {
            const float* kr = kb + (long)j * 384;
            float acc = 0.f;
#pragma unroll
            for (int u = 0; u < 8; u++) {
                float4 k4 = *(const float4*)(kr + 4 * u);
                acc += qr[4 * u] * k4.x + qr[4 * u + 1] * k4.y +
                       qr[4 * u + 2] * k4.z + qr[4 * u + 3] * k4.w;
            }
            s[g] = acc * scale;
            mymax = fmaxf(mymax, s[g]);
        } else {
            s[g] = -1e30f;
        }
    }
    float mx = wave_max(mymax);
    float psum = 0.f;
#pragma unroll
    for (int g = 0; g < 4; g++) {
        int j = lane + 64 * g;
        if (j < 200) {
            float e = __expf(s[g] - mx);
            p[j] = e;
            psum += e;
        }
    }
    float tot = wave_sum(psum);
    __syncthreads();
    const int half = lane >> 5, d = lane & 31;
    const float* vb = kv + (long)(b * 200) * 384 + 192 + h * 32 + d;
    float acc = 0.f;
    for (int jj = 0; jj < 100; jj++) {
        int j = half * 100 + jj;
        acc += p[j] * vb[(long)j * 384];
    }
    acc += __shfl_xor(acc, 32, 64);
    acc /= tot;
    if (lane < 32) out[b * 192 + h * 32 + d] = acc;
}

// ---------------------------------------------------------------------------
__global__ __launch_bounds__(64) void classifier_kernel(
    const float* __restrict__ pooled,
    const float* __restrict__ g, const float* __restrict__ bt,
    const float* __restrict__ W1, const float* __restrict__ b1,
    const float* __restrict__ W2, const float* __restrict__ b2,
    const float* __restrict__ W3, const float* __restrict__ b3,
    float* __restrict__ out)
{
    __shared__ float z[192];
    __shared__ float z1[96];
    __shared__ float z2[48];
    const int b = blockIdx.x, lane = threadIdx.x;
    const float* pr = pooled + b * 192;
    float x0 = pr[lane], x1 = pr[lane + 64], x2 = pr[lane + 128];
    float m = wave_sum(x0 + x1 + x2) * (1.f / 192.f);
    float d0 = x0 - m, d1 = x1 - m, d2 = x2 - m;
    float v = wave_sum(d0 * d0 + d1 * d1 + d2 * d2) * (1.f / 192.f);
    float rs = 1.f / sqrtf(v + 1e-5f);
    z[lane]       = d0 * rs * g[lane]       + bt[lane];
    z[lane + 64]  = d1 * rs * g[lane + 64]  + bt[lane + 64];
    z[lane + 128] = d2 * rs * g[lane + 128] + bt[lane + 128];
    __syncthreads();
#pragma unroll
    for (int rep = 0; rep < 2; rep++) {
        int j = lane + rep * 64;
        if (j < 96) {
            float a = b1[j];
            for (int k = 0; k < 192; k++) a += z[k] * W1[k * 96 + j];
            z1[j] = gelu_exact(a);
        }
    }
    __syncthreads();
    if (lane < 48) {
        float a = b2[lane];
        for (int k = 0; k < 96; k++) a += z1[k] * W2[k * 48 + lane];
        z2[lane] = gelu_exact(a);
    }
    __syncthreads();
    if (lane < 2) {
        float a = b3[lane];
        for (int k = 0; k < 48; k++) a += z2[k] * W3[k * 2 + lane];
        out[b * 2 + lane] = a;
    }
}

// ---------------------------------------------------------------------------
extern "C" void kernel_launch(void* const* d_in, const int* in_sizes, int n_in,
                              void* d_out, int out_size, void* d_ws, size_t ws_size,
                              hipStream_t stream)
{
    (void)in_sizes; (void)n_in; (void)out_size; (void)ws_size;

    const float* x         = (const float*)d_in[0];
    const float* roi_W     = (const float*)d_in[1];
    const float* roi_b     = (const float*)d_in[2];
    const float* roi_ln_g  = (const float*)d_in[3];
    const float* roi_ln_b  = (const float*)d_in[4];
    const float* pos_emb   = (const float*)d_in[5];
    const float* enc_Wqkv  = (const float*)d_in[6];
    const float* enc_bqkv  = (const float*)d_in[7];
    const float* enc_Wo    = (const float*)d_in[8];
    const float* enc_bo    = (const float*)d_in[9];
    const float* enc_ln1_g = (const float*)d_in[10];
    const float* enc_ln1_b = (const float*)d_in[11];
    const float* enc_W1    = (const float*)d_in[12];
    const float* enc_b1    = (const float*)d_in[13];
    const float* enc_W2    = (const float*)d_in[14];
    const float* enc_b2    = (const float*)d_in[15];
    const float* enc_ln2_g = (const float*)d_in[16];
    const float* enc_ln2_b = (const float*)d_in[17];
    const float* pool_Wqkv = (const float*)d_in[18];
    const float* pool_bqkv = (const float*)d_in[19];
    const float* pool_Wo   = (const float*)d_in[20];
    const float* pool_bo   = (const float*)d_in[21];
    const float* cls_ln_g  = (const float*)d_in[22];
    const float* cls_ln_b  = (const float*)d_in[23];
    const float* cls_W1    = (const float*)d_in[24];
    const float* cls_b1    = (const float*)d_in[25];
    const float* cls_W2    = (const float*)d_in[26];
    const float* cls_b2    = (const float*)d_in[27];
    const float* cls_W3    = (const float*)d_in[28];
    const float* cls_b3    = (const float*)d_in[29];

    char* ws = (char*)d_ws;
    u16*   hh    = (u16*)(ws);                      // [T,192] hi
    u16*   hl    = (u16*)(ws + 19660800);           // [T,192] lo
    char*  bufA  = ws + 39321600;                   // 117,964,800 B
    float* bufAf = (float*)bufA;
    // tokenizer-phase layout of bufA:
    u16*   xh    = (u16*)bufA;                      // 200*256*224 u16
    u16*   wth   = (u16*)(bufA + 45875200);         // 200*192*224 u16
    // encoder-phase layout of bufA:
    u16*   qkvh  = (u16*)bufA;                      // [T,576] hi (single plane)
    u16*   ffh   = (u16*)bufA;                      // [T,576] (hi only)
    char*  bufB  = ws + 157286400;
    u16*   bBh   = (u16*)bufB;                      // attn out (hi only)
    float* qmean = (float*)(ws + 196608000);
    float* qp    = qmean + 49152;
    float* pattn = qp + 49152;
    float* pooled= pattn + 49152;
    char*  wts   = ws + 197394432;
    u16* WqkvH = (u16*)(wts);
    u16* Wff1H = (u16*)(wts + 1327104);
    u16* Wff2H = (u16*)(wts + 2654208);
    u16* WwoH  = (u16*)(wts + 3981312);
    u16* WkvH  = (u16*)(wts + 4423680);

    // ---- weight split/transpose (once per call, hi plane only) ----
    conv_wt<<<dim3(144, 1, 9), 256, 0, stream>>>(enc_Wqkv, WqkvH, 192, 192);
    conv_wt<<<dim3(432, 1, 3), 256, 0, stream>>>(enc_W1, Wff1H, 192, 576);
    conv_wt<<<dim3(432, 1, 3), 256, 0, stream>>>(enc_W2, Wff2H, 576, 192);
    conv_wt<<<dim3(144, 1, 3), 256, 0, stream>>>(enc_Wo, WwoH, 192, 192);
    conv_wt<<<dim3(144, 1, 2), 256, 0, stream>>>(pool_Wqkv + 36864, WkvH, 192, 192);

    // ---- tokenizer ----
    conv_x<<<44800, 256, 0, stream>>>(x, xh);
    conv_roiw<<<dim3(7, 6, 200), dim3(32, 8), 0, stream>>>(roi_W, wth);
    tok_mfma<<<dim3(2, 200), 256, 0, stream>>>(
        xh, wth, roi_b, roi_ln_g, roi_ln_b, pos_emb, hh, hl);

    // ---- encoder layers ----
    for (int i = 0; i < 3; i++) {
        // qkv: hi-plane output only (attn is pure-bf16 now)
        gemm_mfma<3><<<dim3(400, 3), 256, 0, stream>>>(
            hh, WqkvH + (long)i * 110592,
            enc_bqkv + i * 576, nullptr, qkvh,
            nullptr, nullptr, nullptr, nullptr, 576, 192);
        attn_enc_mfma<<<1536, 256, 0, stream>>>(qkvh, bBh);
        // Wo + fused residual LN1 (in place on hh/hl)
        gemm_mfma<5><<<dim3(400, 1), 256, 0, stream>>>(
            bBh, WwoH + (long)i * 36864,
            enc_bo + i * 192, nullptr, nullptr,
            hh, hl, enc_ln1_g + i * 192, enc_ln1_b + i * 192, 192, 192);
        // ff1 gelu -> ffh (hi only)
        gemm_mfma<2><<<dim3(400, 3), 256, 0, stream>>>(
            hh, Wff1H + (long)i * 110592,
            enc_b1 + i * 576, nullptr, ffh,
            nullptr, nullptr, nullptr, nullptr, 576, 192);
        // ff2 + fused residual LN2 (in place on hh/hl)
        gemm_mfma<5><<<dim3(400, 1), 256, 0, stream>>>(
            ffh, Wff2H + (long)i * 110592,
            enc_b2 + i * 192, nullptr, nullptr,
            hh, hl, enc_ln2_g + i * 192, enc_ln2_b + i * 192, 192, 576);
    }

    // ---- pooling ----
    mean_tokens_pair<<<256, 192, 0, stream>>>(hh, hl, qmean);
    gemm_kernel<0><<<dim3(2, 3, 1), 256, 0, stream>>>(
        qmean, 192, 0, pool_Wqkv, 0, pool_bqkv, 0, qp, 192, 0, 256, 192, 192, 192);
    gemm_mfma<0><<<dim3(400, 2), 256, 0, stream>>>(
        hh, WkvH, pool_bqkv + 192,
        bufAf, nullptr,
        nullptr, nullptr, nullptr, nullptr, 384, 192);
    attn_pool<<<1536, 64, 0, stream>>>(qp, bufAf, pattn);
    gemm_kernel<0><<<dim3(2, 3, 1), 256, 0, stream>>>(
        pattn, 192, 0, pool_Wo, 0, pool_bo, 0, pooled, 192, 0, 256, 192, 192, 192);

    // ---- classifier ----
    classifier_kernel<<<256, 64, 0, stream>>>(
        pooled, cls_ln_g, cls_ln_b,
        cls_W1, cls_b1, cls_W2, cls_b2, cls_W3, cls_b3,
        (float*)d_out);
}

// Round 10
// 937.347 us; speedup vs baseline: 1.5067x; 1.0046x over previous
//
#include <hip/hip_runtime.h>
#include <math.h>

// B=256, N_ROIS=200, ROI_DIM=199, D=192, H=6, Dh=32, L=3, FF=576, NCLS=2
// T = 51200 tokens.
// R0: fences around Pbuf handoff. R3: GEMM chunk-XOR LDS swizzle.
// R2/R4/R5: never clamp VGPR below natural footprint.
// R6/R7/R8: precision ladder — pure-bf16 GEMMs + pure-bf16 attn internals;
// absmax pinned at the residual-pair floor 2^-16 (threshold 8.5e-5). 941us.
// R9 (this): (a) attn Pbuf double-buffered on global chunk parity — WAR
// fence removed (chunk n's buffer was last read at n-2; n-1's RAW
// lgkmcnt(0) drained it; DS in-order per wave + sched_barrier). 14->7
// drains/q-tile. (b) 2Mx2N wave-split GEMM for EPI 0/2/3 (qkv/ff1/kv):
// 10 ds_read_b128 per wave-K-step instead of 14 (waves no longer
// redundantly read all 12 B fragments); same accumulation order ->
// bitwise identical. EPI5 (wo/ff2, fused row-LN) keeps 4-wave-M form.

typedef unsigned short u16;
typedef unsigned int u32;
typedef __attribute__((ext_vector_type(8))) __bf16 bf16x8;
typedef __attribute__((ext_vector_type(4))) float f32x4;

#define GLL16(gp, lp) __builtin_amdgcn_global_load_lds(                 \
    (const __attribute__((address_space(1))) void*)(gp),                \
    (__attribute__((address_space(3))) void*)(lp), 16, 0, 0)

#define FENCE_VM()   do { asm volatile("s_waitcnt vmcnt(0)" ::: "memory");  \
                          __builtin_amdgcn_sched_barrier(0); } while (0)
#define FENCE_LGKM() do { asm volatile("s_waitcnt lgkmcnt(0)" ::: "memory");\
                          __builtin_amdgcn_sched_barrier(0); } while (0)

__device__ __forceinline__ u16 f2bf(float x) {
    u32 u = __float_as_uint(x);
    u = (u + 0x7FFFu + ((u >> 16) & 1u)) >> 16;   // RNE
    return (u16)u;
}
__device__ __forceinline__ float bf2f(u16 h) {
    return __uint_as_float(((u32)h) << 16);
}

__device__ __forceinline__ float gelu_exact(float x) {
    return 0.5f * x * (1.0f + erff(x * 0.7071067811865475f));
}

__device__ __forceinline__ float wave_sum(float v) {
#pragma unroll
    for (int o = 32; o > 0; o >>= 1) v += __shfl_xor(v, o, 64);
    return v;
}
__device__ __forceinline__ float wave_max(float v) {
#pragma unroll
    for (int o = 32; o > 0; o >>= 1) v = fmaxf(v, __shfl_xor(v, o, 64));
    return v;
}
// reduce across the 16 lanes sharing a quad (row of an MFMA C tile)
__device__ __forceinline__ float row_sum16(float v) {
    v += __shfl_xor(v, 1, 64); v += __shfl_xor(v, 2, 64);
    v += __shfl_xor(v, 4, 64); v += __shfl_xor(v, 8, 64);
    return v;
}

__device__ __forceinline__ f32x4 mfma_bf16(bf16x8 a, bf16x8 b, f32x4 c) {
    return __builtin_amdgcn_mfma_f32_16x16x32_bf16(a, b, c, 0, 0, 0);
}

// ---------------------------------------------------------------------------
// Weight prep: W fp32 [K,N] (blockIdx.z batches) -> transposed bf16 hi [N][K]
// ---------------------------------------------------------------------------
__global__ void conv_wt(const float* __restrict__ W, u16* __restrict__ oh,
                        int K, int N)
{
    const long z = blockIdx.z;
    const int idx = blockIdx.x * 256 + threadIdx.x;
    if (idx >= K * N) return;
    const int k = idx / N, n = idx - k * N;
    const float x = W[z * K * N + idx];
    oh[z * (long)K * N + (long)n * K + k] = f2bf(x);
}

// ---------------------------------------------------------------------------
// x [256][39800] fp32 -> xh [200][256][224] u16 (k>=199 -> 0)
// ---------------------------------------------------------------------------
__global__ void conv_x(const float* __restrict__ x, u16* __restrict__ xh)
{
    const long idx = (long)blockIdx.x * 256 + threadIdx.x;
    if (idx >= 200L * 256 * 224) return;
    const int k = (int)(idx % 224);
    const long t = idx / 224;
    const int m = (int)(t % 256);
    const int z = (int)(t / 256);
    const float v = (k < 199) ? x[(long)m * 39800 + z * 199 + k] : 0.f;
    xh[idx] = f2bf(v);
}

// ---------------------------------------------------------------------------
// roi_W [200][199][192] fp32 -> wth [200][192][224] (LDS-tiled transpose)
// ---------------------------------------------------------------------------
__global__ void conv_roiw(const float* __restrict__ W, u16* __restrict__ oh)
{
    __shared__ float tile[32][33];
    const int z = blockIdx.z;
    const int k0 = blockIdx.x * 32;
    const int n0 = blockIdx.y * 32;
    for (int i = threadIdx.y; i < 32; i += 8) {
        const int k = k0 + i, n = n0 + threadIdx.x;
        tile[i][threadIdx.x] = (k < 199) ? W[((long)z * 199 + k) * 192 + n] : 0.f;
    }
    __syncthreads();
    for (int i = threadIdx.y; i < 32; i += 8) {
        const int n = n0 + i, k = k0 + threadIdx.x;
        const float v = tile[threadIdx.x][i];
        oh[((long)z * 192 + n) * 224 + k] = f2bf(v);
    }
}

// ---------------------------------------------------------------------------
// R9 2Mx2N pure-bf16 GEMM (EPI 0/2/3): C = Ah * Bh. Tile 128x192, BK=32.
// wave = (wm<<1)|wn; wm owns 64 rows, wn owns 96 cols -> per wave-K-step
// 4 A + 6 B ds_read_b128 for 24 MFMAs (vs 14 reads in the 4M layout).
// Same per-element accumulation order -> bitwise identical results.
// EPI 0: fp32 C. EPI 2: gelu, bf16 store. EPI 3: plain bf16 store.
// ---------------------------------------------------------------------------
template<int EPI>
__global__ __launch_bounds__(256, 3) void gemm_ns(
    const u16* __restrict__ Ah,
    const u16* __restrict__ Bh,
    const float* __restrict__ bias,
    float* __restrict__ C, u16* __restrict__ Ch,
    int N, int K)
{
    __shared__ u16 Ash[128][32];
    __shared__ u16 Bsh[192][32];

    const int tid = threadIdx.x;
    const int wave = tid >> 6, lane = tid & 63;
    const int lm = lane & 15, quad = lane >> 4;
    const int wm = wave >> 1, wn = wave & 1;
    const long m0 = (long)blockIdx.x * 128;
    const int n0 = blockIdx.y * 192;
    const int lrow = lane >> 2;
    const int lch  = (((lane & 3) ^ (lrow & 3)) * 8);   // staging swizzle
    const int sq   = (quad ^ (lm & 3)) * 8;             // read swizzle

    // staging layout identical to the 4M kernel (by `wave`)
    const u16* pA0h = Ah + (m0 + wave * 32 +  0 + lrow) * K + lch;
    const u16* pA1h = Ah + (m0 + wave * 32 + 16 + lrow) * K + lch;
    const u16* pB0h = Bh + (long)(n0 + wave * 48 +  0 + lrow) * K + lch;
    const u16* pB1h = Bh + (long)(n0 + wave * 48 + 16 + lrow) * K + lch;
    const u16* pB2h = Bh + (long)(n0 + wave * 48 + 32 + lrow) * K + lch;

    auto stage = [&](int k0) {
        GLL16(pA0h + k0, &Ash[wave * 32][0]);
        GLL16(pA1h + k0, &Ash[wave * 32 + 16][0]);
        GLL16(pB0h + k0, &Bsh[wave * 48][0]);
        GLL16(pB1h + k0, &Bsh[wave * 48 + 16][0]);
        GLL16(pB2h + k0, &Bsh[wave * 48 + 32][0]);
    };

    f32x4 acc[4][6];
#pragma unroll
    for (int i = 0; i < 4; i++)
#pragma unroll
        for (int j = 0; j < 6; j++)
#pragma unroll
            for (int r = 0; r < 4; r++) acc[i][j][r] = 0.f;

    const int kt = K >> 5;
    stage(0);
    FENCE_VM();
    __syncthreads();

    for (int t = 0; t < kt; t++) {
        bf16x8 afh[4];
#pragma unroll
        for (int mi = 0; mi < 4; mi++)
            afh[mi] = *(const bf16x8*)&Ash[wm * 64 + mi * 16 + lm][sq];
#pragma unroll
        for (int jh = 0; jh < 2; jh++) {
            bf16x8 bfh[3];
#pragma unroll
            for (int j = 0; j < 3; j++)
                bfh[j] = *(const bf16x8*)&Bsh[wn * 96 + (jh * 3 + j) * 16 + lm][sq];
#pragma unroll
            for (int mi = 0; mi < 4; mi++)
#pragma unroll
                for (int j = 0; j < 3; j++)
                    acc[mi][jh * 3 + j] =
                        mfma_bf16(afh[mi], bfh[j], acc[mi][jh * 3 + j]);
        }
        if (t + 1 < kt) {
            __syncthreads();
            stage((t + 1) << 5);
            FENCE_VM();
            __syncthreads();
        }
    }

#pragma unroll
    for (int mi = 0; mi < 4; mi++) {
        const long rowb = m0 + wm * 64 + mi * 16 + quad * 4;
#pragma unroll
        for (int nj = 0; nj < 6; nj++) {
            const int col = n0 + wn * 96 + nj * 16 + lm;
            const float bv = bias[col];
#pragma unroll
            for (int r = 0; r < 4; r++) {
                float v = acc[mi][nj][r] + bv;
                if (EPI == 0) {
                    C[(rowb + r) * N + col] = v;
                } else {
                    if (EPI == 2) v = gelu_exact(v);
                    Ch[(rowb + r) * N + col] = f2bf(v);
                }
            }
        }
    }
}

// ---------------------------------------------------------------------------
// 4-wave-M pure-bf16 GEMM with fused residual+LN epilogue (EPI 5 only):
// H := LN(H + acc + bias). N must be 192 (full rows per wave for the LN).
// ---------------------------------------------------------------------------
__global__ __launch_bounds__(256, 3) void gemm_ln(
    const u16* __restrict__ Ah,
    const u16* __restrict__ Bh,
    const float* __restrict__ bias,
    u16* __restrict__ Hh, u16* __restrict__ Hl,
    const float* __restrict__ lng, const float* __restrict__ lnb,
    int K)
{
    __shared__ u16 Ash[128][32];
    __shared__ u16 Bsh[192][32];

    const int tid = threadIdx.x;
    const int wave = tid >> 6, lane = tid & 63;
    const int lm = lane & 15, quad = lane >> 4;
    const long m0 = (long)blockIdx.x * 128;
    const int lrow = lane >> 2;
    const int lch  = (((lane & 3) ^ (lrow & 3)) * 8);
    const int sq   = (quad ^ (lm & 3)) * 8;

    const u16* pA0h = Ah + (m0 + wave * 32 +  0 + lrow) * K + lch;
    const u16* pA1h = Ah + (m0 + wave * 32 + 16 + lrow) * K + lch;
    const u16* pB0h = Bh + (long)(wave * 48 +  0 + lrow) * K + lch;
    const u16* pB1h = Bh + (long)(wave * 48 + 16 + lrow) * K + lch;
    const u16* pB2h = Bh + (long)(wave * 48 + 32 + lrow) * K + lch;

    auto stage = [&](int k0) {
        GLL16(pA0h + k0, &Ash[wave * 32][0]);
        GLL16(pA1h + k0, &Ash[wave * 32 + 16][0]);
        GLL16(pB0h + k0, &Bsh[wave * 48][0]);
        GLL16(pB1h + k0, &Bsh[wave * 48 + 16][0]);
        GLL16(pB2h + k0, &Bsh[wave * 48 + 32][0]);
    };

    f32x4 acc[2][12];
#pragma unroll
    for (int i = 0; i < 2; i++)
#pragma unroll
        for (int j = 0; j < 12; j++)
#pragma unroll
            for (int r = 0; r < 4; r++) acc[i][j][r] = 0.f;

    const int kt = K >> 5;
    stage(0);
    FENCE_VM();
    __syncthreads();

    for (int t = 0; t < kt; t++) {
        bf16x8 afh[2];
#pragma unroll
        for (int mi = 0; mi < 2; mi++)
            afh[mi] = *(const bf16x8*)&Ash[wave * 32 + mi * 16 + lm][sq];
#pragma unroll
        for (int g = 0; g < 4; g++) {
            bf16x8 bfh[3];
#pragma unroll
            for (int j = 0; j < 3; j++)
                bfh[j] = *(const bf16x8*)&Bsh[g * 48 + j * 16 + lm][sq];
#pragma unroll
            for (int mi = 0; mi < 2; mi++)
#pragma unroll
                for (int j = 0; j < 3; j++) {
                    const int ni = g * 3 + j;
                    acc[mi][ni] = mfma_bf16(afh[mi], bfh[j], acc[mi][ni]);
                }
        }
        if (t + 1 < kt) {
            __syncthreads();
            stage((t + 1) << 5);
            FENCE_VM();
            __syncthreads();
        }
    }

    float gv[12], bv2[12], biasv[12];
#pragma unroll
    for (int ni = 0; ni < 12; ni++) {
        const int col = ni * 16 + lm;
        gv[ni] = lng[col]; bv2[ni] = lnb[col]; biasv[ni] = bias[col];
    }
#pragma unroll
    for (int mi = 0; mi < 2; mi++) {
#pragma unroll
        for (int r = 0; r < 4; r++) {
            const long row = m0 + wave * 32 + mi * 16 + quad * 4 + r;
            const long rb = row * 192;
            float vals[12];
            float s = 0.f;
#pragma unroll
            for (int ni = 0; ni < 12; ni++) {
                const int col = ni * 16 + lm;
                const float hval = bf2f(Hh[rb + col]) + bf2f(Hl[rb + col]);
                vals[ni] = acc[mi][ni][r] + biasv[ni] + hval;
                s += vals[ni];
            }
            const float mean = row_sum16(s) * (1.f / 192.f);
            float ss = 0.f;
#pragma unroll
            for (int ni = 0; ni < 12; ni++) {
                vals[ni] -= mean;
                ss += vals[ni] * vals[ni];
            }
            const float var = row_sum16(ss) * (1.f / 192.f);
            const float rsr = 1.f / sqrtf(var + 1e-5f);
#pragma unroll
            for (int ni = 0; ni < 12; ni++) {
                const int col = ni * 16 + lm;
                const float y = vals[ni] * rsr * gv[ni] + bv2[ni];
                const u16 hb = f2bf(y);
                Hh[rb + col] = hb;
                Hl[rb + col] = f2bf(y - bf2f(hb));
            }
        }
    }
}

// ---------------------------------------------------------------------------
// Tokenizer MFMA (pure bf16): per-z GEMM [256,224]@[192,224]^T with fused
// bias+LN+gelu+pos epilogue (full-row LN -> keeps 4-wave-M layout).
// ---------------------------------------------------------------------------
__global__ __launch_bounds__(256, 3) void tok_mfma(
    const u16* __restrict__ xh,
    const u16* __restrict__ wth,
    const float* __restrict__ roi_b,
    const float* __restrict__ lng, const float* __restrict__ lnb,
    const float* __restrict__ pos,
    u16* __restrict__ hh, u16* __restrict__ hl)
{
    __shared__ u16 Ash[128][32];
    __shared__ u16 Bsh[192][32];

    const int tid = threadIdx.x;
    const int wave = tid >> 6, lane = tid & 63;
    const int lm = lane & 15, quad = lane >> 4;
    const int m0 = blockIdx.x * 128;
    const int z = blockIdx.y;
    const int lrow = lane >> 2;
    const int lch  = (((lane & 3) ^ (lrow & 3)) * 8);
    const int sq   = (quad ^ (lm & 3)) * 8;
    const int K = 224;

    const u16* pA0h = xh + ((long)z * 256 + m0 + wave * 32 +  0 + lrow) * K + lch;
    const u16* pA1h = xh + ((long)z * 256 + m0 + wave * 32 + 16 + lrow) * K + lch;
    const u16* pB0h = wth + ((long)z * 192 + wave * 48 +  0 + lrow) * K + lch;
    const u16* pB1h = wth + ((long)z * 192 + wave * 48 + 16 + lrow) * K + lch;
    const u16* pB2h = wth + ((long)z * 192 + wave * 48 + 32 + lrow) * K + lch;

    auto stage = [&](int k0) {
        GLL16(pA0h + k0, &Ash[wave * 32][0]);
        GLL16(pA1h + k0, &Ash[wave * 32 + 16][0]);
        GLL16(pB0h + k0, &Bsh[wave * 48][0]);
        GLL16(pB1h + k0, &Bsh[wave * 48 + 16][0]);
        GLL16(pB2h + k0, &Bsh[wave * 48 + 32][0]);
    };

    f32x4 acc[2][12];
#pragma unroll
    for (int i = 0; i < 2; i++)
#pragma unroll
        for (int j = 0; j < 12; j++)
#pragma unroll
            for (int r = 0; r < 4; r++) acc[i][j][r] = 0.f;

    stage(0);
    FENCE_VM();
    __syncthreads();
    for (int t = 0; t < 7; t++) {
        bf16x8 afh[2];
#pragma unroll
        for (int mi = 0; mi < 2; mi++)
            afh[mi] = *(const bf16x8*)&Ash[wave * 32 + mi * 16 + lm][sq];
#pragma unroll
        for (int g = 0; g < 4; g++) {
            bf16x8 bfh[3];
#pragma unroll
            for (int j = 0; j < 3; j++)
                bfh[j] = *(const bf16x8*)&Bsh[g * 48 + j * 16 + lm][sq];
#pragma unroll
            for (int mi = 0; mi < 2; mi++)
#pragma unroll
                for (int j = 0; j < 3; j++) {
                    const int ni = g * 3 + j;
                    acc[mi][ni] = mfma_bf16(afh[mi], bfh[j], acc[mi][ni]);
                }
        }
        if (t + 1 < 7) {
            __syncthreads();
            stage((t + 1) << 5);
            FENCE_VM();
            __syncthreads();
        }
    }

    float gv[12], bv2[12], biasv[12], pv[12];
#pragma unroll
    for (int ni = 0; ni < 12; ni++) {
        const int col = ni * 16 + lm;
        gv[ni]    = lng[z * 192 + col];
        bv2[ni]   = lnb[z * 192 + col];
        biasv[ni] = roi_b[z * 192 + col];
        pv[ni]    = pos[z * 192 + col];
    }
#pragma unroll
    for (int mi = 0; mi < 2; mi++) {
#pragma unroll
        for (int r = 0; r < 4; r++) {
            const int brow = m0 + wave * 32 + mi * 16 + quad * 4 + r;
            float vals[12];
            float s = 0.f;
#pragma unroll
            for (int ni = 0; ni < 12; ni++) {
                vals[ni] = acc[mi][ni][r] + biasv[ni];
                s += vals[ni];
            }
            const float mean = row_sum16(s) * (1.f / 192.f);
            float ss = 0.f;
#pragma unroll
            for (int ni = 0; ni < 12; ni++) {
                vals[ni] -= mean;
                ss += vals[ni] * vals[ni];
            }
            const float var = row_sum16(ss) * (1.f / 192.f);
            const float rsr = 1.f / sqrtf(var + 1e-5f);
            const long ob = ((long)brow * 200 + z) * 192;
#pragma unroll
            for (int ni = 0; ni < 12; ni++) {
                const int col = ni * 16 + lm;
                const float y = gelu_exact(vals[ni] * rsr * gv[ni] + bv2[ni]) + pv[ni];
                const u16 hb = f2bf(y);
                hh[ob + col] = hb;
                hl[ob + col] = f2bf(y - bf2f(hb));
            }
        }
    }
}

// ---------------------------------------------------------------------------
// fp32 GEMM (tiny pool GEMMs). Tile 128x64, BK=16.
// ---------------------------------------------------------------------------
template<int EPI>
__global__ __launch_bounds__(256) void gemm_kernel(
    const float* __restrict__ A, int lda, long strideA,
    const float* __restrict__ Bw, long strideB,
    const float* __restrict__ bias, long strideBias,
    float* __restrict__ C, int ldc, long strideC,
    int M, int N, int K, int ldb)
{
    __shared__ float As[16][132];
    __shared__ float Bs[16][68];

    const int z = blockIdx.z;
    const float* Ab    = A    + (long)z * strideA;
    const float* Bb    = Bw   + (long)z * strideB;
    const float* biasb = bias + (long)z * strideBias;
    float*       Cb    = C    + (long)z * strideC;

    const int row0 = blockIdx.x * 128;
    const int col0 = blockIdx.y * 64;
    const int tid  = threadIdx.x;
    const int tm = tid >> 4;
    const int tn = tid & 15;

    const int la_m = tid >> 1;
    const int la_k = (tid & 1) * 8;
    const int lb_k = tid >> 4;
    const int lb_n = (tid & 15) * 4;

    const float* bcol = Bb + (col0 + lb_n);
    const float* arow = Ab + (long)(row0 + la_m) * lda;
    const bool vecA = ((lda & 3) == 0) &&
                      ((((unsigned long long)(const void*)arow) & 15ull) == 0ull);

    float acc[8][4];
#pragma unroll
    for (int i = 0; i < 8; i++)
#pragma unroll
        for (int j = 0; j < 4; j++) acc[i][j] = 0.f;

    for (int k0 = 0; k0 < K; k0 += 16) {
        if (vecA && (k0 + 16 <= K)) {
            float4 v0 = *(const float4*)(arow + k0 + la_k);
            float4 v1 = *(const float4*)(arow + k0 + la_k + 4);
            As[la_k + 0][la_m] = v0.x; As[la_k + 1][la_m] = v0.y;
            As[la_k + 2][la_m] = v0.z; As[la_k + 3][la_m] = v0.w;
            As[la_k + 4][la_m] = v1.x; As[la_k + 5][la_m] = v1.y;
            As[la_k + 6][la_m] = v1.z; As[la_k + 7][la_m] = v1.w;
        } else {
#pragma unroll
            for (int i = 0; i < 8; i++) {
                int k = k0 + la_k + i;
                As[la_k + i][la_m] = (k < K) ? arow[k] : 0.f;
            }
        }
        {
            int k = k0 + lb_k;
            float4 v = make_float4(0.f, 0.f, 0.f, 0.f);
            if (k < K) v = *(const float4*)(bcol + (long)k * ldb);
            *(float4*)&Bs[lb_k][lb_n] = v;
        }
        __syncthreads();
#pragma unroll
        for (int kk = 0; kk < 16; kk++) {
            float4 a0 = *(const float4*)&As[kk][tm * 8];
            float4 a1 = *(const float4*)&As[kk][tm * 8 + 4];
            float4 b4 = *(const float4*)&Bs[kk][tn * 4];
            float av[8] = {a0.x, a0.y, a0.z, a0.w, a1.x, a1.y, a1.z, a1.w};
            float bv[4] = {b4.x, b4.y, b4.z, b4.w};
#pragma unroll
            for (int i = 0; i < 8; i++)
#pragma unroll
                for (int j = 0; j < 4; j++) acc[i][j] += av[i] * bv[j];
        }
        __syncthreads();
    }

    const int gcol = col0 + tn * 4;
    float4 bv4 = *(const float4*)(biasb + gcol);
#pragma unroll
    for (int i = 0; i < 8; i++) {
        int grow = row0 + tm * 8 + i;
        float4 o;
        o.x = acc[i][0] + bv4.x; o.y = acc[i][1] + bv4.y;
        o.z = acc[i][2] + bv4.z; o.w = acc[i][3] + bv4.w;
        if (EPI == 1) {
            o.x = gelu_exact(o.x); o.y = gelu_exact(o.y);
            o.z = gelu_exact(o.z); o.w = gelu_exact(o.w);
        }
        *(float4*)(Cb + (long)grow * ldc + gcol) = o;
    }
}

// ---------------------------------------------------------------------------
// MFMA flash encoder attention — pure bf16 internals (R8), R9: Pbuf
// double-buffered on a global chunk-parity counter; WAR fence removed
// (chunk n's buffer last read at chunk n-2, drained by chunk n-1's RAW
// lgkmcnt(0); DS ops in-order per wave; sched_barrier pins compiler).
// LDS = Ksh 7.7K + Vth 6.7K + Pbuf[4][2][16][40] 10.2K = 24.6KB.
// ---------------------------------------------------------------------------
__global__ __launch_bounds__(256, 2) void attn_enc_mfma(
    const u16* __restrict__ qkvh, u16* __restrict__ outh)
{
    __shared__ u16 Ksh[96][40];
    __shared__ u16 Vth[32][104];
    __shared__ u16 Pbuf[4][2][16][40];

    const int bh = blockIdx.x;
    const int b = bh / 6, h = bh % 6;
    const int tid = threadIdx.x;
    const int wave = tid >> 6, lane = tid & 63;
    const int lm = lane & 15, quad = lane >> 4;
    const int nq = (wave == 0) ? 4 : 3;

    uint4 qh[4];
#pragma unroll
    for (int i = 0; i < 4; i++) {
        if (i < nq) {
            int qt = wave + 4 * i;
            int qrow = qt * 16 + lm; if (qrow > 199) qrow = 199;
            const long off = (long)(b * 200 + qrow) * 576 + h * 32 + quad * 8;
            qh[i] = *(const uint4*)(qkvh + off);
        }
    }

    float mrow[4][4], lrow[4][4];
    f32x4 accO[4][2];
#pragma unroll
    for (int i = 0; i < 4; i++)
#pragma unroll
        for (int r = 0; r < 4; r++) {
            mrow[i][r] = -1e30f; lrow[i][r] = 0.f;
            accO[i][0][r] = 0.f; accO[i][1][r] = 0.f;
        }

    const float scale = 0.17677669529663688f;
    int par = 0;   // global chunk parity (wave-uniform control flow)

#pragma unroll
    for (int ph = 0; ph < 3; ph++) {
        const int base = (ph == 0) ? 0 : (ph == 1) ? 96 : 192;
        const int ntl  = (ph == 2) ? 2 : 6;
        const int nslot = ntl * 16;

        __syncthreads();
        // ---- staging: waves 0-1 -> K (hi), waves 2-3 -> V transpose (hi) ----
        if (wave < 2) {
            const int sub = wave * 64 + lane;            // 0..127
#pragma unroll
            for (int rep = 0; rep < 3; rep++) {
                const int idx = rep * 128 + sub;
                if (idx < nslot * 4) {
                    const int key = idx >> 2, ch = idx & 3;
                    const int gk = base + key;
                    const bool valid = gk < 200;
                    const long roff = (long)(b * 200 + (valid ? gk : 0)) * 576
                                      + h * 32 + 192 + ch * 8;
                    uint4 v = valid ? *(const uint4*)(qkvh + roff)
                                    : make_uint4(0, 0, 0, 0);
                    *(uint4*)(&Ksh[0][0] + key * 40 + ch * 8) = v;
                }
            }
        } else {
            const int sub = (wave - 2) * 64 + lane;      // 0..127
#pragma unroll
            for (int rep = 0; rep < 2; rep++) {
                const int idx = rep * 128 + sub;
                if (idx < nslot * 2) {
                    const int key = idx >> 1, hf = idx & 1;
                    const int gk = base + key;
                    const bool valid = gk < 200;
                    const long roff = (long)(b * 200 + (valid ? gk : 0)) * 576
                                      + h * 32 + 384 + hf * 16;
                    uint4 v0 = valid ? *(const uint4*)(qkvh + roff)
                                     : make_uint4(0, 0, 0, 0);
                    uint4 v1 = valid ? *(const uint4*)(qkvh + roff + 8)
                                     : make_uint4(0, 0, 0, 0);
                    const u16* p0 = (const u16*)&v0;
                    const u16* p1 = (const u16*)&v1;
#pragma unroll
                    for (int j = 0; j < 8; j++) {
                        Vth[hf * 16 + j][key]     = p0[j];
                        Vth[hf * 16 + 8 + j][key] = p1[j];
                    }
                }
            }
        }
        __syncthreads();

#pragma unroll
        for (int i = 0; i < 4; i++) {
            if (i >= nq) continue;
            const bf16x8 qhf = *(const bf16x8*)&qh[i];
            float s[6][4];
#pragma unroll
            for (int ni = 0; ni < 6; ni++) {
                if (ni >= ntl) continue;
                bf16x8 kh8 = *(const bf16x8*)&Ksh[ni * 16 + lm][quad * 8];
                f32x4 c = {0.f, 0.f, 0.f, 0.f};
                c = mfma_bf16(qhf, kh8, c);
                const bool masked = (base + ni * 16 + lm) >= 200;
#pragma unroll
                for (int r = 0; r < 4; r++)
                    s[ni][r] = masked ? -1e30f : c[r] * scale;
            }
            float fac[4];
#pragma unroll
            for (int r = 0; r < 4; r++) {
                float pm = s[0][r];
#pragma unroll
                for (int ni = 1; ni < 6; ni++)
                    if (ni < ntl) pm = fmaxf(pm, s[ni][r]);
                pm = fmaxf(pm, __shfl_xor(pm, 1, 64));
                pm = fmaxf(pm, __shfl_xor(pm, 2, 64));
                pm = fmaxf(pm, __shfl_xor(pm, 4, 64));
                pm = fmaxf(pm, __shfl_xor(pm, 8, 64));
                const float mn = fmaxf(mrow[i][r], pm);
                fac[r] = __expf(mrow[i][r] - mn);
                mrow[i][r] = mn;
                float ps = 0.f;
#pragma unroll
                for (int ni = 0; ni < 6; ni++) {
                    if (ni >= ntl) continue;
                    float e = __expf(s[ni][r] - mn);
                    s[ni][r] = e;
                    ps += e;
                }
                ps += __shfl_xor(ps, 1, 64);
                ps += __shfl_xor(ps, 2, 64);
                ps += __shfl_xor(ps, 4, 64);
                ps += __shfl_xor(ps, 8, 64);
                lrow[i][r] = lrow[i][r] * fac[r] + ps;
                accO[i][0][r] *= fac[r];
                accO[i][1][r] *= fac[r];
            }
            // P handoff streamed per 32-key chunk; double-buffered Pbuf.
#pragma unroll
            for (int ck = 0; ck < 3; ck++) {
                if (ck >= (ntl >> 1)) continue;
                const int pb = par & 1; par++;
#pragma unroll
                for (int tl = 0; tl < 2; tl++) {
#pragma unroll
                    for (int r = 0; r < 4; r++) {
                        Pbuf[wave][pb][quad * 4 + r][tl * 16 + lm] =
                            f2bf(s[2 * ck + tl][r]);
                    }
                }
                // RAW guard: cross-lane handoff within the wave.
                FENCE_LGKM();
                const bf16x8 pa = *(const bf16x8*)&Pbuf[wave][pb][lm][quad * 8];
#pragma unroll
                for (int nt = 0; nt < 2; nt++) {
                    bf16x8 vh8 = *(const bf16x8*)&Vth[nt * 16 + lm][ck * 32 + quad * 8];
                    accO[i][nt] = mfma_bf16(pa, vh8, accO[i][nt]);
                }
            }
        }
    }

#pragma unroll
    for (int i = 0; i < 4; i++) {
        if (i >= nq) continue;
        const int qt = wave + 4 * i;
#pragma unroll
        for (int r = 0; r < 4; r++) {
            const int qrow = qt * 16 + quad * 4 + r;
            if (qrow >= 200) continue;
            const float inv = 1.f / lrow[i][r];
            const long ob = (long)(b * 200 + qrow) * 192 + h * 32 + lm;
            outh[ob]      = f2bf(accO[i][0][r] * inv);
            outh[ob + 16] = f2bf(accO[i][1][r] * inv);
        }
    }
}

// ---------------------------------------------------------------------------
__global__ __launch_bounds__(192) void mean_tokens_pair(
    const u16* __restrict__ hh, const u16* __restrict__ hl, float* __restrict__ qmean)
{
    const int b = blockIdx.x, d = threadIdx.x;
    float s = 0.f;
    for (int r = 0; r < 200; r++) {
        const long idx = ((long)b * 200 + r) * 192 + d;
        s += bf2f(hh[idx]) + bf2f(hl[idx]);
    }
    qmean[b * 192 + d] = s * (1.f / 200.f);
}

// ---------------------------------------------------------------------------
__global__ __launch_bounds__(64) void attn_pool(
    const float* __restrict__ qp, const float* __restrict__ kv,
    float* __restrict__ out)
{
    __shared__ float p[200];
    const int b = blockIdx.x / 6, h = blockIdx.x % 6;
    const int lane = threadIdx.x;

    const float* qrow = qp + b * 192 + h * 32;
    float qr[32];
#pragma unroll
    for (int u = 0; u < 8; u++) {
        float4 t = *(const float4*)(qrow + 4 * u);
        qr[4 * u] = t.x; qr[4 * u + 1] = t.y;
        qr[4 * u + 2] = t.z; qr[4 * u + 3] = t.w;
    }
    const float scale = 0.17677669529663688f;
    const float* kb = kv + (long)(b * 200) * 384 + h * 32;
    float s[4];
    float mymax = -1e30f;
#pragma unroll
    for (int g = 0; g < 4; g++) {
        int j = lane + 64 * g;
        if (j < 200) {
            const float* kr = kb + (long)j * 384;
            float acc = 0.f;
#pragma unroll
            for (int u = 0; u < 8; u++) {
                float4 k4 = *(const float4*)(kr + 4 * u);
                acc += qr[4 * u] * k4.x + qr[4 * u + 1] * k4.y +
                       qr[4 * u + 2] * k4.z + qr[4 * u + 3] * k4.w;
            }
            s[g] = acc * scale;
            mymax = fmaxf(mymax, s[g]);
        } else {
            s[g] = -1e30f;
        }
    }
    float mx = wave_max(mymax);
    float psum = 0.f;
#pragma unroll
    for (int g = 0; g < 4; g++) {
        int j = lane + 64 * g;
        if (j < 200) {
            float e = __expf(s[g] - mx);
            p[j] = e;
            psum += e;
        }
    }
    float tot = wave_sum(psum);
    __syncthreads();
    const int half = lane >> 5, d = lane & 31;
    const float* vb = kv + (long)(b * 200) * 384 + 192 + h * 32 + d;
    float acc = 0.f;
    for (int jj = 0; jj < 100; jj++) {
        int j = half * 100 + jj;
        acc += p[j] * vb[(long)j * 384];
    }
    acc += __shfl_xor(acc, 32, 64);
    acc /= tot;
    if (lane < 32) out[b * 192 + h * 32 + d] = acc;
}

// ---------------------------------------------------------------------------
__global__ __launch_bounds__(64) void classifier_kernel(
    const float* __restrict__ pooled,
    const float* __restrict__ g, const float* __restrict__ bt,
    const float* __restrict__ W1, const float* __restrict__ b1,
    const float* __restrict__ W2, const float* __restrict__ b2,
    const float* __restrict__ W3, const float* __restrict__ b3,
    float* __restrict__ out)
{
    __shared__ float z[192];
    __shared__ float z1[96];
    __shared__ float z2[48];
    const int b = blockIdx.x, lane = threadIdx.x;
    const float* pr = pooled + b * 192;
    float x0 = pr[lane], x1 = pr[lane + 64], x2 = pr[lane + 128];
    float m = wave_sum(x0 + x1 + x2) * (1.f / 192.f);
    float d0 = x0 - m, d1 = x1 - m, d2 = x2 - m;
    float v = wave_sum(d0 * d0 + d1 * d1 + d2 * d2) * (1.f / 192.f);
    float rs = 1.f / sqrtf(v + 1e-5f);
    z[lane]       = d0 * rs * g[lane]       + bt[lane];
    z[lane + 64]  = d1 * rs * g[lane + 64]  + bt[lane + 64];
    z[lane + 128] = d2 * rs * g[lane + 128] + bt[lane + 128];
    __syncthreads();
#pragma unroll
    for (int rep = 0; rep < 2; rep++) {
        int j = lane + rep * 64;
        if (j < 96) {
            float a = b1[j];
            for (int k = 0; k < 192; k++) a += z[k] * W1[k * 96 + j];
            z1[j] = gelu_exact(a);
        }
    }
    __syncthreads();
    if (lane < 48) {
        float a = b2[lane];
        for (int k = 0; k < 96; k++) a += z1[k] * W2[k * 48 + lane];
        z2[lane] = gelu_exact(a);
    }
    __syncthreads();
    if (lane < 2) {
        float a = b3[lane];
        for (int k = 0; k < 48; k++) a += z2[k] * W3[k * 2 + lane];
        out[b * 2 + lane] = a;
    }
}

// ---------------------------------------------------------------------------
extern "C" void kernel_launch(void* const* d_in, const int* in_sizes, int n_in,
                              void* d_out, int out_size, void* d_ws, size_t ws_size,
                              hipStream_t stream)
{
    (void)in_sizes; (void)n_in; (void)out_size; (void)ws_size;

    const float* x         = (const float*)d_in[0];
    const float* roi_W     = (const float*)d_in[1];
    const float* roi_b     = (const float*)d_in[2];
    const float* roi_ln_g  = (const float*)d_in[3];
    const float* roi_ln_b  = (const float*)d_in[4];
    const float* pos_emb   = (const float*)d_in[5];
    const float* enc_Wqkv  = (const float*)d_in[6];
    const float* enc_bqkv  = (const float*)d_in[7];
    const float* enc_Wo    = (const float*)d_in[8];
    const float* enc_bo    = (const float*)d_in[9];
    const float* enc_ln1_g = (const float*)d_in[10];
    const float* enc_ln1_b = (const float*)d_in[11];
    const float* enc_W1    = (const float*)d_in[12];
    const float* enc_b1    = (const float*)d_in[13];
    const float* enc_W2    = (const float*)d_in[14];
    const float* enc_b2    = (const float*)d_in[15];
    const float* enc_ln2_g = (const float*)d_in[16];
    const float* enc_ln2_b = (const float*)d_in[17];
    const float* pool_Wqkv = (const float*)d_in[18];
    const float* pool_bqkv = (const float*)d_in[19];
    const float* pool_Wo   = (const float*)d_in[20];
    const float* pool_bo   = (const float*)d_in[21];
    const float* cls_ln_g  = (const float*)d_in[22];
    const float* cls_ln_b  = (const float*)d_in[23];
    const float* cls_W1    = (const float*)d_in[24];
    const float* cls_b1    = (const float*)d_in[25];
    const float* cls_W2    = (const float*)d_in[26];
    const float* cls_b2    = (const float*)d_in[27];
    const float* cls_W3    = (const float*)d_in[28];
    const float* cls_b3    = (const float*)d_in[29];

    char* ws = (char*)d_ws;
    u16*   hh    = (u16*)(ws);                      // [T,192] hi
    u16*   hl    = (u16*)(ws + 19660800);           // [T,192] lo
    char*  bufA  = ws + 39321600;                   // 117,964,800 B
    float* bufAf = (float*)bufA;
    // tokenizer-phase layout of bufA:
    u16*   xh    = (u16*)bufA;                      // 200*256*224 u16
    u16*   wth   = (u16*)(bufA + 45875200);         // 200*192*224 u16
    // encoder-phase layout of bufA:
    u16*   qkvh  = (u16*)bufA;                      // [T,576] hi (single plane)
    u16*   ffh   = (u16*)bufA;                      // [T,576] (hi only)
    char*  bufB  = ws + 157286400;
    u16*   bBh   = (u16*)bufB;                      // attn out (hi only)
    float* qmean = (float*)(ws + 196608000);
    float* qp    = qmean + 49152;
    float* pattn = qp + 49152;
    float* pooled= pattn + 49152;
    char*  wts   = ws + 197394432;
    u16* WqkvH = (u16*)(wts);
    u16* Wff1H = (u16*)(wts + 1327104);
    u16* Wff2H = (u16*)(wts + 2654208);
    u16* WwoH  = (u16*)(wts + 3981312);
    u16* WkvH  = (u16*)(wts + 4423680);

    // ---- weight split/transpose (once per call, hi plane only) ----
    conv_wt<<<dim3(144, 1, 9), 256, 0, stream>>>(enc_Wqkv, WqkvH, 192, 192);
    conv_wt<<<dim3(432, 1, 3), 256, 0, stream>>>(enc_W1, Wff1H, 192, 576);
    conv_wt<<<dim3(432, 1, 3), 256, 0, stream>>>(enc_W2, Wff2H, 576, 192);
    conv_wt<<<dim3(144, 1, 3), 256, 0, stream>>>(enc_Wo, WwoH, 192, 192);
    conv_wt<<<dim3(144, 1, 2), 256, 0, stream>>>(pool_Wqkv + 36864, WkvH, 192, 192);

    // ---- tokenizer ----
    conv_x<<<44800, 256, 0, stream>>>(x, xh);
    conv_roiw<<<dim3(7, 6, 200), dim3(32, 8), 0, stream>>>(roi_W, wth);
    tok_mfma<<<dim3(2, 200), 256, 0, stream>>>(
        xh, wth, roi_b, roi_ln_g, roi_ln_b, pos_emb, hh, hl);

    // ---- encoder layers ----
    for (int i = 0; i < 3; i++) {
        // qkv (2Mx2N split kernel)
        gemm_ns<3><<<dim3(400, 3), 256, 0, stream>>>(
            hh, WqkvH + (long)i * 110592,
            enc_bqkv + i * 576, nullptr, qkvh, 576, 192);
        attn_enc_mfma<<<1536, 256, 0, stream>>>(qkvh, bBh);
        // Wo + fused residual LN1 (4-wave-M LN kernel)
        gemm_ln<<<dim3(400, 1), 256, 0, stream>>>(
            bBh, WwoH + (long)i * 36864,
            enc_bo + i * 192,
            hh, hl, enc_ln1_g + i * 192, enc_ln1_b + i * 192, 192);
        // ff1 gelu (2Mx2N split kernel)
        gemm_ns<2><<<dim3(400, 3), 256, 0, stream>>>(
            hh, Wff1H + (long)i * 110592,
            enc_b1 + i * 576, nullptr, ffh, 576, 192);
        // ff2 + fused residual LN2
        gemm_ln<<<dim3(400, 1), 256, 0, stream>>>(
            ffh, Wff2H + (long)i * 110592,
            enc_b2 + i * 192,
            hh, hl, enc_ln2_g + i * 192, enc_ln2_b + i * 192, 576);
    }

    // ---- pooling ----
    mean_tokens_pair<<<256, 192, 0, stream>>>(hh, hl, qmean);
    gemm_kernel<0><<<dim3(2, 3, 1), 256, 0, stream>>>(
        qmean, 192, 0, pool_Wqkv, 0, pool_bqkv, 0, qp, 192, 0, 256, 192, 192, 192);
    gemm_ns<0><<<dim3(400, 2), 256, 0, stream>>>(
        hh, WkvH, pool_bqkv + 192, bufAf, nullptr, 384, 192);
    attn_pool<<<1536, 64, 0, stream>>>(qp, bufAf, pattn);
    gemm_kernel<0><<<dim3(2, 3, 1), 256, 0, stream>>>(
        pattn, 192, 0, pool_Wo, 0, pool_bo, 0, pooled, 192, 0, 256, 192, 192, 192);

    // ---- classifier ----
    classifier_kernel<<<256, 64, 0, stream>>>(
        pooled, cls_ln_g, cls_ln_b,
        cls_W1, cls_b1, cls_W2, cls_b2, cls_W3, cls_b3,
        (float*)d_out);
}

// Round 11
// 873.114 us; speedup vs baseline: 1.6176x; 1.0736x over previous
//
#include <hip/hip_runtime.h>
#include <math.h>

// B=256, N_ROIS=200, ROI_DIM=199, D=192, H=6, Dh=32, L=3, FF=576, NCLS=2
// T = 51200 tokens.
// R0: fences around Pbuf handoff. R3: GEMM chunk-XOR LDS swizzle.
// R2/R4/R5: never clamp VGPR below natural footprint.
// R6/R7/R8: precision ladder — pure-bf16 GEMMs + pure-bf16 attn internals;
// absmax pinned at residual-pair floor 2^-16 (threshold 8.5e-5).
// R9: Pbuf parity double-buffer + 2Mx2N GEMM split (both ~neutral; kept).
// R10 (this): attn ONE-SHOT softmax — S=200 fits LDS entirely
// (Ksh[208][40] 16.6K + Vth[32][224] 14.3K + Pbuf dbuf 10.2K = 41.2KB).
// Single staging phase (barriers 6->2/block), all 13 score tiles, ONE
// max/exp/sum reduction per q-tile (shuffle chains /3), online-softmax
// rescale machinery (mrow/fac/accO-rescale) deleted. Math-equivalent.

typedef unsigned short u16;
typedef unsigned int u32;
typedef __attribute__((ext_vector_type(8))) __bf16 bf16x8;
typedef __attribute__((ext_vector_type(4))) float f32x4;

#define GLL16(gp, lp) __builtin_amdgcn_global_load_lds(                 \
    (const __attribute__((address_space(1))) void*)(gp),                \
    (__attribute__((address_space(3))) void*)(lp), 16, 0, 0)

#define FENCE_VM()   do { asm volatile("s_waitcnt vmcnt(0)" ::: "memory");  \
                          __builtin_amdgcn_sched_barrier(0); } while (0)
#define FENCE_LGKM() do { asm volatile("s_waitcnt lgkmcnt(0)" ::: "memory");\
                          __builtin_amdgcn_sched_barrier(0); } while (0)

__device__ __forceinline__ u16 f2bf(float x) {
    u32 u = __float_as_uint(x);
    u = (u + 0x7FFFu + ((u >> 16) & 1u)) >> 16;   // RNE
    return (u16)u;
}
__device__ __forceinline__ float bf2f(u16 h) {
    return __uint_as_float(((u32)h) << 16);
}

__device__ __forceinline__ float gelu_exact(float x) {
    return 0.5f * x * (1.0f + erff(x * 0.7071067811865475f));
}

__device__ __forceinline__ float wave_sum(float v) {
#pragma unroll
    for (int o = 32; o > 0; o >>= 1) v += __shfl_xor(v, o, 64);
    return v;
}
__device__ __forceinline__ float wave_max(float v) {
#pragma unroll
    for (int o = 32; o > 0; o >>= 1) v = fmaxf(v, __shfl_xor(v, o, 64));
    return v;
}
// reduce across the 16 lanes sharing a quad (row of an MFMA C tile)
__device__ __forceinline__ float row_sum16(float v) {
    v += __shfl_xor(v, 1, 64); v += __shfl_xor(v, 2, 64);
    v += __shfl_xor(v, 4, 64); v += __shfl_xor(v, 8, 64);
    return v;
}

__device__ __forceinline__ f32x4 mfma_bf16(bf16x8 a, bf16x8 b, f32x4 c) {
    return __builtin_amdgcn_mfma_f32_16x16x32_bf16(a, b, c, 0, 0, 0);
}

// ---------------------------------------------------------------------------
// Weight prep: W fp32 [K,N] (blockIdx.z batches) -> transposed bf16 hi [N][K]
// ---------------------------------------------------------------------------
__global__ void conv_wt(const float* __restrict__ W, u16* __restrict__ oh,
                        int K, int N)
{
    const long z = blockIdx.z;
    const int idx = blockIdx.x * 256 + threadIdx.x;
    if (idx >= K * N) return;
    const int k = idx / N, n = idx - k * N;
    const float x = W[z * K * N + idx];
    oh[z * (long)K * N + (long)n * K + k] = f2bf(x);
}

// ---------------------------------------------------------------------------
// x [256][39800] fp32 -> xh [200][256][224] u16 (k>=199 -> 0)
// ---------------------------------------------------------------------------
__global__ void conv_x(const float* __restrict__ x, u16* __restrict__ xh)
{
    const long idx = (long)blockIdx.x * 256 + threadIdx.x;
    if (idx >= 200L * 256 * 224) return;
    const int k = (int)(idx % 224);
    const long t = idx / 224;
    const int m = (int)(t % 256);
    const int z = (int)(t / 256);
    const float v = (k < 199) ? x[(long)m * 39800 + z * 199 + k] : 0.f;
    xh[idx] = f2bf(v);
}

// ---------------------------------------------------------------------------
// roi_W [200][199][192] fp32 -> wth [200][192][224] (LDS-tiled transpose)
// ---------------------------------------------------------------------------
__global__ void conv_roiw(const float* __restrict__ W, u16* __restrict__ oh)
{
    __shared__ float tile[32][33];
    const int z = blockIdx.z;
    const int k0 = blockIdx.x * 32;
    const int n0 = blockIdx.y * 32;
    for (int i = threadIdx.y; i < 32; i += 8) {
        const int k = k0 + i, n = n0 + threadIdx.x;
        tile[i][threadIdx.x] = (k < 199) ? W[((long)z * 199 + k) * 192 + n] : 0.f;
    }
    __syncthreads();
    for (int i = threadIdx.y; i < 32; i += 8) {
        const int n = n0 + i, k = k0 + threadIdx.x;
        const float v = tile[threadIdx.x][i];
        oh[((long)z * 192 + n) * 224 + k] = f2bf(v);
    }
}

// ---------------------------------------------------------------------------
// 2Mx2N pure-bf16 GEMM (EPI 0/2/3): C = Ah * Bh. Tile 128x192, BK=32.
// EPI 0: fp32 C. EPI 2: gelu, bf16 store. EPI 3: plain bf16 store.
// ---------------------------------------------------------------------------
template<int EPI>
__global__ __launch_bounds__(256, 3) void gemm_ns(
    const u16* __restrict__ Ah,
    const u16* __restrict__ Bh,
    const float* __restrict__ bias,
    float* __restrict__ C, u16* __restrict__ Ch,
    int N, int K)
{
    __shared__ u16 Ash[128][32];
    __shared__ u16 Bsh[192][32];

    const int tid = threadIdx.x;
    const int wave = tid >> 6, lane = tid & 63;
    const int lm = lane & 15, quad = lane >> 4;
    const int wm = wave >> 1, wn = wave & 1;
    const long m0 = (long)blockIdx.x * 128;
    const int n0 = blockIdx.y * 192;
    const int lrow = lane >> 2;
    const int lch  = (((lane & 3) ^ (lrow & 3)) * 8);   // staging swizzle
    const int sq   = (quad ^ (lm & 3)) * 8;             // read swizzle

    const u16* pA0h = Ah + (m0 + wave * 32 +  0 + lrow) * K + lch;
    const u16* pA1h = Ah + (m0 + wave * 32 + 16 + lrow) * K + lch;
    const u16* pB0h = Bh + (long)(n0 + wave * 48 +  0 + lrow) * K + lch;
    const u16* pB1h = Bh + (long)(n0 + wave * 48 + 16 + lrow) * K + lch;
    const u16* pB2h = Bh + (long)(n0 + wave * 48 + 32 + lrow) * K + lch;

    auto stage = [&](int k0) {
        GLL16(pA0h + k0, &Ash[wave * 32][0]);
        GLL16(pA1h + k0, &Ash[wave * 32 + 16][0]);
        GLL16(pB0h + k0, &Bsh[wave * 48][0]);
        GLL16(pB1h + k0, &Bsh[wave * 48 + 16][0]);
        GLL16(pB2h + k0, &Bsh[wave * 48 + 32][0]);
    };

    f32x4 acc[4][6];
#pragma unroll
    for (int i = 0; i < 4; i++)
#pragma unroll
        for (int j = 0; j < 6; j++)
#pragma unroll
            for (int r = 0; r < 4; r++) acc[i][j][r] = 0.f;

    const int kt = K >> 5;
    stage(0);
    FENCE_VM();
    __syncthreads();

    for (int t = 0; t < kt; t++) {
        bf16x8 afh[4];
#pragma unroll
        for (int mi = 0; mi < 4; mi++)
            afh[mi] = *(const bf16x8*)&Ash[wm * 64 + mi * 16 + lm][sq];
#pragma unroll
        for (int jh = 0; jh < 2; jh++) {
            bf16x8 bfh[3];
#pragma unroll
            for (int j = 0; j < 3; j++)
                bfh[j] = *(const bf16x8*)&Bsh[wn * 96 + (jh * 3 + j) * 16 + lm][sq];
#pragma unroll
            for (int mi = 0; mi < 4; mi++)
#pragma unroll
                for (int j = 0; j < 3; j++)
                    acc[mi][jh * 3 + j] =
                        mfma_bf16(afh[mi], bfh[j], acc[mi][jh * 3 + j]);
        }
        if (t + 1 < kt) {
            __syncthreads();
            stage((t + 1) << 5);
            FENCE_VM();
            __syncthreads();
        }
    }

#pragma unroll
    for (int mi = 0; mi < 4; mi++) {
        const long rowb = m0 + wm * 64 + mi * 16 + quad * 4;
#pragma unroll
        for (int nj = 0; nj < 6; nj++) {
            const int col = n0 + wn * 96 + nj * 16 + lm;
            const float bv = bias[col];
#pragma unroll
            for (int r = 0; r < 4; r++) {
                float v = acc[mi][nj][r] + bv;
                if (EPI == 0) {
                    C[(rowb + r) * N + col] = v;
                } else {
                    if (EPI == 2) v = gelu_exact(v);
                    Ch[(rowb + r) * N + col] = f2bf(v);
                }
            }
        }
    }
}

// ---------------------------------------------------------------------------
// 4-wave-M pure-bf16 GEMM with fused residual+LN epilogue:
// H := LN(H + acc + bias). N must be 192 (full rows per wave for the LN).
// ---------------------------------------------------------------------------
__global__ __launch_bounds__(256, 3) void gemm_ln(
    const u16* __restrict__ Ah,
    const u16* __restrict__ Bh,
    const float* __restrict__ bias,
    u16* __restrict__ Hh, u16* __restrict__ Hl,
    const float* __restrict__ lng, const float* __restrict__ lnb,
    int K)
{
    __shared__ u16 Ash[128][32];
    __shared__ u16 Bsh[192][32];

    const int tid = threadIdx.x;
    const int wave = tid >> 6, lane = tid & 63;
    const int lm = lane & 15, quad = lane >> 4;
    const long m0 = (long)blockIdx.x * 128;
    const int lrow = lane >> 2;
    const int lch  = (((lane & 3) ^ (lrow & 3)) * 8);
    const int sq   = (quad ^ (lm & 3)) * 8;

    const u16* pA0h = Ah + (m0 + wave * 32 +  0 + lrow) * K + lch;
    const u16* pA1h = Ah + (m0 + wave * 32 + 16 + lrow) * K + lch;
    const u16* pB0h = Bh + (long)(wave * 48 +  0 + lrow) * K + lch;
    const u16* pB1h = Bh + (long)(wave * 48 + 16 + lrow) * K + lch;
    const u16* pB2h = Bh + (long)(wave * 48 + 32 + lrow) * K + lch;

    auto stage = [&](int k0) {
        GLL16(pA0h + k0, &Ash[wave * 32][0]);
        GLL16(pA1h + k0, &Ash[wave * 32 + 16][0]);
        GLL16(pB0h + k0, &Bsh[wave * 48][0]);
        GLL16(pB1h + k0, &Bsh[wave * 48 + 16][0]);
        GLL16(pB2h + k0, &Bsh[wave * 48 + 32][0]);
    };

    f32x4 acc[2][12];
#pragma unroll
    for (int i = 0; i < 2; i++)
#pragma unroll
        for (int j = 0; j < 12; j++)
#pragma unroll
            for (int r = 0; r < 4; r++) acc[i][j][r] = 0.f;

    const int kt = K >> 5;
    stage(0);
    FENCE_VM();
    __syncthreads();

    for (int t = 0; t < kt; t++) {
        bf16x8 afh[2];
#pragma unroll
        for (int mi = 0; mi < 2; mi++)
            afh[mi] = *(const bf16x8*)&Ash[wave * 32 + mi * 16 + lm][sq];
#pragma unroll
        for (int g = 0; g < 4; g++) {
            bf16x8 bfh[3];
#pragma unroll
            for (int j = 0; j < 3; j++)
                bfh[j] = *(const bf16x8*)&Bsh[g * 48 + j * 16 + lm][sq];
#pragma unroll
            for (int mi = 0; mi < 2; mi++)
#pragma unroll
                for (int j = 0; j < 3; j++) {
                    const int ni = g * 3 + j;
                    acc[mi][ni] = mfma_bf16(afh[mi], bfh[j], acc[mi][ni]);
                }
        }
        if (t + 1 < kt) {
            __syncthreads();
            stage((t + 1) << 5);
            FENCE_VM();
            __syncthreads();
        }
    }

    float gv[12], bv2[12], biasv[12];
#pragma unroll
    for (int ni = 0; ni < 12; ni++) {
        const int col = ni * 16 + lm;
        gv[ni] = lng[col]; bv2[ni] = lnb[col]; biasv[ni] = bias[col];
    }
#pragma unroll
    for (int mi = 0; mi < 2; mi++) {
#pragma unroll
        for (int r = 0; r < 4; r++) {
            const long row = m0 + wave * 32 + mi * 16 + quad * 4 + r;
            const long rb = row * 192;
            float vals[12];
            float s = 0.f;
#pragma unroll
            for (int ni = 0; ni < 12; ni++) {
                const int col = ni * 16 + lm;
                const float hval = bf2f(Hh[rb + col]) + bf2f(Hl[rb + col]);
                vals[ni] = acc[mi][ni][r] + biasv[ni] + hval;
                s += vals[ni];
            }
            const float mean = row_sum16(s) * (1.f / 192.f);
            float ss = 0.f;
#pragma unroll
            for (int ni = 0; ni < 12; ni++) {
                vals[ni] -= mean;
                ss += vals[ni] * vals[ni];
            }
            const float var = row_sum16(ss) * (1.f / 192.f);
            const float rsr = 1.f / sqrtf(var + 1e-5f);
#pragma unroll
            for (int ni = 0; ni < 12; ni++) {
                const int col = ni * 16 + lm;
                const float y = vals[ni] * rsr * gv[ni] + bv2[ni];
                const u16 hb = f2bf(y);
                Hh[rb + col] = hb;
                Hl[rb + col] = f2bf(y - bf2f(hb));
            }
        }
    }
}

// ---------------------------------------------------------------------------
// Tokenizer MFMA (pure bf16): per-z GEMM [256,224]@[192,224]^T with fused
// bias+LN+gelu+pos epilogue (full-row LN -> keeps 4-wave-M layout).
// ---------------------------------------------------------------------------
__global__ __launch_bounds__(256, 3) void tok_mfma(
    const u16* __restrict__ xh,
    const u16* __restrict__ wth,
    const float* __restrict__ roi_b,
    const float* __restrict__ lng, const float* __restrict__ lnb,
    const float* __restrict__ pos,
    u16* __restrict__ hh, u16* __restrict__ hl)
{
    __shared__ u16 Ash[128][32];
    __shared__ u16 Bsh[192][32];

    const int tid = threadIdx.x;
    const int wave = tid >> 6, lane = tid & 63;
    const int lm = lane & 15, quad = lane >> 4;
    const int m0 = blockIdx.x * 128;
    const int z = blockIdx.y;
    const int lrow = lane >> 2;
    const int lch  = (((lane & 3) ^ (lrow & 3)) * 8);
    const int sq   = (quad ^ (lm & 3)) * 8;
    const int K = 224;

    const u16* pA0h = xh + ((long)z * 256 + m0 + wave * 32 +  0 + lrow) * K + lch;
    const u16* pA1h = xh + ((long)z * 256 + m0 + wave * 32 + 16 + lrow) * K + lch;
    const u16* pB0h = wth + ((long)z * 192 + wave * 48 +  0 + lrow) * K + lch;
    const u16* pB1h = wth + ((long)z * 192 + wave * 48 + 16 + lrow) * K + lch;
    const u16* pB2h = wth + ((long)z * 192 + wave * 48 + 32 + lrow) * K + lch;

    auto stage = [&](int k0) {
        GLL16(pA0h + k0, &Ash[wave * 32][0]);
        GLL16(pA1h + k0, &Ash[wave * 32 + 16][0]);
        GLL16(pB0h + k0, &Bsh[wave * 48][0]);
        GLL16(pB1h + k0, &Bsh[wave * 48 + 16][0]);
        GLL16(pB2h + k0, &Bsh[wave * 48 + 32][0]);
    };

    f32x4 acc[2][12];
#pragma unroll
    for (int i = 0; i < 2; i++)
#pragma unroll
        for (int j = 0; j < 12; j++)
#pragma unroll
            for (int r = 0; r < 4; r++) acc[i][j][r] = 0.f;

    stage(0);
    FENCE_VM();
    __syncthreads();
    for (int t = 0; t < 7; t++) {
        bf16x8 afh[2];
#pragma unroll
        for (int mi = 0; mi < 2; mi++)
            afh[mi] = *(const bf16x8*)&Ash[wave * 32 + mi * 16 + lm][sq];
#pragma unroll
        for (int g = 0; g < 4; g++) {
            bf16x8 bfh[3];
#pragma unroll
            for (int j = 0; j < 3; j++)
                bfh[j] = *(const bf16x8*)&Bsh[g * 48 + j * 16 + lm][sq];
#pragma unroll
            for (int mi = 0; mi < 2; mi++)
#pragma unroll
                for (int j = 0; j < 3; j++) {
                    const int ni = g * 3 + j;
                    acc[mi][ni] = mfma_bf16(afh[mi], bfh[j], acc[mi][ni]);
                }
        }
        if (t + 1 < 7) {
            __syncthreads();
            stage((t + 1) << 5);
            FENCE_VM();
            __syncthreads();
        }
    }

    float gv[12], bv2[12], biasv[12], pv[12];
#pragma unroll
    for (int ni = 0; ni < 12; ni++) {
        const int col = ni * 16 + lm;
        gv[ni]    = lng[z * 192 + col];
        bv2[ni]   = lnb[z * 192 + col];
        biasv[ni] = roi_b[z * 192 + col];
        pv[ni]    = pos[z * 192 + col];
    }
#pragma unroll
    for (int mi = 0; mi < 2; mi++) {
#pragma unroll
        for (int r = 0; r < 4; r++) {
            const int brow = m0 + wave * 32 + mi * 16 + quad * 4 + r;
            float vals[12];
            float s = 0.f;
#pragma unroll
            for (int ni = 0; ni < 12; ni++) {
                vals[ni] = acc[mi][ni][r] + biasv[ni];
                s += vals[ni];
            }
            const float mean = row_sum16(s) * (1.f / 192.f);
            float ss = 0.f;
#pragma unroll
            for (int ni = 0; ni < 12; ni++) {
                vals[ni] -= mean;
                ss += vals[ni] * vals[ni];
            }
            const float var = row_sum16(ss) * (1.f / 192.f);
            const float rsr = 1.f / sqrtf(var + 1e-5f);
            const long ob = ((long)brow * 200 + z) * 192;
#pragma unroll
            for (int ni = 0; ni < 12; ni++) {
                const int col = ni * 16 + lm;
                const float y = gelu_exact(vals[ni] * rsr * gv[ni] + bv2[ni]) + pv[ni];
                const u16 hb = f2bf(y);
                hh[ob + col] = hb;
                hl[ob + col] = f2bf(y - bf2f(hb));
            }
        }
    }
}

// ---------------------------------------------------------------------------
// fp32 GEMM (tiny pool GEMMs). Tile 128x64, BK=16.
// ---------------------------------------------------------------------------
template<int EPI>
__global__ __launch_bounds__(256) void gemm_kernel(
    const float* __restrict__ A, int lda, long strideA,
    const float* __restrict__ Bw, long strideB,
    const float* __restrict__ bias, long strideBias,
    float* __restrict__ C, int ldc, long strideC,
    int M, int N, int K, int ldb)
{
    __shared__ float As[16][132];
    __shared__ float Bs[16][68];

    const int z = blockIdx.z;
    const float* Ab    = A    + (long)z * strideA;
    const float* Bb    = Bw   + (long)z * strideB;
    const float* biasb = bias + (long)z * strideBias;
    float*       Cb    = C    + (long)z * strideC;

    const int row0 = blockIdx.x * 128;
    const int col0 = blockIdx.y * 64;
    const int tid  = threadIdx.x;
    const int tm = tid >> 4;
    const int tn = tid & 15;

    const int la_m = tid >> 1;
    const int la_k = (tid & 1) * 8;
    const int lb_k = tid >> 4;
    const int lb_n = (tid & 15) * 4;

    const float* bcol = Bb + (col0 + lb_n);
    const float* arow = Ab + (long)(row0 + la_m) * lda;
    const bool vecA = ((lda & 3) == 0) &&
                      ((((unsigned long long)(const void*)arow) & 15ull) == 0ull);

    float acc[8][4];
#pragma unroll
    for (int i = 0; i < 8; i++)
#pragma unroll
        for (int j = 0; j < 4; j++) acc[i][j] = 0.f;

    for (int k0 = 0; k0 < K; k0 += 16) {
        if (vecA && (k0 + 16 <= K)) {
            float4 v0 = *(const float4*)(arow + k0 + la_k);
            float4 v1 = *(const float4*)(arow + k0 + la_k + 4);
            As[la_k + 0][la_m] = v0.x; As[la_k + 1][la_m] = v0.y;
            As[la_k + 2][la_m] = v0.z; As[la_k + 3][la_m] = v0.w;
            As[la_k + 4][la_m] = v1.x; As[la_k + 5][la_m] = v1.y;
            As[la_k + 6][la_m] = v1.z; As[la_k + 7][la_m] = v1.w;
        } else {
#pragma unroll
            for (int i = 0; i < 8; i++) {
                int k = k0 + la_k + i;
                As[la_k + i][la_m] = (k < K) ? arow[k] : 0.f;
            }
        }
        {
            int k = k0 + lb_k;
            float4 v = make_float4(0.f, 0.f, 0.f, 0.f);
            if (k < K) v = *(const float4*)(bcol + (long)k * ldb);
            *(float4*)&Bs[lb_k][lb_n] = v;
        }
        __syncthreads();
#pragma unroll
        for (int kk = 0; kk < 16; kk++) {
            float4 a0 = *(const float4*)&As[kk][tm * 8];
            float4 a1 = *(const float4*)&As[kk][tm * 8 + 4];
            float4 b4 = *(const float4*)&Bs[kk][tn * 4];
            float av[8] = {a0.x, a0.y, a0.z, a0.w, a1.x, a1.y, a1.z, a1.w};
            float bv[4] = {b4.x, b4.y, b4.z, b4.w};
#pragma unroll
            for (int i = 0; i < 8; i++)
#pragma unroll
                for (int j = 0; j < 4; j++) acc[i][j] += av[i] * bv[j];
        }
        __syncthreads();
    }

    const int gcol = col0 + tn * 4;
    float4 bv4 = *(const float4*)(biasb + gcol);
#pragma unroll
    for (int i = 0; i < 8; i++) {
        int grow = row0 + tm * 8 + i;
        float4 o;
        o.x = acc[i][0] + bv4.x; o.y = acc[i][1] + bv4.y;
        o.z = acc[i][2] + bv4.z; o.w = acc[i][3] + bv4.w;
        if (EPI == 1) {
            o.x = gelu_exact(o.x); o.y = gelu_exact(o.y);
            o.z = gelu_exact(o.z); o.w = gelu_exact(o.w);
        }
        *(float4*)(Cb + (long)grow * ldc + gcol) = o;
    }
}

// ---------------------------------------------------------------------------
// MFMA flash encoder attention — R10: ONE-SHOT softmax (S=200 fits LDS).
// Stage all keys once: Ksh[208][40] + Vth[32][224] + Pbuf dbuf = 41.2 KB.
// Per q-tile: 13 QK MFMAs -> ONE max/exp/sum reduction -> 7 PV chunks
// (parity double-buffered Pbuf, RAW lgkmcnt fence per chunk).
// No online-softmax rescale (mrow/fac deleted). 2 barriers per block.
// launch_bounds (256,2): natural regs (watch WRITE_SIZE for spill).
// ---------------------------------------------------------------------------
__global__ __launch_bounds__(256, 2) void attn_enc_mfma(
    const u16* __restrict__ qkvh, u16* __restrict__ outh)
{
    __shared__ u16 Ksh[208][40];        // 16640 B
    __shared__ u16 Vth[32][224];        // 14336 B
    __shared__ u16 Pbuf[4][2][16][40];  // 10240 B

    const int bh = blockIdx.x;
    const int b = bh / 6, h = bh % 6;
    const int tid = threadIdx.x;
    const int wave = tid >> 6, lane = tid & 63;
    const int lm = lane & 15, quad = lane >> 4;
    const int nq = (wave == 0) ? 4 : 3;

    uint4 qh[4];
#pragma unroll
    for (int i = 0; i < 4; i++) {
        if (i < nq) {
            int qt = wave + 4 * i;
            int qrow = qt * 16 + lm; if (qrow > 199) qrow = 199;
            const long off = (long)(b * 200 + qrow) * 576 + h * 32 + quad * 8;
            qh[i] = *(const uint4*)(qkvh + off);
        }
    }

    // ---- staging (single phase): waves 0-1 -> K, waves 2-3 -> V^T ----
    if (wave < 2) {
        const int sub = wave * 64 + lane;            // 0..127
#pragma unroll
        for (int rep = 0; rep < 7; rep++) {
            const int idx = rep * 128 + sub;
            if (idx < 208 * 4) {
                const int key = idx >> 2, ch = idx & 3;
                const bool valid = key < 200;
                const long roff = (long)(b * 200 + (valid ? key : 0)) * 576
                                  + h * 32 + 192 + ch * 8;
                uint4 v = valid ? *(const uint4*)(qkvh + roff)
                                : make_uint4(0, 0, 0, 0);
                *(uint4*)(&Ksh[0][0] + key * 40 + ch * 8) = v;
            }
        }
    } else {
        const int sub = (wave - 2) * 64 + lane;      // 0..127
#pragma unroll
        for (int rep = 0; rep < 4; rep++) {
            const int idx = rep * 128 + sub;
            if (idx < 224 * 2) {
                const int key = idx >> 1, hf = idx & 1;
                const bool valid = key < 200;
                const long roff = (long)(b * 200 + (valid ? key : 0)) * 576
                                  + h * 32 + 384 + hf * 16;
                uint4 v0 = valid ? *(const uint4*)(qkvh + roff)
                                 : make_uint4(0, 0, 0, 0);
                uint4 v1 = valid ? *(const uint4*)(qkvh + roff + 8)
                                 : make_uint4(0, 0, 0, 0);
                const u16* p0 = (const u16*)&v0;
                const u16* p1 = (const u16*)&v1;
#pragma unroll
                for (int j = 0; j < 8; j++) {
                    Vth[hf * 16 + j][key]     = p0[j];
                    Vth[hf * 16 + 8 + j][key] = p1[j];
                }
            }
        }
    }
    __syncthreads();

    const float scale = 0.17677669529663688f;
    int par = 0;   // Pbuf parity (wave-uniform)
    float lrow[4][4];
    f32x4 accO[4][2];

#pragma unroll
    for (int i = 0; i < 4; i++) {
        if (i >= nq) continue;
        const bf16x8 qhf = *(const bf16x8*)&qh[i];
        float s[13][4];
#pragma unroll
        for (int ni = 0; ni < 13; ni++) {
            bf16x8 kh8 = *(const bf16x8*)&Ksh[ni * 16 + lm][quad * 8];
            f32x4 c = {0.f, 0.f, 0.f, 0.f};
            c = mfma_bf16(qhf, kh8, c);
            const bool masked = (ni * 16 + lm) >= 200;
#pragma unroll
            for (int r = 0; r < 4; r++)
                s[ni][r] = masked ? -1e30f : c[r] * scale;
        }
        // one-shot softmax per row
#pragma unroll
        for (int r = 0; r < 4; r++) {
            float pm = s[0][r];
#pragma unroll
            for (int ni = 1; ni < 13; ni++) pm = fmaxf(pm, s[ni][r]);
            pm = fmaxf(pm, __shfl_xor(pm, 1, 64));
            pm = fmaxf(pm, __shfl_xor(pm, 2, 64));
            pm = fmaxf(pm, __shfl_xor(pm, 4, 64));
            pm = fmaxf(pm, __shfl_xor(pm, 8, 64));
            float ps = 0.f;
#pragma unroll
            for (int ni = 0; ni < 13; ni++) {
                float e = __expf(s[ni][r] - pm);
                s[ni][r] = e;
                ps += e;
            }
            ps += __shfl_xor(ps, 1, 64);
            ps += __shfl_xor(ps, 2, 64);
            ps += __shfl_xor(ps, 4, 64);
            ps += __shfl_xor(ps, 8, 64);
            lrow[i][r] = ps;
            accO[i][0][r] = 0.f;
            accO[i][1][r] = 0.f;
        }
        // PV: 7 chunks of 32 keys through parity-double-buffered Pbuf
#pragma unroll
        for (int ck = 0; ck < 7; ck++) {
            const int pb = par & 1; par++;
#pragma unroll
            for (int tl = 0; tl < 2; tl++) {
                const int t = 2 * ck + tl;   // 0..13
#pragma unroll
                for (int r = 0; r < 4; r++) {
                    const float val = (t < 13) ? s[t][r] : 0.f;
                    Pbuf[wave][pb][quad * 4 + r][tl * 16 + lm] = f2bf(val);
                }
            }
            // RAW guard: cross-lane handoff within the wave.
            FENCE_LGKM();
            const bf16x8 pa = *(const bf16x8*)&Pbuf[wave][pb][lm][quad * 8];
#pragma unroll
            for (int nt = 0; nt < 2; nt++) {
                bf16x8 vh8 = *(const bf16x8*)&Vth[nt * 16 + lm][ck * 32 + quad * 8];
                accO[i][nt] = mfma_bf16(pa, vh8, accO[i][nt]);
            }
        }
    }

#pragma unroll
    for (int i = 0; i < 4; i++) {
        if (i >= nq) continue;
        const int qt = wave + 4 * i;
#pragma unroll
        for (int r = 0; r < 4; r++) {
            const int qrow = qt * 16 + quad * 4 + r;
            if (qrow >= 200) continue;
            const float inv = 1.f / lrow[i][r];
            const long ob = (long)(b * 200 + qrow) * 192 + h * 32 + lm;
            outh[ob]      = f2bf(accO[i][0][r] * inv);
            outh[ob + 16] = f2bf(accO[i][1][r] * inv);
        }
    }
}

// ---------------------------------------------------------------------------
__global__ __launch_bounds__(192) void mean_tokens_pair(
    const u16* __restrict__ hh, const u16* __restrict__ hl, float* __restrict__ qmean)
{
    const int b = blockIdx.x, d = threadIdx.x;
    float s = 0.f;
    for (int r = 0; r < 200; r++) {
        const long idx = ((long)b * 200 + r) * 192 + d;
        s += bf2f(hh[idx]) + bf2f(hl[idx]);
    }
    qmean[b * 192 + d] = s * (1.f / 200.f);
}

// ---------------------------------------------------------------------------
__global__ __launch_bounds__(64) void attn_pool(
    const float* __restrict__ qp, const float* __restrict__ kv,
    float* __restrict__ out)
{
    __shared__ float p[200];
    const int b = blockIdx.x / 6, h = blockIdx.x % 6;
    const int lane = threadIdx.x;

    const float* qrow = qp + b * 192 + h * 32;
    float qr[32];
#pragma unroll
    for (int u = 0; u < 8; u++) {
        float4 t = *(const float4*)(qrow + 4 * u);
        qr[4 * u] = t.x; qr[4 * u + 1] = t.y;
        qr[4 * u + 2] = t.z; qr[4 * u + 3] = t.w;
    }
    const float scale = 0.17677669529663688f;
    const float* kb = kv + (long)(b * 200) * 384 + h * 32;
    float s[4];
    float mymax = -1e30f;
#pragma unroll
    for (int g = 0; g < 4; g++) {
        int j = lane + 64 * g;
        if (j < 200) {
            const float* kr = kb + (long)j * 384;
            float acc = 0.f;
#pragma unroll
            for (int u = 0; u < 8; u++) {
                float4 k4 = *(const float4*)(kr + 4 * u);
                acc += qr[4 * u] * k4.x + qr[4 * u + 1] * k4.y +
                       qr[4 * u + 2] * k4.z + qr[4 * u + 3] * k4.w;
            }
            s[g] = acc * scale;
            mymax = fmaxf(mymax, s[g]);
        } else {
            s[g] = -1e30f;
        }
    }
    float mx = wave_max(mymax);
    float psum = 0.f;
#pragma unroll
    for (int g = 0; g < 4; g++) {
        int j = lane + 64 * g;
        if (j < 200) {
            float e = __expf(s[g] - mx);
            p[j] = e;
            psum += e;
        }
    }
    float tot = wave_sum(psum);
    __syncthreads();
    const int half = lane >> 5, d = lane & 31;
    const float* vb = kv + (long)(b * 200) * 384 + 192 + h * 32 + d;
    float acc = 0.f;
    for (int jj = 0; jj < 100; jj++) {
        int j = half * 100 + jj;
        acc += p[j] * vb[(long)j * 384];
    }
    acc += __shfl_xor(acc, 32, 64);
    acc /= tot;
    if (lane < 32) out[b * 192 + h * 32 + d] = acc;
}

// ---------------------------------------------------------------------------
__global__ __launch_bounds__(64) void classifier_kernel(
    const float* __restrict__ pooled,
    const float* __restrict__ g, const float* __restrict__ bt,
    const float* __restrict__ W1, const float* __restrict__ b1,
    const float* __restrict__ W2, const float* __restrict__ b2,
    const float* __restrict__ W3, const float* __restrict__ b3,
    float* __restrict__ out)
{
    __shared__ float z[192];
    __shared__ float z1[96];
    __shared__ float z2[48];
    const int b = blockIdx.x, lane = threadIdx.x;
    const float* pr = pooled + b * 192;
    float x0 = pr[lane], x1 = pr[lane + 64], x2 = pr[lane + 128];
    float m = wave_sum(x0 + x1 + x2) * (1.f / 192.f);
    float d0 = x0 - m, d1 = x1 - m, d2 = x2 - m;
    float v = wave_sum(d0 * d0 + d1 * d1 + d2 * d2) * (1.f / 192.f);
    float rs = 1.f / sqrtf(v + 1e-5f);
    z[lane]       = d0 * rs * g[lane]       + bt[lane];
    z[lane + 64]  = d1 * rs * g[lane + 64]  + bt[lane + 64];
    z[lane + 128] = d2 * rs * g[lane + 128] + bt[lane + 128];
    __syncthreads();
#pragma unroll
    for (int rep = 0; rep < 2; rep++) {
        int j = lane + rep * 64;
        if (j < 96) {
            float a = b1[j];
            for (int k = 0; k < 192; k++) a += z[k] * W1[k * 96 + j];
            z1[j] = gelu_exact(a);
        }
    }
    __syncthreads();
    if (lane < 48) {
        float a = b2[lane];
        for (int k = 0; k < 96; k++) a += z1[k] * W2[k * 48 + lane];
        z2[lane] = gelu_exact(a);
    }
    __syncthreads();
    if (lane < 2) {
        float a = b3[lane];
        for (int k = 0; k < 48; k++) a += z2[k] * W3[k * 2 + lane];
        out[b * 2 + lane] = a;
    }
}

// ---------------------------------------------------------------------------
extern "C" void kernel_launch(void* const* d_in, const int* in_sizes, int n_in,
                              void* d_out, int out_size, void* d_ws, size_t ws_size,
                              hipStream_t stream)
{
    (void)in_sizes; (void)n_in; (void)out_size; (void)ws_size;

    const float* x         = (const float*)d_in[0];
    const float* roi_W     = (const float*)d_in[1];
    const float* roi_b     = (const float*)d_in[2];
    const float* roi_ln_g  = (const float*)d_in[3];
    const float* roi_ln_b  = (const float*)d_in[4];
    const float* pos_emb   = (const float*)d_in[5];
    const float* enc_Wqkv  = (const float*)d_in[6];
    const float* enc_bqkv  = (const float*)d_in[7];
    const float* enc_Wo    = (const float*)d_in[8];
    const float* enc_bo    = (const float*)d_in[9];
    const float* enc_ln1_g = (const float*)d_in[10];
    const float* enc_ln1_b = (const float*)d_in[11];
    const float* enc_W1    = (const float*)d_in[12];
    const float* enc_b1    = (const float*)d_in[13];
    const float* enc_W2    = (const float*)d_in[14];
    const float* enc_b2    = (const float*)d_in[15];
    const float* enc_ln2_g = (const float*)d_in[16];
    const float* enc_ln2_b = (const float*)d_in[17];
    const float* pool_Wqkv = (const float*)d_in[18];
    const float* pool_bqkv = (const float*)d_in[19];
    const float* pool_Wo   = (const float*)d_in[20];
    const float* pool_bo   = (const float*)d_in[21];
    const float* cls_ln_g  = (const float*)d_in[22];
    const float* cls_ln_b  = (const float*)d_in[23];
    const float* cls_W1    = (const float*)d_in[24];
    const float* cls_b1    = (const float*)d_in[25];
    const float* cls_W2    = (const float*)d_in[26];
    const float* cls_b2    = (const float*)d_in[27];
    const float* cls_W3    = (const float*)d_in[28];
    const float* cls_b3    = (const float*)d_in[29];

    char* ws = (char*)d_ws;
    u16*   hh    = (u16*)(ws);                      // [T,192] hi
    u16*   hl    = (u16*)(ws + 19660800);           // [T,192] lo
    char*  bufA  = ws + 39321600;                   // 117,964,800 B
    float* bufAf = (float*)bufA;
    // tokenizer-phase layout of bufA:
    u16*   xh    = (u16*)bufA;                      // 200*256*224 u16
    u16*   wth   = (u16*)(bufA + 45875200);         // 200*192*224 u16
    // encoder-phase layout of bufA:
    u16*   qkvh  = (u16*)bufA;                      // [T,576] hi (single plane)
    u16*   ffh   = (u16*)bufA;                      // [T,576] (hi only)
    char*  bufB  = ws + 157286400;
    u16*   bBh   = (u16*)bufB;                      // attn out (hi only)
    float* qmean = (float*)(ws + 196608000);
    float* qp    = qmean + 49152;
    float* pattn = qp + 49152;
    float* pooled= pattn + 49152;
    char*  wts   = ws + 197394432;
    u16* WqkvH = (u16*)(wts);
    u16* Wff1H = (u16*)(wts + 1327104);
    u16* Wff2H = (u16*)(wts + 2654208);
    u16* WwoH  = (u16*)(wts + 3981312);
    u16* WkvH  = (u16*)(wts + 4423680);

    // ---- weight split/transpose (once per call, hi plane only) ----
    conv_wt<<<dim3(144, 1, 9), 256, 0, stream>>>(enc_Wqkv, WqkvH, 192, 192);
    conv_wt<<<dim3(432, 1, 3), 256, 0, stream>>>(enc_W1, Wff1H, 192, 576);
    conv_wt<<<dim3(432, 1, 3), 256, 0, stream>>>(enc_W2, Wff2H, 576, 192);
    conv_wt<<<dim3(144, 1, 3), 256, 0, stream>>>(enc_Wo, WwoH, 192, 192);
    conv_wt<<<dim3(144, 1, 2), 256, 0, stream>>>(pool_Wqkv + 36864, WkvH, 192, 192);

    // ---- tokenizer ----
    conv_x<<<44800, 256, 0, stream>>>(x, xh);
    conv_roiw<<<dim3(7, 6, 200), dim3(32, 8), 0, stream>>>(roi_W, wth);
    tok_mfma<<<dim3(2, 200), 256, 0, stream>>>(
        xh, wth, roi_b, roi_ln_g, roi_ln_b, pos_emb, hh, hl);

    // ---- encoder layers ----
    for (int i = 0; i < 3; i++) {
        gemm_ns<3><<<dim3(400, 3), 256, 0, stream>>>(
            hh, WqkvH + (long)i * 110592,
            enc_bqkv + i * 576, nullptr, qkvh, 576, 192);
        attn_enc_mfma<<<1536, 256, 0, stream>>>(qkvh, bBh);
        gemm_ln<<<dim3(400, 1), 256, 0, stream>>>(
            bBh, WwoH + (long)i * 36864,
            enc_bo + i * 192,
            hh, hl, enc_ln1_g + i * 192, enc_ln1_b + i * 192, 192);
        gemm_ns<2><<<dim3(400, 3), 256, 0, stream>>>(
            hh, Wff1H + (long)i * 110592,
            enc_b1 + i * 576, nullptr, ffh, 576, 192);
        gemm_ln<<<dim3(400, 1), 256, 0, stream>>>(
            ffh, Wff2H + (long)i * 110592,
            enc_b2 + i * 192,
            hh, hl, enc_ln2_g + i * 192, enc_ln2_b + i * 192, 576);
    }

    // ---- pooling ----
    mean_tokens_pair<<<256, 192, 0, stream>>>(hh, hl, qmean);
    gemm_kernel<0><<<dim3(2, 3, 1), 256, 0, stream>>>(
        qmean, 192, 0, pool_Wqkv, 0, pool_bqkv, 0, qp, 192, 0, 256, 192, 192, 192);
    gemm_ns<0><<<dim3(400, 2), 256, 0, stream>>>(
        hh, WkvH, pool_bqkv + 192, bufAf, nullptr, 384, 192);
    attn_pool<<<1536, 64, 0, stream>>>(qp, bufAf, pattn);
    gemm_kernel<0><<<dim3(2, 3, 1), 256, 0, stream>>>(
        pattn, 192, 0, pool_Wo, 0, pool_bo, 0, pooled, 192, 0, 256, 192, 192, 192);

    // ---- classifier ----
    classifier_kernel<<<256, 64, 0, stream>>>(
        pooled, cls_ln_g, cls_ln_b,
        cls_W1, cls_b1, cls_W2, cls_b2, cls_W3, cls_b3,
        (float*)d_out);
}